// Round 1
// baseline (2605.949 us; speedup 1.0000x reference)
//
#include <hip/hip_runtime.h>
#include <math.h>

// ---------------- constants ----------------
#define EE 128
#define DI 256
#define HH 8
#define PP 32
#define NN 64
#define DC 4
#define XBC 384
#define DIN 648
#define NL 4
#define LSEQ 256
#define BB 256
#define TTOK (BB * LSEQ)   // 65536 tokens
#define EPSF 1e-5f

// ---------------- generic fp32 GEMM: C[M][N] = A[M][K] * B[N][K]^T (+bias)(+resid) ----------------
// 64x64 tile, 256 threads, 4x4 per thread, K multiple of 16, M multiple of 64, N guarded.
__global__ __launch_bounds__(256) void gemm_nt_kernel(
    const float* __restrict__ A, const float* __restrict__ B,
    float* C, const float* resid, const float* __restrict__ bias,
    int M, int N, int K) {
  __shared__ float As[16][68];
  __shared__ float Bs[16][68];
  const int tid = threadIdx.x;
  const int m0 = blockIdx.x * 64, n0 = blockIdx.y * 64;
  const int tx = tid & 15, ty = tid >> 4;
  const int li = tid >> 2, ki = (tid & 3) * 4;
  float acc[4][4] = {};
  for (int k0 = 0; k0 < K; k0 += 16) {
    float4 av = *(const float4*)(A + (size_t)(m0 + li) * K + k0 + ki);
    float4 bv = make_float4(0.f, 0.f, 0.f, 0.f);
    if (n0 + li < N) bv = *(const float4*)(B + (size_t)(n0 + li) * K + k0 + ki);
    As[ki + 0][li] = av.x; As[ki + 1][li] = av.y; As[ki + 2][li] = av.z; As[ki + 3][li] = av.w;
    Bs[ki + 0][li] = bv.x; Bs[ki + 1][li] = bv.y; Bs[ki + 2][li] = bv.z; Bs[ki + 3][li] = bv.w;
    __syncthreads();
#pragma unroll
    for (int k = 0; k < 16; ++k) {
      float4 a = *(const float4*)&As[k][ty * 4];
      float4 b4 = *(const float4*)&Bs[k][tx * 4];
      acc[0][0] += a.x * b4.x; acc[0][1] += a.x * b4.y; acc[0][2] += a.x * b4.z; acc[0][3] += a.x * b4.w;
      acc[1][0] += a.y * b4.x; acc[1][1] += a.y * b4.y; acc[1][2] += a.y * b4.z; acc[1][3] += a.y * b4.w;
      acc[2][0] += a.z * b4.x; acc[2][1] += a.z * b4.y; acc[2][2] += a.z * b4.z; acc[2][3] += a.z * b4.w;
      acc[3][0] += a.w * b4.x; acc[3][1] += a.w * b4.y; acc[3][2] += a.w * b4.z; acc[3][3] += a.w * b4.w;
    }
    __syncthreads();
  }
#pragma unroll
  for (int i = 0; i < 4; ++i) {
    int m = m0 + ty * 4 + i;
#pragma unroll
    for (int j = 0; j < 4; ++j) {
      int n = n0 + tx * 4 + j;
      if (n < N) {
        float v = acc[i][j];
        if (bias) v += bias[n];
        if (resid) v += resid[(size_t)m * N + n];
        C[(size_t)m * N + n] = v;
      }
    }
  }
}

// ---------------- patch-embed GEMM: t[token][e] = sum_k patch(x)[token][k]*conv_w[e][k] + conv_b ----------------
// M=65536, N=128, K=768 (c*256 + dx*16 + dy)
__global__ __launch_bounds__(256) void gemm_patch_kernel(
    const float* __restrict__ X, const float* __restrict__ B,
    const float* __restrict__ bias, float* __restrict__ C) {
  __shared__ float As[16][68];
  __shared__ float Bs[16][68];
  const int tid = threadIdx.x;
  const int m0 = blockIdx.x * 64, n0 = blockIdx.y * 64;
  const int tx = tid & 15, ty = tid >> 4;
  const int li = tid >> 2, ki = (tid & 3) * 4;
  const int m = m0 + li;
  const int bb = m >> 8, px = (m >> 4) & 15, py = m & 15;
  float acc[4][4] = {};
  for (int k0 = 0; k0 < 768; k0 += 16) {
    int k = k0 + ki;
    int c = k >> 8, dx = (k >> 4) & 15, dy = k & 15;
    float4 av = *(const float4*)(X + (((size_t)(bb * 3 + c) * 256 + px * 16 + dx) * 256 + py * 16 + dy));
    float4 bv = *(const float4*)(B + (size_t)(n0 + li) * 768 + k);
    As[ki + 0][li] = av.x; As[ki + 1][li] = av.y; As[ki + 2][li] = av.z; As[ki + 3][li] = av.w;
    Bs[ki + 0][li] = bv.x; Bs[ki + 1][li] = bv.y; Bs[ki + 2][li] = bv.z; Bs[ki + 3][li] = bv.w;
    __syncthreads();
#pragma unroll
    for (int kk = 0; kk < 16; ++kk) {
      float4 a = *(const float4*)&As[kk][ty * 4];
      float4 b4 = *(const float4*)&Bs[kk][tx * 4];
      acc[0][0] += a.x * b4.x; acc[0][1] += a.x * b4.y; acc[0][2] += a.x * b4.z; acc[0][3] += a.x * b4.w;
      acc[1][0] += a.y * b4.x; acc[1][1] += a.y * b4.y; acc[1][2] += a.y * b4.z; acc[1][3] += a.y * b4.w;
      acc[2][0] += a.z * b4.x; acc[2][1] += a.z * b4.y; acc[2][2] += a.z * b4.z; acc[2][3] += a.z * b4.w;
      acc[3][0] += a.w * b4.x; acc[3][1] += a.w * b4.y; acc[3][2] += a.w * b4.z; acc[3][3] += a.w * b4.w;
    }
    __syncthreads();
  }
#pragma unroll
  for (int i = 0; i < 4; ++i) {
    int mm = m0 + ty * 4 + i;
#pragma unroll
    for (int j = 0; j < 4; ++j) {
      int n = n0 + tx * 4 + j;
      C[(size_t)mm * 128 + n] = acc[i][j] + bias[n];
    }
  }
}

// ---------------- LayerNorm over E=128, wave per token ----------------
__global__ __launch_bounds__(256) void ln_kernel(const float* in, float* out,
                                                 const float* __restrict__ w, const float* __restrict__ b) {
  int wid = threadIdx.x >> 6, lane = threadIdx.x & 63;
  size_t token = (size_t)blockIdx.x * 4 + wid;
  const float* p = in + token * 128;
  float2 v = *(const float2*)(p + lane * 2);
  float s = v.x + v.y;
#pragma unroll
  for (int off = 1; off < 64; off <<= 1) s += __shfl_xor(s, off);
  float mu = s * (1.f / 128.f);
  float dx = v.x - mu, dy = v.y - mu;
  float vs = dx * dx + dy * dy;
#pragma unroll
  for (int off = 1; off < 64; off <<= 1) vs += __shfl_xor(vs, off);
  float r = rsqrtf(vs * (1.f / 128.f) + EPSF);
  float2 o;
  o.x = dx * r * w[lane * 2 + 0] + b[lane * 2 + 0];
  o.y = dy * r * w[lane * 2 + 1] + b[lane * 2 + 1];
  *(float2*)(out + token * 128 + lane * 2) = o;
}

// ---------------- causal conv1d (DC=4) + SiLU over xbc channels ----------------
__global__ __launch_bounds__(256) void conv_silu_kernel(
    const float* __restrict__ zx, const float* __restrict__ cw,
    const float* __restrict__ cb, float* __restrict__ xbc) {
  int gid = blockIdx.x * 256 + threadIdx.x;  // T*96
  int token = gid / 96;
  int c4 = (gid - token * 96) * 4;
  int l = token & 255;
  const float* base = zx + (size_t)token * DIN + DI + c4;
  float4 z4 = make_float4(0.f, 0.f, 0.f, 0.f);
  float4 v0 = (l >= 3) ? *(const float4*)(base - 3 * DIN) : z4;
  float4 v1 = (l >= 2) ? *(const float4*)(base - 2 * DIN) : z4;
  float4 v2 = (l >= 1) ? *(const float4*)(base - 1 * DIN) : z4;
  float4 v3 = *(const float4*)(base);
  float4 w0 = *(const float4*)(cw + (c4 + 0) * 4);
  float4 w1 = *(const float4*)(cw + (c4 + 1) * 4);
  float4 w2 = *(const float4*)(cw + (c4 + 2) * 4);
  float4 w3 = *(const float4*)(cw + (c4 + 3) * 4);
  float4 cbv = *(const float4*)(cb + c4);
  float s0 = cbv.x + w0.x * v0.x + w0.y * v1.x + w0.z * v2.x + w0.w * v3.x;
  float s1 = cbv.y + w1.x * v0.y + w1.y * v1.y + w1.z * v2.y + w1.w * v3.y;
  float s2 = cbv.z + w2.x * v0.z + w2.y * v1.z + w2.z * v2.z + w2.w * v3.z;
  float s3 = cbv.w + w3.x * v0.w + w3.y * v1.w + w3.z * v2.w + w3.w * v3.w;
  s0 = s0 / (1.f + expf(-s0));
  s1 = s1 / (1.f + expf(-s1));
  s2 = s2 / (1.f + expf(-s2));
  s3 = s3 / (1.f + expf(-s3));
  *(float4*)(xbc + (size_t)token * XBC + c4) = make_float4(s0, s1, s2, s3);
}

// ---------------- dt = softplus(raw + bias), dA = exp(dt * -exp(A_log)) ----------------
__global__ __launch_bounds__(256) void dt_kernel(
    const float* __restrict__ zx, const float* __restrict__ dtb,
    const float* __restrict__ A_log, float* __restrict__ dtv, float* __restrict__ dAv) {
  int gid = blockIdx.x * 256 + threadIdx.x;  // T*8
  int token = gid >> 3, h = gid & 7;
  float raw = zx[(size_t)token * DIN + (DI + XBC) + h] + dtb[h];
  float dt = raw > 20.f ? raw : log1pf(expf(raw));
  dtv[gid] = dt;
  dAv[gid] = expf(-expf(A_log[h]) * dt);
}

// ---------------- sequential SSM scan ----------------
// grid = B*2 blocks, 512 threads (8 waves). Block handles 4 heads of one b.
// wave pair per head; lane owns (p in 16-range, n-quarter of 16) -> 16 state regs.
__global__ __launch_bounds__(512) void scan_kernel(
    const float* __restrict__ xbc, const float* __restrict__ dtv,
    const float* __restrict__ dAv, const float* __restrict__ Dp,
    float* __restrict__ y) {
  const int b = blockIdx.x >> 1;
  const int hgrp = (blockIdx.x & 1) * 4;
  const int tid = threadIdx.x;
  const int wid = tid >> 6, lane = tid & 63;
  const int hh = wid >> 1;                 // local head 0..3
  const int head = hgrp + hh;
  const int p = (wid & 1) * 16 + (lane & 15);
  const int nq = lane >> 4;                // n-quarter 0..3
  __shared__ float st[3][264];
  float hs[16];
#pragma unroll
  for (int j = 0; j < 16; ++j) hs[j] = 0.f;
  const float dp = Dp[head];

  // stage token l into buffer q
#define STAGE(l, q)                                                                  \
  {                                                                                  \
    int tok_ = b * 256 + (l);                                                        \
    const float* base_ = xbc + (size_t)tok_ * XBC;                                   \
    if (tid < 64) st[q][tid] = base_[256 + tid];                                     \
    else if (tid < 128) st[q][tid] = base_[320 + (tid - 64)];                        \
    else if (tid < 256) st[q][tid] = base_[hgrp * 32 + (tid - 128)];                 \
    else if (tid < 260) st[q][256 + (tid - 256)] = dAv[tok_ * 8 + hgrp + (tid - 256)]; \
    else if (tid < 264) st[q][260 + (tid - 260)] = dtv[tok_ * 8 + hgrp + (tid - 260)]; \
  }

  STAGE(0, 0);
  __syncthreads();
  for (int l = 0; l < 256; ++l) {
    int q = l % 3;
    if (l + 1 < 256) { int q2 = (l + 1) % 3; STAGE(l + 1, q2); }
    __syncthreads();
    const float* s = st[q];
    float dA = s[256 + hh];
    float dtt = s[260 + hh];
    float xv = s[128 + hh * 32 + p];
    float coef = dtt * xv;
    float yp = 0.f;
    const float* Bp = s + nq * 16;
    const float* Cp = s + 64 + nq * 16;
#pragma unroll
    for (int j = 0; j < 16; ++j) {
      hs[j] = dA * hs[j] + coef * Bp[j];
      yp += hs[j] * Cp[j];
    }
    yp += __shfl_xor(yp, 16);
    yp += __shfl_xor(yp, 32);
    if (nq == 0) {
      int tok = b * 256 + l;
      y[(size_t)tok * DI + head * 32 + p] = yp + dp * xv;
    }
  }
#undef STAGE
}

// ---------------- y = rmsnorm(y * silu(z)) * nw  (in-place on y) ----------------
__global__ __launch_bounds__(256) void gate_rms_kernel(
    float* y, const float* __restrict__ zx, const float* __restrict__ nw) {
  int wid = threadIdx.x >> 6, lane = threadIdx.x & 63;
  size_t token = (size_t)blockIdx.x * 4 + wid;
  float4 yv = *(const float4*)(y + token * DI + lane * 4);
  float4 zv = *(const float4*)(zx + token * DIN + lane * 4);
  float g0 = yv.x * (zv.x / (1.f + expf(-zv.x)));
  float g1 = yv.y * (zv.y / (1.f + expf(-zv.y)));
  float g2 = yv.z * (zv.z / (1.f + expf(-zv.z)));
  float g3 = yv.w * (zv.w / (1.f + expf(-zv.w)));
  float ss = g0 * g0 + g1 * g1 + g2 * g2 + g3 * g3;
#pragma unroll
  for (int off = 1; off < 64; off <<= 1) ss += __shfl_xor(ss, off);
  float r = rsqrtf(ss * (1.f / 256.f) + EPSF);
  float4 o;
  o.x = g0 * r * nw[lane * 4 + 0];
  o.y = g1 * r * nw[lane * 4 + 1];
  o.z = g2 * r * nw[lane * 4 + 2];
  o.w = g3 * r * nw[lane * 4 + 3];
  *(float4*)(y + token * DI + lane * 4) = o;
}

// ---------------- column mean over L ----------------
__global__ __launch_bounds__(128) void colmean_kernel(const float* __restrict__ tn, float* __restrict__ tmean) {
  int b = blockIdx.x, e = threadIdx.x;
  const float* p = tn + (size_t)b * 256 * 128 + e;
  float acc = 0.f;
  for (int l = 0; l < 256; ++l) acc += p[l * 128];
  tmean[b * 128 + e] = acc * (1.f / 256.f);
}

// ---------------- head matmul + L2 normalize ----------------
__global__ __launch_bounds__(128) void head_kernel(
    const float* __restrict__ tmean, const float* __restrict__ hw,
    const float* __restrict__ hb, float* __restrict__ out) {
  __shared__ float tm[128];
  __shared__ float red[2];
  int b = blockIdx.x, o = threadIdx.x;
  tm[o] = tmean[b * 128 + o];
  __syncthreads();
  float acc = hb[o];
  for (int e = 0; e < 128; ++e) acc += tm[e] * hw[o * 128 + e];
  float ss = acc * acc;
#pragma unroll
  for (int off = 1; off < 64; off <<= 1) ss += __shfl_xor(ss, off);
  if ((o & 63) == 0) red[o >> 6] = ss;
  __syncthreads();
  float nrm = fmaxf(sqrtf(red[0] + red[1]), 1e-12f);
  out[b * 128 + o] = acc / nrm;
}

extern "C" void kernel_launch(void* const* d_in, const int* in_sizes, int n_in,
                              void* d_out, int out_size, void* d_ws, size_t ws_size,
                              hipStream_t stream) {
  const float* x      = (const float*)d_in[0];
  const float* conv_w = (const float*)d_in[1];
  const float* conv_b = (const float*)d_in[2];
  const float* pe_w   = (const float*)d_in[3];
  const float* pe_b   = (const float*)d_in[4];
  const float* ln_w   = (const float*)d_in[5];
  const float* ln_b   = (const float*)d_in[6];
  const float* in_w   = (const float*)d_in[7];
  const float* c1w    = (const float*)d_in[8];
  const float* c1b    = (const float*)d_in[9];
  const float* dtb    = (const float*)d_in[10];
  const float* A_log  = (const float*)d_in[11];
  const float* Dp     = (const float*)d_in[12];
  const float* nw     = (const float*)d_in[13];
  const float* ow     = (const float*)d_in[14];
  const float* fn_w   = (const float*)d_in[15];
  const float* fn_b   = (const float*)d_in[16];
  const float* hw     = (const float*)d_in[17];
  const float* hb     = (const float*)d_in[18];
  float* out = (float*)d_out;
  float* ws = (float*)d_ws;

  const size_t T = TTOK;
  float* t_buf = ws;
  float* tn    = t_buf + T * 128;
  float* zx    = tn + T * 128;
  float* xbc   = zx + T * DIN;
  float* dtv   = xbc + T * XBC;
  float* dAv   = dtv + T * 8;
  float* ybuf  = dAv + T * 8;
  float* tmean = ybuf + T * DI;
  size_t need = (T * (size_t)(128 * 2 + DIN + XBC + 8 + 8 + DI) + 256 * 128) * sizeof(float);
  if (ws_size < need) return;  // workspace too small -> fail visibly

  // patch embed + bias, then pe layernorm (in place)
  gemm_patch_kernel<<<dim3(1024, 2), 256, 0, stream>>>(x, conv_w, conv_b, t_buf);
  ln_kernel<<<16384, 256, 0, stream>>>(t_buf, t_buf, pe_w, pe_b);

  for (int i = 0; i < NL; ++i) {
    ln_kernel<<<16384, 256, 0, stream>>>(t_buf, tn, ln_w + i * 128, ln_b + i * 128);
    gemm_nt_kernel<<<dim3(1024, 11), 256, 0, stream>>>(
        tn, in_w + (size_t)i * DIN * EE, zx, nullptr, nullptr, TTOK, DIN, EE);
    conv_silu_kernel<<<24576, 256, 0, stream>>>(zx, c1w + (size_t)i * XBC * DC, c1b + (size_t)i * XBC, xbc);
    dt_kernel<<<2048, 256, 0, stream>>>(zx, dtb + i * HH, A_log + i * HH, dtv, dAv);
    scan_kernel<<<512, 512, 0, stream>>>(xbc, dtv, dAv, Dp + i * HH, ybuf);
    gate_rms_kernel<<<16384, 256, 0, stream>>>(ybuf, zx, nw + i * DI);
    gemm_nt_kernel<<<dim3(1024, 2), 256, 0, stream>>>(
        ybuf, ow + (size_t)i * EE * DI, t_buf, t_buf, nullptr, TTOK, EE, DI);
  }

  ln_kernel<<<16384, 256, 0, stream>>>(t_buf, tn, fn_w, fn_b);
  colmean_kernel<<<256, 128, 0, stream>>>(tn, tmean);
  head_kernel<<<256, 128, 0, stream>>>(tmean, hw, hb, out);
}

// Round 2
// 1981.708 us; speedup vs baseline: 1.3150x; 1.3150x over previous
//
#include <hip/hip_runtime.h>
#include <math.h>

// ---------------- constants ----------------
#define EE 128
#define DI 256
#define HH 8
#define PP 32
#define NN 64
#define DC 4
#define XBC 384
#define DIN 648
#define NL 4
#define LSEQ 256
#define BB 256
#define TTOK (BB * LSEQ)   // 65536 tokens
#define EPSF 1e-5f

typedef __attribute__((ext_vector_type(8))) short short8;
typedef __attribute__((ext_vector_type(4))) float f32x4;

__device__ inline short f2bf(float f) {
  unsigned u = __builtin_bit_cast(unsigned, f);
  u += 0x7fff + ((u >> 16) & 1);   // RNE
  return (short)(u >> 16);
}

// ---------------- bf16 MFMA GEMM: C[M][N] = A[M][K] * B[N][K]^T (+bias)(+resid) ----------------
// 128x128 tile, 256 threads (4 waves 2x2), each wave 64x64 (4x4 frags of 16x16x32).
// A,B loaded fp32 from global, converted to bf16 in regs, staged to LDS.
// K multiple of 32, M multiple of 128, N guarded.
__global__ __launch_bounds__(256) void gemm_bf16_nt(
    const float* __restrict__ A, const float* __restrict__ B,
    float* C, const float* resid, const float* __restrict__ bias,
    int M, int N, int K) {
  __shared__ short As[128][40];
  __shared__ short Bs[128][40];
  const int tid = threadIdx.x;
  const int lane = tid & 63, wid = tid >> 6;
  const int wm = wid >> 1, wn = wid & 1;
  const int m0 = blockIdx.x * 128, n0 = blockIdx.y * 128;
  const int r = tid >> 1, hf = tid & 1;       // staging: row 0..127, k-half
  const int lr = lane & 15, lk = (lane >> 4) * 8;
  f32x4 acc[4][4] = {};
  for (int k0 = 0; k0 < K; k0 += 32) {
    // stage A
    {
      const float* ap = A + (size_t)(m0 + r) * K + k0 + hf * 16;
      float4 v0 = *(const float4*)(ap + 0);
      float4 v1 = *(const float4*)(ap + 4);
      float4 v2 = *(const float4*)(ap + 8);
      float4 v3 = *(const float4*)(ap + 12);
      short8 s0, s1;
      s0[0] = f2bf(v0.x); s0[1] = f2bf(v0.y); s0[2] = f2bf(v0.z); s0[3] = f2bf(v0.w);
      s0[4] = f2bf(v1.x); s0[5] = f2bf(v1.y); s0[6] = f2bf(v1.z); s0[7] = f2bf(v1.w);
      s1[0] = f2bf(v2.x); s1[1] = f2bf(v2.y); s1[2] = f2bf(v2.z); s1[3] = f2bf(v2.w);
      s1[4] = f2bf(v3.x); s1[5] = f2bf(v3.y); s1[6] = f2bf(v3.z); s1[7] = f2bf(v3.w);
      *(short8*)&As[r][hf * 16] = s0;
      *(short8*)&As[r][hf * 16 + 8] = s1;
    }
    // stage B (guarded)
    {
      short8 s0 = {}, s1 = {};
      if (n0 + r < N) {
        const float* bp = B + (size_t)(n0 + r) * K + k0 + hf * 16;
        float4 v0 = *(const float4*)(bp + 0);
        float4 v1 = *(const float4*)(bp + 4);
        float4 v2 = *(const float4*)(bp + 8);
        float4 v3 = *(const float4*)(bp + 12);
        s0[0] = f2bf(v0.x); s0[1] = f2bf(v0.y); s0[2] = f2bf(v0.z); s0[3] = f2bf(v0.w);
        s0[4] = f2bf(v1.x); s0[5] = f2bf(v1.y); s0[6] = f2bf(v1.z); s0[7] = f2bf(v1.w);
        s1[0] = f2bf(v2.x); s1[1] = f2bf(v2.y); s1[2] = f2bf(v2.z); s1[3] = f2bf(v2.w);
        s1[4] = f2bf(v3.x); s1[5] = f2bf(v3.y); s1[6] = f2bf(v3.z); s1[7] = f2bf(v3.w);
      }
      *(short8*)&Bs[r][hf * 16] = s0;
      *(short8*)&Bs[r][hf * 16 + 8] = s1;
    }
    __syncthreads();
    short8 af[4], bfr[4];
#pragma unroll
    for (int mi = 0; mi < 4; ++mi) af[mi] = *(const short8*)&As[wm * 64 + mi * 16 + lr][lk];
#pragma unroll
    for (int ni = 0; ni < 4; ++ni) bfr[ni] = *(const short8*)&Bs[wn * 64 + ni * 16 + lr][lk];
#pragma unroll
    for (int mi = 0; mi < 4; ++mi)
#pragma unroll
      for (int ni = 0; ni < 4; ++ni)
        acc[mi][ni] = __builtin_amdgcn_mfma_f32_16x16x32_bf16(af[mi], bfr[ni], acc[mi][ni], 0, 0, 0);
    __syncthreads();
  }
#pragma unroll
  for (int mi = 0; mi < 4; ++mi) {
#pragma unroll
    for (int ni = 0; ni < 4; ++ni) {
      int row0 = m0 + wm * 64 + mi * 16 + (lane >> 4) * 4;
      int col = n0 + wn * 64 + ni * 16 + (lane & 15);
      if (col < N) {
        float bv = bias ? bias[col] : 0.f;
#pragma unroll
        for (int j = 0; j < 4; ++j) {
          size_t idx = (size_t)(row0 + j) * N + col;
          float v = acc[mi][ni][j] + bv;
          if (resid) v += resid[idx];
          C[idx] = v;
        }
      }
    }
  }
}

// ---------------- patch-embed bf16 MFMA GEMM ----------------
// M=65536 tokens, N=128 (E), K=768 (c*256 + dx*16 + dy); A is im2col of X on the fly.
__global__ __launch_bounds__(256) void gemm_bf16_patch(
    const float* __restrict__ X, const float* __restrict__ B,
    const float* __restrict__ bias, float* __restrict__ C) {
  __shared__ short As[128][40];
  __shared__ short Bs[128][40];
  const int tid = threadIdx.x;
  const int lane = tid & 63, wid = tid >> 6;
  const int wm = wid >> 1, wn = wid & 1;
  const int m0 = blockIdx.x * 128;
  const int r = tid >> 1, hf = tid & 1;
  const int lr = lane & 15, lk = (lane >> 4) * 8;
  const int m = m0 + r;
  const int bb = m >> 8, px = (m >> 4) & 15, py = m & 15;
  f32x4 acc[4][4] = {};
  for (int k0 = 0; k0 < 768; k0 += 32) {
    int k = k0 + hf * 16;
    int c = k >> 8, dx = (k >> 4) & 15;
    {
      const float* ap = X + (((size_t)(bb * 3 + c) * 256 + px * 16 + dx) * 256 + py * 16);
      float4 v0 = *(const float4*)(ap + 0);
      float4 v1 = *(const float4*)(ap + 4);
      float4 v2 = *(const float4*)(ap + 8);
      float4 v3 = *(const float4*)(ap + 12);
      short8 s0, s1;
      s0[0] = f2bf(v0.x); s0[1] = f2bf(v0.y); s0[2] = f2bf(v0.z); s0[3] = f2bf(v0.w);
      s0[4] = f2bf(v1.x); s0[5] = f2bf(v1.y); s0[6] = f2bf(v1.z); s0[7] = f2bf(v1.w);
      s1[0] = f2bf(v2.x); s1[1] = f2bf(v2.y); s1[2] = f2bf(v2.z); s1[3] = f2bf(v2.w);
      s1[4] = f2bf(v3.x); s1[5] = f2bf(v3.y); s1[6] = f2bf(v3.z); s1[7] = f2bf(v3.w);
      *(short8*)&As[r][hf * 16] = s0;
      *(short8*)&As[r][hf * 16 + 8] = s1;
    }
    {
      const float* bp = B + (size_t)r * 768 + k;
      float4 v0 = *(const float4*)(bp + 0);
      float4 v1 = *(const float4*)(bp + 4);
      float4 v2 = *(const float4*)(bp + 8);
      float4 v3 = *(const float4*)(bp + 12);
      short8 s0, s1;
      s0[0] = f2bf(v0.x); s0[1] = f2bf(v0.y); s0[2] = f2bf(v0.z); s0[3] = f2bf(v0.w);
      s0[4] = f2bf(v1.x); s0[5] = f2bf(v1.y); s0[6] = f2bf(v1.z); s0[7] = f2bf(v1.w);
      s1[0] = f2bf(v2.x); s1[1] = f2bf(v2.y); s1[2] = f2bf(v2.z); s1[3] = f2bf(v2.w);
      s1[4] = f2bf(v3.x); s1[5] = f2bf(v3.y); s1[6] = f2bf(v3.z); s1[7] = f2bf(v3.w);
      *(short8*)&Bs[r][hf * 16] = s0;
      *(short8*)&Bs[r][hf * 16 + 8] = s1;
    }
    __syncthreads();
    short8 af[4], bfr[4];
#pragma unroll
    for (int mi = 0; mi < 4; ++mi) af[mi] = *(const short8*)&As[wm * 64 + mi * 16 + lr][lk];
#pragma unroll
    for (int ni = 0; ni < 4; ++ni) bfr[ni] = *(const short8*)&Bs[wn * 64 + ni * 16 + lr][lk];
#pragma unroll
    for (int mi = 0; mi < 4; ++mi)
#pragma unroll
      for (int ni = 0; ni < 4; ++ni)
        acc[mi][ni] = __builtin_amdgcn_mfma_f32_16x16x32_bf16(af[mi], bfr[ni], acc[mi][ni], 0, 0, 0);
    __syncthreads();
  }
#pragma unroll
  for (int mi = 0; mi < 4; ++mi) {
#pragma unroll
    for (int ni = 0; ni < 4; ++ni) {
      int row0 = m0 + wm * 64 + mi * 16 + (lane >> 4) * 4;
      int col = wn * 64 + ni * 16 + (lane & 15);
#pragma unroll
      for (int j = 0; j < 4; ++j)
        C[(size_t)(row0 + j) * 128 + col] = acc[mi][ni][j] + bias[col];
    }
  }
}

// ---------------- LayerNorm over E=128, wave per token ----------------
__global__ __launch_bounds__(256) void ln_kernel(const float* in, float* out,
                                                 const float* __restrict__ w, const float* __restrict__ b) {
  int wid = threadIdx.x >> 6, lane = threadIdx.x & 63;
  size_t token = (size_t)blockIdx.x * 4 + wid;
  const float* p = in + token * 128;
  float2 v = *(const float2*)(p + lane * 2);
  float s = v.x + v.y;
#pragma unroll
  for (int off = 1; off < 64; off <<= 1) s += __shfl_xor(s, off);
  float mu = s * (1.f / 128.f);
  float dx = v.x - mu, dy = v.y - mu;
  float vs = dx * dx + dy * dy;
#pragma unroll
  for (int off = 1; off < 64; off <<= 1) vs += __shfl_xor(vs, off);
  float r = rsqrtf(vs * (1.f / 128.f) + EPSF);
  float2 o;
  o.x = dx * r * w[lane * 2 + 0] + b[lane * 2 + 0];
  o.y = dy * r * w[lane * 2 + 1] + b[lane * 2 + 1];
  *(float2*)(out + token * 128 + lane * 2) = o;
}

// ---------------- causal conv1d (DC=4) + SiLU over xbc channels ----------------
__global__ __launch_bounds__(256) void conv_silu_kernel(
    const float* __restrict__ zx, const float* __restrict__ cw,
    const float* __restrict__ cb, float* __restrict__ xbc) {
  int gid = blockIdx.x * 256 + threadIdx.x;  // T*96
  int token = gid / 96;
  int c4 = (gid - token * 96) * 4;
  int l = token & 255;
  const float* base = zx + (size_t)token * DIN + DI + c4;
  float4 z4 = make_float4(0.f, 0.f, 0.f, 0.f);
  float4 v0 = (l >= 3) ? *(const float4*)(base - 3 * DIN) : z4;
  float4 v1 = (l >= 2) ? *(const float4*)(base - 2 * DIN) : z4;
  float4 v2 = (l >= 1) ? *(const float4*)(base - 1 * DIN) : z4;
  float4 v3 = *(const float4*)(base);
  float4 w0 = *(const float4*)(cw + (c4 + 0) * 4);
  float4 w1 = *(const float4*)(cw + (c4 + 1) * 4);
  float4 w2 = *(const float4*)(cw + (c4 + 2) * 4);
  float4 w3 = *(const float4*)(cw + (c4 + 3) * 4);
  float4 cbv = *(const float4*)(cb + c4);
  float s0 = cbv.x + w0.x * v0.x + w0.y * v1.x + w0.z * v2.x + w0.w * v3.x;
  float s1 = cbv.y + w1.x * v0.y + w1.y * v1.y + w1.z * v2.y + w1.w * v3.y;
  float s2 = cbv.z + w2.x * v0.z + w2.y * v1.z + w2.z * v2.z + w2.w * v3.z;
  float s3 = cbv.w + w3.x * v0.w + w3.y * v1.w + w3.z * v2.w + w3.w * v3.w;
  s0 = s0 / (1.f + expf(-s0));
  s1 = s1 / (1.f + expf(-s1));
  s2 = s2 / (1.f + expf(-s2));
  s3 = s3 / (1.f + expf(-s3));
  *(float4*)(xbc + (size_t)token * XBC + c4) = make_float4(s0, s1, s2, s3);
}

// ---------------- dt = softplus(raw + bias), dA = exp(dt * -exp(A_log)) ----------------
__global__ __launch_bounds__(256) void dt_kernel(
    const float* __restrict__ zx, const float* __restrict__ dtb,
    const float* __restrict__ A_log, float* __restrict__ dtv, float* __restrict__ dAv) {
  int gid = blockIdx.x * 256 + threadIdx.x;  // T*8
  int token = gid >> 3, h = gid & 7;
  float raw = zx[(size_t)token * DIN + (DI + XBC) + h] + dtb[h];
  float dt = raw > 20.f ? raw : log1pf(expf(raw));
  dtv[gid] = dt;
  dAv[gid] = expf(-expf(A_log[h]) * dt);
}

// ---------------- sequential SSM scan ----------------
__global__ __launch_bounds__(512) void scan_kernel(
    const float* __restrict__ xbc, const float* __restrict__ dtv,
    const float* __restrict__ dAv, const float* __restrict__ Dp,
    float* __restrict__ y) {
  const int b = blockIdx.x >> 1;
  const int hgrp = (blockIdx.x & 1) * 4;
  const int tid = threadIdx.x;
  const int wid = tid >> 6, lane = tid & 63;
  const int hh = wid >> 1;                 // local head 0..3
  const int head = hgrp + hh;
  const int p = (wid & 1) * 16 + (lane & 15);
  const int nq = lane >> 4;                // n-quarter 0..3
  __shared__ float st[3][264];
  float hs[16];
#pragma unroll
  for (int j = 0; j < 16; ++j) hs[j] = 0.f;
  const float dp = Dp[head];

#define STAGE(l, q)                                                                  \
  {                                                                                  \
    int tok_ = b * 256 + (l);                                                        \
    const float* base_ = xbc + (size_t)tok_ * XBC;                                   \
    if (tid < 64) st[q][tid] = base_[256 + tid];                                     \
    else if (tid < 128) st[q][tid] = base_[320 + (tid - 64)];                        \
    else if (tid < 256) st[q][tid] = base_[hgrp * 32 + (tid - 128)];                 \
    else if (tid < 260) st[q][256 + (tid - 256)] = dAv[tok_ * 8 + hgrp + (tid - 256)]; \
    else if (tid < 264) st[q][260 + (tid - 260)] = dtv[tok_ * 8 + hgrp + (tid - 260)]; \
  }

  STAGE(0, 0);
  __syncthreads();
  for (int l = 0; l < 256; ++l) {
    int q = l % 3;
    if (l + 1 < 256) { int q2 = (l + 1) % 3; STAGE(l + 1, q2); }
    __syncthreads();
    const float* s = st[q];
    float dA = s[256 + hh];
    float dtt = s[260 + hh];
    float xv = s[128 + hh * 32 + p];
    float coef = dtt * xv;
    float yp = 0.f;
    const float* Bp = s + nq * 16;
    const float* Cp = s + 64 + nq * 16;
#pragma unroll
    for (int j = 0; j < 16; ++j) {
      hs[j] = dA * hs[j] + coef * Bp[j];
      yp += hs[j] * Cp[j];
    }
    yp += __shfl_xor(yp, 16);
    yp += __shfl_xor(yp, 32);
    if (nq == 0) {
      int tok = b * 256 + l;
      y[(size_t)tok * DI + head * 32 + p] = yp + dp * xv;
    }
  }
#undef STAGE
}

// ---------------- y = rmsnorm(y * silu(z)) * nw  (in-place on y) ----------------
__global__ __launch_bounds__(256) void gate_rms_kernel(
    float* y, const float* __restrict__ zx, const float* __restrict__ nw) {
  int wid = threadIdx.x >> 6, lane = threadIdx.x & 63;
  size_t token = (size_t)blockIdx.x * 4 + wid;
  float4 yv = *(const float4*)(y + token * DI + lane * 4);
  float4 zv = *(const float4*)(zx + token * DIN + lane * 4);
  float g0 = yv.x * (zv.x / (1.f + expf(-zv.x)));
  float g1 = yv.y * (zv.y / (1.f + expf(-zv.y)));
  float g2 = yv.z * (zv.z / (1.f + expf(-zv.z)));
  float g3 = yv.w * (zv.w / (1.f + expf(-zv.w)));
  float ss = g0 * g0 + g1 * g1 + g2 * g2 + g3 * g3;
#pragma unroll
  for (int off = 1; off < 64; off <<= 1) ss += __shfl_xor(ss, off);
  float r = rsqrtf(ss * (1.f / 256.f) + EPSF);
  float4 o;
  o.x = g0 * r * nw[lane * 4 + 0];
  o.y = g1 * r * nw[lane * 4 + 1];
  o.z = g2 * r * nw[lane * 4 + 2];
  o.w = g3 * r * nw[lane * 4 + 3];
  *(float4*)(y + token * DI + lane * 4) = o;
}

// ---------------- column mean over L ----------------
__global__ __launch_bounds__(128) void colmean_kernel(const float* __restrict__ tn, float* __restrict__ tmean) {
  int b = blockIdx.x, e = threadIdx.x;
  const float* p = tn + (size_t)b * 256 * 128 + e;
  float acc = 0.f;
  for (int l = 0; l < 256; ++l) acc += p[l * 128];
  tmean[b * 128 + e] = acc * (1.f / 256.f);
}

// ---------------- head matmul + L2 normalize ----------------
__global__ __launch_bounds__(128) void head_kernel(
    const float* __restrict__ tmean, const float* __restrict__ hw,
    const float* __restrict__ hb, float* __restrict__ out) {
  __shared__ float tm[128];
  __shared__ float red[2];
  int b = blockIdx.x, o = threadIdx.x;
  tm[o] = tmean[b * 128 + o];
  __syncthreads();
  float acc = hb[o];
  for (int e = 0; e < 128; ++e) acc += tm[e] * hw[o * 128 + e];
  float ss = acc * acc;
#pragma unroll
  for (int off = 1; off < 64; off <<= 1) ss += __shfl_xor(ss, off);
  if ((o & 63) == 0) red[o >> 6] = ss;
  __syncthreads();
  float nrm = fmaxf(sqrtf(red[0] + red[1]), 1e-12f);
  out[b * 128 + o] = acc / nrm;
}

extern "C" void kernel_launch(void* const* d_in, const int* in_sizes, int n_in,
                              void* d_out, int out_size, void* d_ws, size_t ws_size,
                              hipStream_t stream) {
  const float* x      = (const float*)d_in[0];
  const float* conv_w = (const float*)d_in[1];
  const float* conv_b = (const float*)d_in[2];
  const float* pe_w   = (const float*)d_in[3];
  const float* pe_b   = (const float*)d_in[4];
  const float* ln_w   = (const float*)d_in[5];
  const float* ln_b   = (const float*)d_in[6];
  const float* in_w   = (const float*)d_in[7];
  const float* c1w    = (const float*)d_in[8];
  const float* c1b    = (const float*)d_in[9];
  const float* dtb    = (const float*)d_in[10];
  const float* A_log  = (const float*)d_in[11];
  const float* Dp     = (const float*)d_in[12];
  const float* nw     = (const float*)d_in[13];
  const float* ow     = (const float*)d_in[14];
  const float* fn_w   = (const float*)d_in[15];
  const float* fn_b   = (const float*)d_in[16];
  const float* hw     = (const float*)d_in[17];
  const float* hb     = (const float*)d_in[18];
  float* out = (float*)d_out;
  float* ws = (float*)d_ws;

  const size_t T = TTOK;
  float* t_buf = ws;
  float* tn    = t_buf + T * 128;
  float* zx    = tn + T * 128;
  float* xbc   = zx + T * DIN;
  float* dtv   = xbc + T * XBC;
  float* dAv   = dtv + T * 8;
  float* ybuf  = dAv + T * 8;
  float* tmean = ybuf + T * DI;
  size_t need = (T * (size_t)(128 * 2 + DIN + XBC + 8 + 8 + DI) + 256 * 128) * sizeof(float);
  if (ws_size < need) return;  // workspace too small -> fail visibly

  // patch embed + bias, then pe layernorm (in place)
  gemm_bf16_patch<<<dim3(512, 1), 256, 0, stream>>>(x, conv_w, conv_b, t_buf);
  ln_kernel<<<16384, 256, 0, stream>>>(t_buf, t_buf, pe_w, pe_b);

  for (int i = 0; i < NL; ++i) {
    ln_kernel<<<16384, 256, 0, stream>>>(t_buf, tn, ln_w + i * 128, ln_b + i * 128);
    gemm_bf16_nt<<<dim3(512, 6), 256, 0, stream>>>(
        tn, in_w + (size_t)i * DIN * EE, zx, nullptr, nullptr, TTOK, DIN, EE);
    conv_silu_kernel<<<24576, 256, 0, stream>>>(zx, c1w + (size_t)i * XBC * DC, c1b + (size_t)i * XBC, xbc);
    dt_kernel<<<2048, 256, 0, stream>>>(zx, dtb + i * HH, A_log + i * HH, dtv, dAv);
    scan_kernel<<<512, 512, 0, stream>>>(xbc, dtv, dAv, Dp + i * HH, ybuf);
    gate_rms_kernel<<<16384, 256, 0, stream>>>(ybuf, zx, nw + i * DI);
    gemm_bf16_nt<<<dim3(512, 2), 256, 0, stream>>>(
        ybuf, ow + (size_t)i * EE * DI, t_buf, t_buf, nullptr, TTOK, EE, DI);
  }

  ln_kernel<<<16384, 256, 0, stream>>>(t_buf, tn, fn_w, fn_b);
  colmean_kernel<<<256, 128, 0, stream>>>(tn, tmean);
  head_kernel<<<256, 128, 0, stream>>>(tmean, hw, hb, out);
}

// Round 3
// 1686.220 us; speedup vs baseline: 1.5454x; 1.1752x over previous
//
#include <hip/hip_runtime.h>
#include <math.h>

// ---------------- constants ----------------
#define EE 128
#define DI 256
#define HH 8
#define PP 32
#define NN 64
#define DC 4
#define XBC 384
#define DIN 648
#define NL 4
#define LSEQ 256
#define BB 256
#define TTOK (BB * LSEQ)   // 65536 tokens
#define EPSF 1e-5f

typedef __attribute__((ext_vector_type(8))) short short8;
typedef __attribute__((ext_vector_type(4))) float f32x4;

__device__ inline short f2bf(float f) {
  unsigned u = __builtin_bit_cast(unsigned, f);
  u += 0x7fff + ((u >> 16) & 1);   // RNE
  return (short)(u >> 16);
}

// ---------------- bf16 MFMA GEMM: C[M][N] = A[M][K] * B[N][K]^T (+bias)(+resid) ----------------
__global__ __launch_bounds__(256) void gemm_bf16_nt(
    const float* __restrict__ A, const float* __restrict__ B,
    float* C, const float* resid, const float* __restrict__ bias,
    int M, int N, int K) {
  __shared__ short As[128][40];
  __shared__ short Bs[128][40];
  const int tid = threadIdx.x;
  const int lane = tid & 63, wid = tid >> 6;
  const int wm = wid >> 1, wn = wid & 1;
  const int m0 = blockIdx.x * 128, n0 = blockIdx.y * 128;
  const int r = tid >> 1, hf = tid & 1;       // staging: row 0..127, k-half
  const int lr = lane & 15, lk = (lane >> 4) * 8;
  f32x4 acc[4][4] = {};
  for (int k0 = 0; k0 < K; k0 += 32) {
    // stage A
    {
      const float* ap = A + (size_t)(m0 + r) * K + k0 + hf * 16;
      float4 v0 = *(const float4*)(ap + 0);
      float4 v1 = *(const float4*)(ap + 4);
      float4 v2 = *(const float4*)(ap + 8);
      float4 v3 = *(const float4*)(ap + 12);
      short8 s0, s1;
      s0[0] = f2bf(v0.x); s0[1] = f2bf(v0.y); s0[2] = f2bf(v0.z); s0[3] = f2bf(v0.w);
      s0[4] = f2bf(v1.x); s0[5] = f2bf(v1.y); s0[6] = f2bf(v1.z); s0[7] = f2bf(v1.w);
      s1[0] = f2bf(v2.x); s1[1] = f2bf(v2.y); s1[2] = f2bf(v2.z); s1[3] = f2bf(v2.w);
      s1[4] = f2bf(v3.x); s1[5] = f2bf(v3.y); s1[6] = f2bf(v3.z); s1[7] = f2bf(v3.w);
      *(short8*)&As[r][hf * 16] = s0;
      *(short8*)&As[r][hf * 16 + 8] = s1;
    }
    // stage B (guarded)
    {
      short8 s0 = {}, s1 = {};
      if (n0 + r < N) {
        const float* bp = B + (size_t)(n0 + r) * K + k0 + hf * 16;
        float4 v0 = *(const float4*)(bp + 0);
        float4 v1 = *(const float4*)(bp + 4);
        float4 v2 = *(const float4*)(bp + 8);
        float4 v3 = *(const float4*)(bp + 12);
        s0[0] = f2bf(v0.x); s0[1] = f2bf(v0.y); s0[2] = f2bf(v0.z); s0[3] = f2bf(v0.w);
        s0[4] = f2bf(v1.x); s0[5] = f2bf(v1.y); s0[6] = f2bf(v1.z); s0[7] = f2bf(v1.w);
        s1[0] = f2bf(v2.x); s1[1] = f2bf(v2.y); s1[2] = f2bf(v2.z); s1[3] = f2bf(v2.w);
        s1[4] = f2bf(v3.x); s1[5] = f2bf(v3.y); s1[6] = f2bf(v3.z); s1[7] = f2bf(v3.w);
      }
      *(short8*)&Bs[r][hf * 16] = s0;
      *(short8*)&Bs[r][hf * 16 + 8] = s1;
    }
    __syncthreads();
    short8 af[4], bfr[4];
#pragma unroll
    for (int mi = 0; mi < 4; ++mi) af[mi] = *(const short8*)&As[wm * 64 + mi * 16 + lr][lk];
#pragma unroll
    for (int ni = 0; ni < 4; ++ni) bfr[ni] = *(const short8*)&Bs[wn * 64 + ni * 16 + lr][lk];
#pragma unroll
    for (int mi = 0; mi < 4; ++mi)
#pragma unroll
      for (int ni = 0; ni < 4; ++ni)
        acc[mi][ni] = __builtin_amdgcn_mfma_f32_16x16x32_bf16(af[mi], bfr[ni], acc[mi][ni], 0, 0, 0);
    __syncthreads();
  }
#pragma unroll
  for (int mi = 0; mi < 4; ++mi) {
#pragma unroll
    for (int ni = 0; ni < 4; ++ni) {
      int row0 = m0 + wm * 64 + mi * 16 + (lane >> 4) * 4;
      int col = n0 + wn * 64 + ni * 16 + (lane & 15);
      if (col < N) {
        float bv = bias ? bias[col] : 0.f;
#pragma unroll
        for (int j = 0; j < 4; ++j) {
          size_t idx = (size_t)(row0 + j) * N + col;
          float v = acc[mi][ni][j] + bv;
          if (resid) v += resid[idx];
          C[idx] = v;
        }
      }
    }
  }
}

// ---------------- patch-embed bf16 MFMA GEMM ----------------
__global__ __launch_bounds__(256) void gemm_bf16_patch(
    const float* __restrict__ X, const float* __restrict__ B,
    const float* __restrict__ bias, float* __restrict__ C) {
  __shared__ short As[128][40];
  __shared__ short Bs[128][40];
  const int tid = threadIdx.x;
  const int lane = tid & 63, wid = tid >> 6;
  const int wm = wid >> 1, wn = wid & 1;
  const int m0 = blockIdx.x * 128;
  const int r = tid >> 1, hf = tid & 1;
  const int lr = lane & 15, lk = (lane >> 4) * 8;
  const int m = m0 + r;
  const int bb = m >> 8, px = (m >> 4) & 15, py = m & 15;
  f32x4 acc[4][4] = {};
  for (int k0 = 0; k0 < 768; k0 += 32) {
    int k = k0 + hf * 16;
    int c = k >> 8, dx = (k >> 4) & 15;
    {
      const float* ap = X + (((size_t)(bb * 3 + c) * 256 + px * 16 + dx) * 256 + py * 16);
      float4 v0 = *(const float4*)(ap + 0);
      float4 v1 = *(const float4*)(ap + 4);
      float4 v2 = *(const float4*)(ap + 8);
      float4 v3 = *(const float4*)(ap + 12);
      short8 s0, s1;
      s0[0] = f2bf(v0.x); s0[1] = f2bf(v0.y); s0[2] = f2bf(v0.z); s0[3] = f2bf(v0.w);
      s0[4] = f2bf(v1.x); s0[5] = f2bf(v1.y); s0[6] = f2bf(v1.z); s0[7] = f2bf(v1.w);
      s1[0] = f2bf(v2.x); s1[1] = f2bf(v2.y); s1[2] = f2bf(v2.z); s1[3] = f2bf(v2.w);
      s1[4] = f2bf(v3.x); s1[5] = f2bf(v3.y); s1[6] = f2bf(v3.z); s1[7] = f2bf(v3.w);
      *(short8*)&As[r][hf * 16] = s0;
      *(short8*)&As[r][hf * 16 + 8] = s1;
    }
    {
      const float* bp = B + (size_t)r * 768 + k;
      float4 v0 = *(const float4*)(bp + 0);
      float4 v1 = *(const float4*)(bp + 4);
      float4 v2 = *(const float4*)(bp + 8);
      float4 v3 = *(const float4*)(bp + 12);
      short8 s0, s1;
      s0[0] = f2bf(v0.x); s0[1] = f2bf(v0.y); s0[2] = f2bf(v0.z); s0[3] = f2bf(v0.w);
      s0[4] = f2bf(v1.x); s0[5] = f2bf(v1.y); s0[6] = f2bf(v1.z); s0[7] = f2bf(v1.w);
      s1[0] = f2bf(v2.x); s1[1] = f2bf(v2.y); s1[2] = f2bf(v2.z); s1[3] = f2bf(v2.w);
      s1[4] = f2bf(v3.x); s1[5] = f2bf(v3.y); s1[6] = f2bf(v3.z); s1[7] = f2bf(v3.w);
      *(short8*)&Bs[r][hf * 16] = s0;
      *(short8*)&Bs[r][hf * 16 + 8] = s1;
    }
    __syncthreads();
    short8 af[4], bfr[4];
#pragma unroll
    for (int mi = 0; mi < 4; ++mi) af[mi] = *(const short8*)&As[wm * 64 + mi * 16 + lr][lk];
#pragma unroll
    for (int ni = 0; ni < 4; ++ni) bfr[ni] = *(const short8*)&Bs[wn * 64 + ni * 16 + lr][lk];
#pragma unroll
    for (int mi = 0; mi < 4; ++mi)
#pragma unroll
      for (int ni = 0; ni < 4; ++ni)
        acc[mi][ni] = __builtin_amdgcn_mfma_f32_16x16x32_bf16(af[mi], bfr[ni], acc[mi][ni], 0, 0, 0);
    __syncthreads();
  }
#pragma unroll
  for (int mi = 0; mi < 4; ++mi) {
#pragma unroll
    for (int ni = 0; ni < 4; ++ni) {
      int row0 = m0 + wm * 64 + mi * 16 + (lane >> 4) * 4;
      int col = wn * 64 + ni * 16 + (lane & 15);
#pragma unroll
      for (int j = 0; j < 4; ++j)
        C[(size_t)(row0 + j) * 128 + col] = acc[mi][ni][j] + bias[col];
    }
  }
}

// ---------------- LayerNorm over E=128, wave per token ----------------
__global__ __launch_bounds__(256) void ln_kernel(const float* in, float* out,
                                                 const float* __restrict__ w, const float* __restrict__ b) {
  int wid = threadIdx.x >> 6, lane = threadIdx.x & 63;
  size_t token = (size_t)blockIdx.x * 4 + wid;
  const float* p = in + token * 128;
  float2 v = *(const float2*)(p + lane * 2);
  float s = v.x + v.y;
#pragma unroll
  for (int off = 1; off < 64; off <<= 1) s += __shfl_xor(s, off);
  float mu = s * (1.f / 128.f);
  float dx = v.x - mu, dy = v.y - mu;
  float vs = dx * dx + dy * dy;
#pragma unroll
  for (int off = 1; off < 64; off <<= 1) vs += __shfl_xor(vs, off);
  float r = rsqrtf(vs * (1.f / 128.f) + EPSF);
  float2 o;
  o.x = dx * r * w[lane * 2 + 0] + b[lane * 2 + 0];
  o.y = dy * r * w[lane * 2 + 1] + b[lane * 2 + 1];
  *(float2*)(out + token * 128 + lane * 2) = o;
}

// ---------------- causal conv1d (DC=4) + SiLU over xbc channels ----------------
__global__ __launch_bounds__(256) void conv_silu_kernel(
    const float* __restrict__ zx, const float* __restrict__ cw,
    const float* __restrict__ cb, float* __restrict__ xbc) {
  int gid = blockIdx.x * 256 + threadIdx.x;  // T*96
  int token = gid / 96;
  int c4 = (gid - token * 96) * 4;
  int l = token & 255;
  const float* base = zx + (size_t)token * DIN + DI + c4;
  float4 z4 = make_float4(0.f, 0.f, 0.f, 0.f);
  float4 v0 = (l >= 3) ? *(const float4*)(base - 3 * DIN) : z4;
  float4 v1 = (l >= 2) ? *(const float4*)(base - 2 * DIN) : z4;
  float4 v2 = (l >= 1) ? *(const float4*)(base - 1 * DIN) : z4;
  float4 v3 = *(const float4*)(base);
  float4 w0 = *(const float4*)(cw + (c4 + 0) * 4);
  float4 w1 = *(const float4*)(cw + (c4 + 1) * 4);
  float4 w2 = *(const float4*)(cw + (c4 + 2) * 4);
  float4 w3 = *(const float4*)(cw + (c4 + 3) * 4);
  float4 cbv = *(const float4*)(cb + c4);
  float s0 = cbv.x + w0.x * v0.x + w0.y * v1.x + w0.z * v2.x + w0.w * v3.x;
  float s1 = cbv.y + w1.x * v0.y + w1.y * v1.y + w1.z * v2.y + w1.w * v3.y;
  float s2 = cbv.z + w2.x * v0.z + w2.y * v1.z + w2.z * v2.z + w2.w * v3.z;
  float s3 = cbv.w + w3.x * v0.w + w3.y * v1.w + w3.z * v2.w + w3.w * v3.w;
  s0 = s0 / (1.f + expf(-s0));
  s1 = s1 / (1.f + expf(-s1));
  s2 = s2 / (1.f + expf(-s2));
  s3 = s3 / (1.f + expf(-s3));
  *(float4*)(xbc + (size_t)token * XBC + c4) = make_float4(s0, s1, s2, s3);
}

// ---------------- dt = softplus(raw + bias), dA = exp(dt * -exp(A_log)) ----------------
__global__ __launch_bounds__(256) void dt_kernel(
    const float* __restrict__ zx, const float* __restrict__ dtb,
    const float* __restrict__ A_log, float* __restrict__ dtv, float* __restrict__ dAv) {
  int gid = blockIdx.x * 256 + threadIdx.x;  // T*8
  int token = gid >> 3, h = gid & 7;
  float raw = zx[(size_t)token * DIN + (DI + XBC) + h] + dtb[h];
  float dt = raw > 20.f ? raw : log1pf(expf(raw));
  dtv[gid] = dt;
  dAv[gid] = expf(-expf(A_log[h]) * dt);
}

// ---------------- sequential SSM scan, grouped-staged pipeline ----------------
// grid = 256 blocks (one per b), 512 threads = 8 waves, wave w = head w.
// Lane owns p = lane&31, n-half nh = lane>>5 -> 32 state regs (n = nh*32 + j).
// Tokens staged in groups of 8 (one token per wave): global->regs issued a full
// group ahead, regs->LDS + ONE __syncthreads per 8 steps. No per-step barrier.
__global__ __launch_bounds__(512) void scan_kernel(
    const float* __restrict__ xbc, const float* __restrict__ dtv,
    const float* __restrict__ dAv, const float* __restrict__ Dp,
    float* __restrict__ y) {
  const int b = blockIdx.x;
  const int tid = threadIdx.x;
  const int w = tid >> 6, lane = tid & 63;
  const int h = w;
  const int p = lane & 31, nh = lane >> 5;
  // LDS slot per token: [0..255]=x (8 heads x 32), [256..319]=B, [320..383]=C,
  // [384..391]=dA, [392..399]=dt
  __shared__ float st[2][8][400];
  float hs[32];
#pragma unroll
  for (int j = 0; j < 32; ++j) hs[j] = 0.f;
  const float dp = Dp[h];

  float4 r0, r1;
  float sc;

#define LOAD_GRP(g)                                                   \
  {                                                                   \
    int tok_ = b * 256 + (g) * 8 + w;                                 \
    const float* row_ = xbc + (size_t)tok_ * XBC;                     \
    r0 = ((const float4*)row_)[lane];                                 \
    if (lane < 32) r1 = ((const float4*)row_)[64 + lane];             \
    if (lane < 8) sc = dAv[tok_ * 8 + lane];                          \
    else if (lane < 16) sc = dtv[tok_ * 8 + lane - 8];                \
  }
#define WRITE_GRP(bf)                                                 \
  {                                                                   \
    float* slot_ = &st[bf][w][0];                                     \
    *(float4*)(slot_ + 4 * lane) = r0;                                \
    if (lane < 32) *(float4*)(slot_ + 256 + 4 * lane) = r1;           \
    if (lane < 16) slot_[384 + lane] = sc;                            \
  }

  LOAD_GRP(0);
  WRITE_GRP(0);
  __syncthreads();
  LOAD_GRP(1);

  for (int g = 0; g < 32; ++g) {
    const int buf = g & 1;
    const int tok0 = b * 256 + g * 8;
#pragma unroll
    for (int s8 = 0; s8 < 8; ++s8) {
      const float* sl = &st[buf][s8][0];
      float dA = sl[384 + h];
      float dtt = sl[392 + h];
      float xv = sl[h * 32 + p];
      float coef = dtt * xv;
      const float* Bh = sl + 256 + nh * 32;
      const float* Ch = sl + 320 + nh * 32;
      float y0 = 0.f, y1 = 0.f, y2 = 0.f, y3 = 0.f;
#pragma unroll
      for (int j = 0; j < 32; j += 4) {
        hs[j + 0] = dA * hs[j + 0] + coef * Bh[j + 0]; y0 += hs[j + 0] * Ch[j + 0];
        hs[j + 1] = dA * hs[j + 1] + coef * Bh[j + 1]; y1 += hs[j + 1] * Ch[j + 1];
        hs[j + 2] = dA * hs[j + 2] + coef * Bh[j + 2]; y2 += hs[j + 2] * Ch[j + 2];
        hs[j + 3] = dA * hs[j + 3] + coef * Bh[j + 3]; y3 += hs[j + 3] * Ch[j + 3];
      }
      float yp = (y0 + y1) + (y2 + y3);
      yp += __shfl_xor(yp, 32);
      if (nh == 0)
        y[(size_t)(tok0 + s8) * DI + h * 32 + p] = yp + dp * xv;
    }
    if (g < 31) {
      WRITE_GRP(buf ^ 1);   // regs hold group g+1 (issued >=1 group ago)
      __syncthreads();
      if (g < 30) LOAD_GRP(g + 2);
    }
  }
#undef LOAD_GRP
#undef WRITE_GRP
}

// ---------------- y = rmsnorm(y * silu(z)) * nw  (in-place on y) ----------------
__global__ __launch_bounds__(256) void gate_rms_kernel(
    float* y, const float* __restrict__ zx, const float* __restrict__ nw) {
  int wid = threadIdx.x >> 6, lane = threadIdx.x & 63;
  size_t token = (size_t)blockIdx.x * 4 + wid;
  float4 yv = *(const float4*)(y + token * DI + lane * 4);
  float4 zv = *(const float4*)(zx + token * DIN + lane * 4);
  float g0 = yv.x * (zv.x / (1.f + expf(-zv.x)));
  float g1 = yv.y * (zv.y / (1.f + expf(-zv.y)));
  float g2 = yv.z * (zv.z / (1.f + expf(-zv.z)));
  float g3 = yv.w * (zv.w / (1.f + expf(-zv.w)));
  float ss = g0 * g0 + g1 * g1 + g2 * g2 + g3 * g3;
#pragma unroll
  for (int off = 1; off < 64; off <<= 1) ss += __shfl_xor(ss, off);
  float r = rsqrtf(ss * (1.f / 256.f) + EPSF);
  float4 o;
  o.x = g0 * r * nw[lane * 4 + 0];
  o.y = g1 * r * nw[lane * 4 + 1];
  o.z = g2 * r * nw[lane * 4 + 2];
  o.w = g3 * r * nw[lane * 4 + 3];
  *(float4*)(y + token * DI + lane * 4) = o;
}

// ---------------- column mean over L ----------------
__global__ __launch_bounds__(128) void colmean_kernel(const float* __restrict__ tn, float* __restrict__ tmean) {
  int b = blockIdx.x, e = threadIdx.x;
  const float* p = tn + (size_t)b * 256 * 128 + e;
  float acc = 0.f;
  for (int l = 0; l < 256; ++l) acc += p[l * 128];
  tmean[b * 128 + e] = acc * (1.f / 256.f);
}

// ---------------- head matmul + L2 normalize ----------------
__global__ __launch_bounds__(128) void head_kernel(
    const float* __restrict__ tmean, const float* __restrict__ hw,
    const float* __restrict__ hb, float* __restrict__ out) {
  __shared__ float tm[128];
  __shared__ float red[2];
  int b = blockIdx.x, o = threadIdx.x;
  tm[o] = tmean[b * 128 + o];
  __syncthreads();
  float acc = hb[o];
  for (int e = 0; e < 128; ++e) acc += tm[e] * hw[o * 128 + e];
  float ss = acc * acc;
#pragma unroll
  for (int off = 1; off < 64; off <<= 1) ss += __shfl_xor(ss, off);
  if ((o & 63) == 0) red[o >> 6] = ss;
  __syncthreads();
  float nrm = fmaxf(sqrtf(red[0] + red[1]), 1e-12f);
  out[b * 128 + o] = acc / nrm;
}

extern "C" void kernel_launch(void* const* d_in, const int* in_sizes, int n_in,
                              void* d_out, int out_size, void* d_ws, size_t ws_size,
                              hipStream_t stream) {
  const float* x      = (const float*)d_in[0];
  const float* conv_w = (const float*)d_in[1];
  const float* conv_b = (const float*)d_in[2];
  const float* pe_w   = (const float*)d_in[3];
  const float* pe_b   = (const float*)d_in[4];
  const float* ln_w   = (const float*)d_in[5];
  const float* ln_b   = (const float*)d_in[6];
  const float* in_w   = (const float*)d_in[7];
  const float* c1w    = (const float*)d_in[8];
  const float* c1b    = (const float*)d_in[9];
  const float* dtb    = (const float*)d_in[10];
  const float* A_log  = (const float*)d_in[11];
  const float* Dp     = (const float*)d_in[12];
  const float* nw     = (const float*)d_in[13];
  const float* ow     = (const float*)d_in[14];
  const float* fn_w   = (const float*)d_in[15];
  const float* fn_b   = (const float*)d_in[16];
  const float* hw     = (const float*)d_in[17];
  const float* hb     = (const float*)d_in[18];
  float* out = (float*)d_out;
  float* ws = (float*)d_ws;

  const size_t T = TTOK;
  float* t_buf = ws;
  float* tn    = t_buf + T * 128;
  float* zx    = tn + T * 128;
  float* xbc   = zx + T * DIN;
  float* dtv   = xbc + T * XBC;
  float* dAv   = dtv + T * 8;
  float* ybuf  = dAv + T * 8;
  float* tmean = ybuf + T * DI;
  size_t need = (T * (size_t)(128 * 2 + DIN + XBC + 8 + 8 + DI) + 256 * 128) * sizeof(float);
  if (ws_size < need) return;  // workspace too small -> fail visibly

  // patch embed + bias, then pe layernorm (in place)
  gemm_bf16_patch<<<dim3(512, 1), 256, 0, stream>>>(x, conv_w, conv_b, t_buf);
  ln_kernel<<<16384, 256, 0, stream>>>(t_buf, t_buf, pe_w, pe_b);

  for (int i = 0; i < NL; ++i) {
    ln_kernel<<<16384, 256, 0, stream>>>(t_buf, tn, ln_w + i * 128, ln_b + i * 128);
    gemm_bf16_nt<<<dim3(512, 6), 256, 0, stream>>>(
        tn, in_w + (size_t)i * DIN * EE, zx, nullptr, nullptr, TTOK, DIN, EE);
    conv_silu_kernel<<<24576, 256, 0, stream>>>(zx, c1w + (size_t)i * XBC * DC, c1b + (size_t)i * XBC, xbc);
    dt_kernel<<<2048, 256, 0, stream>>>(zx, dtb + i * HH, A_log + i * HH, dtv, dAv);
    scan_kernel<<<256, 512, 0, stream>>>(xbc, dtv, dAv, Dp + i * HH, ybuf);
    gate_rms_kernel<<<16384, 256, 0, stream>>>(ybuf, zx, nw + i * DI);
    gemm_bf16_nt<<<dim3(512, 2), 256, 0, stream>>>(
        ybuf, ow + (size_t)i * EE * DI, t_buf, t_buf, nullptr, TTOK, EE, DI);
  }

  ln_kernel<<<16384, 256, 0, stream>>>(t_buf, tn, fn_w, fn_b);
  colmean_kernel<<<256, 128, 0, stream>>>(tn, tmean);
  head_kernel<<<256, 128, 0, stream>>>(tmean, hw, hb, out);
}

// Round 4
// 1605.838 us; speedup vs baseline: 1.6228x; 1.0501x over previous
//
#include <hip/hip_runtime.h>
#include <math.h>

// ---------------- constants ----------------
#define EE 128
#define DI 256
#define HH 8
#define PP 32
#define NN 64
#define DC 4
#define XBC 384
#define DIN 648
#define NL 4
#define LSEQ 256
#define BB 256
#define TTOK (BB * LSEQ)   // 65536 tokens
#define EPSF 1e-5f

typedef __attribute__((ext_vector_type(8))) short short8;
typedef __attribute__((ext_vector_type(4))) float f32x4;

__device__ inline short f2bf(float f) {
  unsigned u = __builtin_bit_cast(unsigned, f);
  u += 0x7fff + ((u >> 16) & 1);   // RNE
  return (short)(u >> 16);
}
__device__ inline float bf2f(unsigned short u) {
  unsigned x = ((unsigned)u) << 16;
  return __builtin_bit_cast(float, x);
}

// ---------------- bf16 MFMA GEMM, A already bf16: C[M][N] = A[M][K]*B[N][K]^T (+bias)(+resid) ----------------
// 128x128 tile, 256 threads (4 waves 2x2). K multiple of 32, M multiple of 128, N guarded.
__global__ __launch_bounds__(256) void gemm_bf16_nt_abf(
    const unsigned short* __restrict__ A, const float* __restrict__ B,
    float* C, const float* resid, const float* __restrict__ bias,
    int M, int N, int K) {
  __shared__ short As[128][40];
  __shared__ short Bs[128][40];
  const int tid = threadIdx.x;
  const int lane = tid & 63, wid = tid >> 6;
  const int wm = wid >> 1, wn = wid & 1;
  const int m0 = blockIdx.x * 128, n0 = blockIdx.y * 128;
  const int r = tid >> 1, hf = tid & 1;       // staging: row 0..127, k-half
  const int lr = lane & 15, lk = (lane >> 4) * 8;
  f32x4 acc[4][4] = {};
  for (int k0 = 0; k0 < K; k0 += 32) {
    // stage A (bf16 direct)
    {
      const unsigned short* ap = A + (size_t)(m0 + r) * K + k0 + hf * 16;
      short8 s0 = *(const short8*)(ap);
      short8 s1 = *(const short8*)(ap + 8);
      *(short8*)&As[r][hf * 16] = s0;
      *(short8*)&As[r][hf * 16 + 8] = s1;
    }
    // stage B (fp32 -> bf16, guarded)
    {
      short8 s0 = {}, s1 = {};
      if (n0 + r < N) {
        const float* bp = B + (size_t)(n0 + r) * K + k0 + hf * 16;
        float4 v0 = *(const float4*)(bp + 0);
        float4 v1 = *(const float4*)(bp + 4);
        float4 v2 = *(const float4*)(bp + 8);
        float4 v3 = *(const float4*)(bp + 12);
        s0[0] = f2bf(v0.x); s0[1] = f2bf(v0.y); s0[2] = f2bf(v0.z); s0[3] = f2bf(v0.w);
        s0[4] = f2bf(v1.x); s0[5] = f2bf(v1.y); s0[6] = f2bf(v1.z); s0[7] = f2bf(v1.w);
        s1[0] = f2bf(v2.x); s1[1] = f2bf(v2.y); s1[2] = f2bf(v2.z); s1[3] = f2bf(v2.w);
        s1[4] = f2bf(v3.x); s1[5] = f2bf(v3.y); s1[6] = f2bf(v3.z); s1[7] = f2bf(v3.w);
      }
      *(short8*)&Bs[r][hf * 16] = s0;
      *(short8*)&Bs[r][hf * 16 + 8] = s1;
    }
    __syncthreads();
    short8 af[4], bfr[4];
#pragma unroll
    for (int mi = 0; mi < 4; ++mi) af[mi] = *(const short8*)&As[wm * 64 + mi * 16 + lr][lk];
#pragma unroll
    for (int ni = 0; ni < 4; ++ni) bfr[ni] = *(const short8*)&Bs[wn * 64 + ni * 16 + lr][lk];
#pragma unroll
    for (int mi = 0; mi < 4; ++mi)
#pragma unroll
      for (int ni = 0; ni < 4; ++ni)
        acc[mi][ni] = __builtin_amdgcn_mfma_f32_16x16x32_bf16(af[mi], bfr[ni], acc[mi][ni], 0, 0, 0);
    __syncthreads();
  }
#pragma unroll
  for (int mi = 0; mi < 4; ++mi) {
#pragma unroll
    for (int ni = 0; ni < 4; ++ni) {
      int row0 = m0 + wm * 64 + mi * 16 + (lane >> 4) * 4;
      int col = n0 + wn * 64 + ni * 16 + (lane & 15);
      if (col < N) {
        float bv = bias ? bias[col] : 0.f;
#pragma unroll
        for (int j = 0; j < 4; ++j) {
          size_t idx = (size_t)(row0 + j) * N + col;
          float v = acc[mi][ni][j] + bv;
          if (resid) v += resid[idx];
          C[idx] = v;
        }
      }
    }
  }
}

// ---------------- patch-embed bf16 MFMA GEMM ----------------
__global__ __launch_bounds__(256) void gemm_bf16_patch(
    const float* __restrict__ X, const float* __restrict__ B,
    const float* __restrict__ bias, float* __restrict__ C) {
  __shared__ short As[128][40];
  __shared__ short Bs[128][40];
  const int tid = threadIdx.x;
  const int lane = tid & 63, wid = tid >> 6;
  const int wm = wid >> 1, wn = wid & 1;
  const int m0 = blockIdx.x * 128;
  const int r = tid >> 1, hf = tid & 1;
  const int lr = lane & 15, lk = (lane >> 4) * 8;
  const int m = m0 + r;
  const int bb = m >> 8, px = (m >> 4) & 15, py = m & 15;
  f32x4 acc[4][4] = {};
  for (int k0 = 0; k0 < 768; k0 += 32) {
    int k = k0 + hf * 16;
    int c = k >> 8, dx = (k >> 4) & 15;
    {
      const float* ap = X + (((size_t)(bb * 3 + c) * 256 + px * 16 + dx) * 256 + py * 16);
      float4 v0 = *(const float4*)(ap + 0);
      float4 v1 = *(const float4*)(ap + 4);
      float4 v2 = *(const float4*)(ap + 8);
      float4 v3 = *(const float4*)(ap + 12);
      short8 s0, s1;
      s0[0] = f2bf(v0.x); s0[1] = f2bf(v0.y); s0[2] = f2bf(v0.z); s0[3] = f2bf(v0.w);
      s0[4] = f2bf(v1.x); s0[5] = f2bf(v1.y); s0[6] = f2bf(v1.z); s0[7] = f2bf(v1.w);
      s1[0] = f2bf(v2.x); s1[1] = f2bf(v2.y); s1[2] = f2bf(v2.z); s1[3] = f2bf(v2.w);
      s1[4] = f2bf(v3.x); s1[5] = f2bf(v3.y); s1[6] = f2bf(v3.z); s1[7] = f2bf(v3.w);
      *(short8*)&As[r][hf * 16] = s0;
      *(short8*)&As[r][hf * 16 + 8] = s1;
    }
    {
      const float* bp = B + (size_t)r * 768 + k;
      float4 v0 = *(const float4*)(bp + 0);
      float4 v1 = *(const float4*)(bp + 4);
      float4 v2 = *(const float4*)(bp + 8);
      float4 v3 = *(const float4*)(bp + 12);
      short8 s0, s1;
      s0[0] = f2bf(v0.x); s0[1] = f2bf(v0.y); s0[2] = f2bf(v0.z); s0[3] = f2bf(v0.w);
      s0[4] = f2bf(v1.x); s0[5] = f2bf(v1.y); s0[6] = f2bf(v1.z); s0[7] = f2bf(v1.w);
      s1[0] = f2bf(v2.x); s1[1] = f2bf(v2.y); s1[2] = f2bf(v2.z); s1[3] = f2bf(v2.w);
      s1[4] = f2bf(v3.x); s1[5] = f2bf(v3.y); s1[6] = f2bf(v3.z); s1[7] = f2bf(v3.w);
      *(short8*)&Bs[r][hf * 16] = s0;
      *(short8*)&Bs[r][hf * 16 + 8] = s1;
    }
    __syncthreads();
    short8 af[4], bfr[4];
#pragma unroll
    for (int mi = 0; mi < 4; ++mi) af[mi] = *(const short8*)&As[wm * 64 + mi * 16 + lr][lk];
#pragma unroll
    for (int ni = 0; ni < 4; ++ni) bfr[ni] = *(const short8*)&Bs[wn * 64 + ni * 16 + lr][lk];
#pragma unroll
    for (int mi = 0; mi < 4; ++mi)
#pragma unroll
      for (int ni = 0; ni < 4; ++ni)
        acc[mi][ni] = __builtin_amdgcn_mfma_f32_16x16x32_bf16(af[mi], bfr[ni], acc[mi][ni], 0, 0, 0);
    __syncthreads();
  }
#pragma unroll
  for (int mi = 0; mi < 4; ++mi) {
#pragma unroll
    for (int ni = 0; ni < 4; ++ni) {
      int row0 = m0 + wm * 64 + mi * 16 + (lane >> 4) * 4;
      int col = wn * 64 + ni * 16 + (lane & 15);
#pragma unroll
      for (int j = 0; j < 4; ++j)
        C[(size_t)(row0 + j) * 128 + col] = acc[mi][ni][j] + bias[col];
    }
  }
}

// ---------------- LayerNorm over E=128, fp32 out (PE only) ----------------
__global__ __launch_bounds__(256) void ln_kernel(const float* in, float* out,
                                                 const float* __restrict__ w, const float* __restrict__ b) {
  int wid = threadIdx.x >> 6, lane = threadIdx.x & 63;
  size_t token = (size_t)blockIdx.x * 4 + wid;
  const float* p = in + token * 128;
  float2 v = *(const float2*)(p + lane * 2);
  float s = v.x + v.y;
#pragma unroll
  for (int off = 1; off < 64; off <<= 1) s += __shfl_xor(s, off);
  float mu = s * (1.f / 128.f);
  float dx = v.x - mu, dy = v.y - mu;
  float vs = dx * dx + dy * dy;
#pragma unroll
  for (int off = 1; off < 64; off <<= 1) vs += __shfl_xor(vs, off);
  float r = rsqrtf(vs * (1.f / 128.f) + EPSF);
  float2 o;
  o.x = dx * r * w[lane * 2 + 0] + b[lane * 2 + 0];
  o.y = dy * r * w[lane * 2 + 1] + b[lane * 2 + 1];
  *(float2*)(out + token * 128 + lane * 2) = o;
}

// ---------------- LayerNorm over E=128, bf16-packed out ----------------
__global__ __launch_bounds__(256) void ln_bf16_kernel(const float* in, unsigned* out,
                                                      const float* __restrict__ w, const float* __restrict__ b) {
  int wid = threadIdx.x >> 6, lane = threadIdx.x & 63;
  size_t token = (size_t)blockIdx.x * 4 + wid;
  const float* p = in + token * 128;
  float2 v = *(const float2*)(p + lane * 2);
  float s = v.x + v.y;
#pragma unroll
  for (int off = 1; off < 64; off <<= 1) s += __shfl_xor(s, off);
  float mu = s * (1.f / 128.f);
  float dx = v.x - mu, dy = v.y - mu;
  float vs = dx * dx + dy * dy;
#pragma unroll
  for (int off = 1; off < 64; off <<= 1) vs += __shfl_xor(vs, off);
  float r = rsqrtf(vs * (1.f / 128.f) + EPSF);
  unsigned lo = (unsigned short)f2bf(dx * r * w[lane * 2 + 0] + b[lane * 2 + 0]);
  unsigned hi = (unsigned short)f2bf(dy * r * w[lane * 2 + 1] + b[lane * 2 + 1]);
  out[token * 64 + lane] = lo | (hi << 16);
}

// ---------------- causal conv1d (DC=4) + SiLU over xbc channels ----------------
__global__ __launch_bounds__(256) void conv_silu_kernel(
    const float* __restrict__ zx, const float* __restrict__ cw,
    const float* __restrict__ cb, float* __restrict__ xbc) {
  int gid = blockIdx.x * 256 + threadIdx.x;  // T*96
  int token = gid / 96;
  int c4 = (gid - token * 96) * 4;
  int l = token & 255;
  const float* base = zx + (size_t)token * DIN + DI + c4;
  float4 z4 = make_float4(0.f, 0.f, 0.f, 0.f);
  float4 v0 = (l >= 3) ? *(const float4*)(base - 3 * DIN) : z4;
  float4 v1 = (l >= 2) ? *(const float4*)(base - 2 * DIN) : z4;
  float4 v2 = (l >= 1) ? *(const float4*)(base - 1 * DIN) : z4;
  float4 v3 = *(const float4*)(base);
  float4 w0 = *(const float4*)(cw + (c4 + 0) * 4);
  float4 w1 = *(const float4*)(cw + (c4 + 1) * 4);
  float4 w2 = *(const float4*)(cw + (c4 + 2) * 4);
  float4 w3 = *(const float4*)(cw + (c4 + 3) * 4);
  float4 cbv = *(const float4*)(cb + c4);
  float s0 = cbv.x + w0.x * v0.x + w0.y * v1.x + w0.z * v2.x + w0.w * v3.x;
  float s1 = cbv.y + w1.x * v0.y + w1.y * v1.y + w1.z * v2.y + w1.w * v3.y;
  float s2 = cbv.z + w2.x * v0.z + w2.y * v1.z + w2.z * v2.z + w2.w * v3.z;
  float s3 = cbv.w + w3.x * v0.w + w3.y * v1.w + w3.z * v2.w + w3.w * v3.w;
  s0 = s0 / (1.f + expf(-s0));
  s1 = s1 / (1.f + expf(-s1));
  s2 = s2 / (1.f + expf(-s2));
  s3 = s3 / (1.f + expf(-s3));
  *(float4*)(xbc + (size_t)token * XBC + c4) = make_float4(s0, s1, s2, s3);
}

// ---------------- dt = softplus(raw + bias), dA = exp(dt * -exp(A_log)) ----------------
__global__ __launch_bounds__(256) void dt_kernel(
    const float* __restrict__ zx, const float* __restrict__ dtb,
    const float* __restrict__ A_log, float* __restrict__ dtv, float* __restrict__ dAv) {
  int gid = blockIdx.x * 256 + threadIdx.x;  // T*8
  int token = gid >> 3, h = gid & 7;
  float raw = zx[(size_t)token * DIN + (DI + XBC) + h] + dtb[h];
  float dt = raw > 20.f ? raw : log1pf(expf(raw));
  dtv[gid] = dt;
  dAv[gid] = expf(-expf(A_log[h]) * dt);
}

// ---------------- sequential SSM scan, 2 heads per lane ----------------
// grid = 256 (one per b), 256 threads = 4 waves. Wave w: heads w and w+4.
// Lane: p = lane&31, n-half nh = lane>>5. hs0/hs1 = 32 state regs per head.
// B/C LDS reads shared between the two heads (halves redundant LDS traffic).
// Token groups of 8 staged double-buffered; each wave stages 2 tokens/group.
// y is written into the x-slot of xbc (rows are fully consumed 2 groups ahead).
__global__ __launch_bounds__(256) void scan_kernel(
    const float* __restrict__ xbc, const float* __restrict__ dtv,
    const float* __restrict__ dAv, const float* __restrict__ Dp,
    float* __restrict__ yout) {
  const int b = blockIdx.x;
  const int tid = threadIdx.x;
  const int w = tid >> 6, lane = tid & 63;
  const int h0 = w, h1 = w + 4;
  const int p = lane & 31, nh = lane >> 5;
  // slot: [0..255]=x (8h x 32), [256..319]=B, [320..383]=C, [384..391]=dA, [392..399]=dt
  __shared__ float st[2][8][400];
  float hs0[32], hs1[32];
#pragma unroll
  for (int j = 0; j < 32; ++j) { hs0[j] = 0.f; hs1[j] = 0.f; }
  const float dp0 = Dp[h0], dp1 = Dp[h1];

  float4 r0a, r1a; float sca = 0.f;
  float4 r0b, r1b; float scb = 0.f;

#define LOAD_GRP(g)                                                   \
  {                                                                   \
    int tokA_ = b * 256 + (g) * 8 + 2 * w;                            \
    const float* rowA_ = xbc + (size_t)tokA_ * XBC;                   \
    r0a = ((const float4*)rowA_)[lane];                               \
    if (lane < 32) r1a = ((const float4*)rowA_)[64 + lane];           \
    if (lane < 8) sca = dAv[tokA_ * 8 + lane];                        \
    else if (lane < 16) sca = dtv[tokA_ * 8 + lane - 8];              \
    const float* rowB_ = rowA_ + XBC;                                 \
    r0b = ((const float4*)rowB_)[lane];                               \
    if (lane < 32) r1b = ((const float4*)rowB_)[64 + lane];           \
    if (lane < 8) scb = dAv[tokA_ * 8 + 8 + lane];                    \
    else if (lane < 16) scb = dtv[tokA_ * 8 + 8 + lane - 8];          \
  }
#define WRITE_GRP(bf)                                                 \
  {                                                                   \
    float* slA_ = &st[bf][2 * w][0];                                  \
    *(float4*)(slA_ + 4 * lane) = r0a;                                \
    if (lane < 32) *(float4*)(slA_ + 256 + 4 * lane) = r1a;           \
    if (lane < 16) slA_[384 + lane] = sca;                            \
    float* slB_ = &st[bf][2 * w + 1][0];                              \
    *(float4*)(slB_ + 4 * lane) = r0b;                                \
    if (lane < 32) *(float4*)(slB_ + 256 + 4 * lane) = r1b;           \
    if (lane < 16) slB_[384 + lane] = scb;                            \
  }

  LOAD_GRP(0);
  WRITE_GRP(0);
  __syncthreads();
  LOAD_GRP(1);

  for (int g = 0; g < 32; ++g) {
    const int buf = g & 1;
    const int tok0 = b * 256 + g * 8;
#pragma unroll
    for (int s8 = 0; s8 < 8; ++s8) {
      const float* sl = &st[buf][s8][0];
      float dA0 = sl[384 + h0], dA1 = sl[384 + h1];
      float dt0 = sl[392 + h0], dt1 = sl[392 + h1];
      float xv0 = sl[h0 * 32 + p], xv1 = sl[h1 * 32 + p];
      float c0 = dt0 * xv0, c1 = dt1 * xv1;
      const float4* B4 = (const float4*)(sl + 256 + nh * 32);
      const float4* C4 = (const float4*)(sl + 320 + nh * 32);
      float ya0 = 0.f, ya1 = 0.f, yb0 = 0.f, yb1 = 0.f;
#pragma unroll
      for (int jq = 0; jq < 8; ++jq) {
        float4 bq = B4[jq], cq = C4[jq];
        int j = jq * 4;
        hs0[j + 0] = dA0 * hs0[j + 0] + c0 * bq.x; ya0 += hs0[j + 0] * cq.x;
        hs1[j + 0] = dA1 * hs1[j + 0] + c1 * bq.x; yb0 += hs1[j + 0] * cq.x;
        hs0[j + 1] = dA0 * hs0[j + 1] + c0 * bq.y; ya1 += hs0[j + 1] * cq.y;
        hs1[j + 1] = dA1 * hs1[j + 1] + c1 * bq.y; yb1 += hs1[j + 1] * cq.y;
        hs0[j + 2] = dA0 * hs0[j + 2] + c0 * bq.z; ya0 += hs0[j + 2] * cq.z;
        hs1[j + 2] = dA1 * hs1[j + 2] + c1 * bq.z; yb0 += hs1[j + 2] * cq.z;
        hs0[j + 3] = dA0 * hs0[j + 3] + c0 * bq.w; ya1 += hs0[j + 3] * cq.w;
        hs1[j + 3] = dA1 * hs1[j + 3] + c1 * bq.w; yb1 += hs1[j + 3] * cq.w;
      }
      float y0 = ya0 + ya1, y1 = yb0 + yb1;
      y0 += __shfl_xor(y0, 32);
      y1 += __shfl_xor(y1, 32);
      if (nh == 0) {
        size_t base = (size_t)(tok0 + s8) * XBC;
        yout[base + h0 * 32 + p] = y0 + dp0 * xv0;
        yout[base + h1 * 32 + p] = y1 + dp1 * xv1;
      }
    }
    if (g < 31) {
      WRITE_GRP(buf ^ 1);
      __syncthreads();
      if (g < 30) LOAD_GRP(g + 2);
    }
  }
#undef LOAD_GRP
#undef WRITE_GRP
}

// ---------------- y = rmsnorm(yraw * silu(z)) * nw -> bf16 ----------------
// yraw lives in xbc rows (stride XBC, first 256 floats).
__global__ __launch_bounds__(256) void gate_rms_kernel(
    const float* __restrict__ yraw, const float* __restrict__ zx,
    const float* __restrict__ nw, unsigned short* __restrict__ yout) {
  int wid = threadIdx.x >> 6, lane = threadIdx.x & 63;
  size_t token = (size_t)blockIdx.x * 4 + wid;
  float4 yv = *(const float4*)(yraw + token * XBC + lane * 4);
  float4 zv = *(const float4*)(zx + token * DIN + lane * 4);
  float g0 = yv.x * (zv.x / (1.f + expf(-zv.x)));
  float g1 = yv.y * (zv.y / (1.f + expf(-zv.y)));
  float g2 = yv.z * (zv.z / (1.f + expf(-zv.z)));
  float g3 = yv.w * (zv.w / (1.f + expf(-zv.w)));
  float ss = g0 * g0 + g1 * g1 + g2 * g2 + g3 * g3;
#pragma unroll
  for (int off = 1; off < 64; off <<= 1) ss += __shfl_xor(ss, off);
  float r = rsqrtf(ss * (1.f / 256.f) + EPSF);
  unsigned w0 = (unsigned short)f2bf(g0 * r * nw[lane * 4 + 0]);
  unsigned w1 = (unsigned short)f2bf(g1 * r * nw[lane * 4 + 1]);
  unsigned w2 = (unsigned short)f2bf(g2 * r * nw[lane * 4 + 2]);
  unsigned w3 = (unsigned short)f2bf(g3 * r * nw[lane * 4 + 3]);
  uint2 packed = make_uint2(w0 | (w1 << 16), w2 | (w3 << 16));
  *(uint2*)(yout + token * DI + lane * 4) = packed;
}

// ---------------- column mean over L (bf16 in) ----------------
__global__ __launch_bounds__(128) void colmean_kernel(const unsigned short* __restrict__ tn,
                                                      float* __restrict__ tmean) {
  int b = blockIdx.x, e = threadIdx.x;
  const unsigned short* p = tn + (size_t)b * 256 * 128 + e;
  float acc = 0.f;
  for (int l = 0; l < 256; ++l) acc += bf2f(p[l * 128]);
  tmean[b * 128 + e] = acc * (1.f / 256.f);
}

// ---------------- head matmul + L2 normalize ----------------
__global__ __launch_bounds__(128) void head_kernel(
    const float* __restrict__ tmean, const float* __restrict__ hw,
    const float* __restrict__ hb, float* __restrict__ out) {
  __shared__ float tm[128];
  __shared__ float red[2];
  int b = blockIdx.x, o = threadIdx.x;
  tm[o] = tmean[b * 128 + o];
  __syncthreads();
  float acc = hb[o];
  for (int e = 0; e < 128; ++e) acc += tm[e] * hw[o * 128 + e];
  float ss = acc * acc;
#pragma unroll
  for (int off = 1; off < 64; off <<= 1) ss += __shfl_xor(ss, off);
  if ((o & 63) == 0) red[o >> 6] = ss;
  __syncthreads();
  float nrm = fmaxf(sqrtf(red[0] + red[1]), 1e-12f);
  out[b * 128 + o] = acc / nrm;
}

extern "C" void kernel_launch(void* const* d_in, const int* in_sizes, int n_in,
                              void* d_out, int out_size, void* d_ws, size_t ws_size,
                              hipStream_t stream) {
  const float* x      = (const float*)d_in[0];
  const float* conv_w = (const float*)d_in[1];
  const float* conv_b = (const float*)d_in[2];
  const float* pe_w   = (const float*)d_in[3];
  const float* pe_b   = (const float*)d_in[4];
  const float* ln_w   = (const float*)d_in[5];
  const float* ln_b   = (const float*)d_in[6];
  const float* in_w   = (const float*)d_in[7];
  const float* c1w    = (const float*)d_in[8];
  const float* c1b    = (const float*)d_in[9];
  const float* dtb    = (const float*)d_in[10];
  const float* A_log  = (const float*)d_in[11];
  const float* Dp     = (const float*)d_in[12];
  const float* nw     = (const float*)d_in[13];
  const float* ow     = (const float*)d_in[14];
  const float* fn_w   = (const float*)d_in[15];
  const float* fn_b   = (const float*)d_in[16];
  const float* hw     = (const float*)d_in[17];
  const float* hb     = (const float*)d_in[18];
  float* out = (float*)d_out;

  const size_t T = TTOK;
  float* t_buf = (float*)d_ws;                               // T*128 f32
  unsigned* tnb = (unsigned*)(t_buf + T * 128);              // T*128 bf16 (T*64 u32)
  float* zx    = (float*)(tnb + T * 64);                     // T*648 f32
  float* xbc   = zx + T * DIN;                               // T*384 f32 (y reuses cols 0..255)
  float* dtv   = xbc + T * XBC;                              // T*8
  float* dAv   = dtv + T * 8;                                // T*8
  unsigned short* ybb = (unsigned short*)(dAv + T * 8);      // T*256 bf16
  float* tmean = (float*)(ybb + T * 256);                    // 256*128
  size_t need = 4 * (T * (size_t)(128 + 64 + 648 + 384 + 8 + 8 + 128) + 256 * 128);
  if (ws_size < need) return;  // workspace too small -> fail visibly

  // patch embed + bias, then pe layernorm (in place, fp32)
  gemm_bf16_patch<<<dim3(512, 1), 256, 0, stream>>>(x, conv_w, conv_b, t_buf);
  ln_kernel<<<16384, 256, 0, stream>>>(t_buf, t_buf, pe_w, pe_b);

  for (int i = 0; i < NL; ++i) {
    ln_bf16_kernel<<<16384, 256, 0, stream>>>(t_buf, tnb, ln_w + i * 128, ln_b + i * 128);
    gemm_bf16_nt_abf<<<dim3(512, 6), 256, 0, stream>>>(
        (const unsigned short*)tnb, in_w + (size_t)i * DIN * EE, zx, nullptr, nullptr, TTOK, DIN, EE);
    conv_silu_kernel<<<24576, 256, 0, stream>>>(zx, c1w + (size_t)i * XBC * DC, c1b + (size_t)i * XBC, xbc);
    dt_kernel<<<2048, 256, 0, stream>>>(zx, dtb + i * HH, A_log + i * HH, dtv, dAv);
    scan_kernel<<<256, 256, 0, stream>>>(xbc, dtv, dAv, Dp + i * HH, xbc);
    gate_rms_kernel<<<16384, 256, 0, stream>>>(xbc, zx, nw + i * DI, ybb);
    gemm_bf16_nt_abf<<<dim3(512, 1), 256, 0, stream>>>(
        ybb, ow + (size_t)i * EE * DI, t_buf, t_buf, nullptr, TTOK, EE, DI);
  }

  ln_bf16_kernel<<<16384, 256, 0, stream>>>(t_buf, tnb, fn_w, fn_b);
  colmean_kernel<<<256, 128, 0, stream>>>((const unsigned short*)tnb, tmean);
  head_kernel<<<256, 128, 0, stream>>>(tmean, hw, hb, out);
}

// Round 5
// 1556.004 us; speedup vs baseline: 1.6748x; 1.0320x over previous
//
#include <hip/hip_runtime.h>
#include <math.h>

// ---------------- constants ----------------
#define EE 128
#define DI 256
#define HH 8
#define PP 32
#define NN 64
#define DC 4
#define XBC 384
#define DIN 648
#define NL 4
#define LSEQ 256
#define BB 256
#define TTOK (BB * LSEQ)   // 65536 tokens
#define EPSF 1e-5f

typedef __attribute__((ext_vector_type(8))) short short8;
typedef __attribute__((ext_vector_type(4))) float f32x4;

__device__ inline short f2bf(float f) {
  unsigned u = __builtin_bit_cast(unsigned, f);
  u += 0x7fff + ((u >> 16) & 1);   // RNE
  return (short)(u >> 16);
}
__device__ inline float bf2f(unsigned short u) {
  unsigned x = ((unsigned)u) << 16;
  return __builtin_bit_cast(float, x);
}

// ---------------- bf16 MFMA GEMM, A already bf16: C[M][N] = A[M][K]*B[N][K]^T (+bias)(+resid) ----------------
// 128x128 tile, 256 threads (4 waves 2x2). K multiple of 32, M multiple of 128, N guarded.
__global__ __launch_bounds__(256) void gemm_bf16_nt_abf(
    const unsigned short* __restrict__ A, const float* __restrict__ B,
    float* C, const float* resid, const float* __restrict__ bias,
    int M, int N, int K) {
  __shared__ short As[128][40];
  __shared__ short Bs[128][40];
  const int tid = threadIdx.x;
  const int lane = tid & 63, wid = tid >> 6;
  const int wm = wid >> 1, wn = wid & 1;
  const int m0 = blockIdx.x * 128, n0 = blockIdx.y * 128;
  const int r = tid >> 1, hf = tid & 1;       // staging: row 0..127, k-half
  const int lr = lane & 15, lk = (lane >> 4) * 8;
  f32x4 acc[4][4] = {};
  for (int k0 = 0; k0 < K; k0 += 32) {
    // stage A (bf16 direct)
    {
      const unsigned short* ap = A + (size_t)(m0 + r) * K + k0 + hf * 16;
      short8 s0 = *(const short8*)(ap);
      short8 s1 = *(const short8*)(ap + 8);
      *(short8*)&As[r][hf * 16] = s0;
      *(short8*)&As[r][hf * 16 + 8] = s1;
    }
    // stage B (fp32 -> bf16, guarded)
    {
      short8 s0 = {}, s1 = {};
      if (n0 + r < N) {
        const float* bp = B + (size_t)(n0 + r) * K + k0 + hf * 16;
        float4 v0 = *(const float4*)(bp + 0);
        float4 v1 = *(const float4*)(bp + 4);
        float4 v2 = *(const float4*)(bp + 8);
        float4 v3 = *(const float4*)(bp + 12);
        s0[0] = f2bf(v0.x); s0[1] = f2bf(v0.y); s0[2] = f2bf(v0.z); s0[3] = f2bf(v0.w);
        s0[4] = f2bf(v1.x); s0[5] = f2bf(v1.y); s0[6] = f2bf(v1.z); s0[7] = f2bf(v1.w);
        s1[0] = f2bf(v2.x); s1[1] = f2bf(v2.y); s1[2] = f2bf(v2.z); s1[3] = f2bf(v2.w);
        s1[4] = f2bf(v3.x); s1[5] = f2bf(v3.y); s1[6] = f2bf(v3.z); s1[7] = f2bf(v3.w);
      }
      *(short8*)&Bs[r][hf * 16] = s0;
      *(short8*)&Bs[r][hf * 16 + 8] = s1;
    }
    __syncthreads();
    short8 af[4], bfr[4];
#pragma unroll
    for (int mi = 0; mi < 4; ++mi) af[mi] = *(const short8*)&As[wm * 64 + mi * 16 + lr][lk];
#pragma unroll
    for (int ni = 0; ni < 4; ++ni) bfr[ni] = *(const short8*)&Bs[wn * 64 + ni * 16 + lr][lk];
#pragma unroll
    for (int mi = 0; mi < 4; ++mi)
#pragma unroll
      for (int ni = 0; ni < 4; ++ni)
        acc[mi][ni] = __builtin_amdgcn_mfma_f32_16x16x32_bf16(af[mi], bfr[ni], acc[mi][ni], 0, 0, 0);
    __syncthreads();
  }
#pragma unroll
  for (int mi = 0; mi < 4; ++mi) {
#pragma unroll
    for (int ni = 0; ni < 4; ++ni) {
      int row0 = m0 + wm * 64 + mi * 16 + (lane >> 4) * 4;
      int col = n0 + wn * 64 + ni * 16 + (lane & 15);
      if (col < N) {
        float bv = bias ? bias[col] : 0.f;
#pragma unroll
        for (int j = 0; j < 4; ++j) {
          size_t idx = (size_t)(row0 + j) * N + col;
          float v = acc[mi][ni][j] + bv;
          if (resid) v += resid[idx];
          C[idx] = v;
        }
      }
    }
  }
}

// ---------------- patch-embed bf16 MFMA GEMM ----------------
__global__ __launch_bounds__(256) void gemm_bf16_patch(
    const float* __restrict__ X, const float* __restrict__ B,
    const float* __restrict__ bias, float* __restrict__ C) {
  __shared__ short As[128][40];
  __shared__ short Bs[128][40];
  const int tid = threadIdx.x;
  const int lane = tid & 63, wid = tid >> 6;
  const int wm = wid >> 1, wn = wid & 1;
  const int m0 = blockIdx.x * 128;
  const int r = tid >> 1, hf = tid & 1;
  const int lr = lane & 15, lk = (lane >> 4) * 8;
  const int m = m0 + r;
  const int bb = m >> 8, px = (m >> 4) & 15, py = m & 15;
  f32x4 acc[4][4] = {};
  for (int k0 = 0; k0 < 768; k0 += 32) {
    int k = k0 + hf * 16;
    int c = k >> 8, dx = (k >> 4) & 15;
    {
      const float* ap = X + (((size_t)(bb * 3 + c) * 256 + px * 16 + dx) * 256 + py * 16);
      float4 v0 = *(const float4*)(ap + 0);
      float4 v1 = *(const float4*)(ap + 4);
      float4 v2 = *(const float4*)(ap + 8);
      float4 v3 = *(const float4*)(ap + 12);
      short8 s0, s1;
      s0[0] = f2bf(v0.x); s0[1] = f2bf(v0.y); s0[2] = f2bf(v0.z); s0[3] = f2bf(v0.w);
      s0[4] = f2bf(v1.x); s0[5] = f2bf(v1.y); s0[6] = f2bf(v1.z); s0[7] = f2bf(v1.w);
      s1[0] = f2bf(v2.x); s1[1] = f2bf(v2.y); s1[2] = f2bf(v2.z); s1[3] = f2bf(v2.w);
      s1[4] = f2bf(v3.x); s1[5] = f2bf(v3.y); s1[6] = f2bf(v3.z); s1[7] = f2bf(v3.w);
      *(short8*)&As[r][hf * 16] = s0;
      *(short8*)&As[r][hf * 16 + 8] = s1;
    }
    {
      const float* bp = B + (size_t)r * 768 + k;
      float4 v0 = *(const float4*)(bp + 0);
      float4 v1 = *(const float4*)(bp + 4);
      float4 v2 = *(const float4*)(bp + 8);
      float4 v3 = *(const float4*)(bp + 12);
      short8 s0, s1;
      s0[0] = f2bf(v0.x); s0[1] = f2bf(v0.y); s0[2] = f2bf(v0.z); s0[3] = f2bf(v0.w);
      s0[4] = f2bf(v1.x); s0[5] = f2bf(v1.y); s0[6] = f2bf(v1.z); s0[7] = f2bf(v1.w);
      s1[0] = f2bf(v2.x); s1[1] = f2bf(v2.y); s1[2] = f2bf(v2.z); s1[3] = f2bf(v2.w);
      s1[4] = f2bf(v3.x); s1[5] = f2bf(v3.y); s1[6] = f2bf(v3.z); s1[7] = f2bf(v3.w);
      *(short8*)&Bs[r][hf * 16] = s0;
      *(short8*)&Bs[r][hf * 16 + 8] = s1;
    }
    __syncthreads();
    short8 af[4], bfr[4];
#pragma unroll
    for (int mi = 0; mi < 4; ++mi) af[mi] = *(const short8*)&As[wm * 64 + mi * 16 + lr][lk];
#pragma unroll
    for (int ni = 0; ni < 4; ++ni) bfr[ni] = *(const short8*)&Bs[wn * 64 + ni * 16 + lr][lk];
#pragma unroll
    for (int mi = 0; mi < 4; ++mi)
#pragma unroll
      for (int ni = 0; ni < 4; ++ni)
        acc[mi][ni] = __builtin_amdgcn_mfma_f32_16x16x32_bf16(af[mi], bfr[ni], acc[mi][ni], 0, 0, 0);
    __syncthreads();
  }
#pragma unroll
  for (int mi = 0; mi < 4; ++mi) {
#pragma unroll
    for (int ni = 0; ni < 4; ++ni) {
      int row0 = m0 + wm * 64 + mi * 16 + (lane >> 4) * 4;
      int col = wn * 64 + ni * 16 + (lane & 15);
#pragma unroll
      for (int j = 0; j < 4; ++j)
        C[(size_t)(row0 + j) * 128 + col] = acc[mi][ni][j] + bias[col];
    }
  }
}

// ---------------- LayerNorm over E=128, fp32 out (PE only) ----------------
__global__ __launch_bounds__(256) void ln_kernel(const float* in, float* out,
                                                 const float* __restrict__ w, const float* __restrict__ b) {
  int wid = threadIdx.x >> 6, lane = threadIdx.x & 63;
  size_t token = (size_t)blockIdx.x * 4 + wid;
  const float* p = in + token * 128;
  float2 v = *(const float2*)(p + lane * 2);
  float s = v.x + v.y;
#pragma unroll
  for (int off = 1; off < 64; off <<= 1) s += __shfl_xor(s, off);
  float mu = s * (1.f / 128.f);
  float dx = v.x - mu, dy = v.y - mu;
  float vs = dx * dx + dy * dy;
#pragma unroll
  for (int off = 1; off < 64; off <<= 1) vs += __shfl_xor(vs, off);
  float r = rsqrtf(vs * (1.f / 128.f) + EPSF);
  float2 o;
  o.x = dx * r * w[lane * 2 + 0] + b[lane * 2 + 0];
  o.y = dy * r * w[lane * 2 + 1] + b[lane * 2 + 1];
  *(float2*)(out + token * 128 + lane * 2) = o;
}

// ---------------- LayerNorm over E=128, bf16-packed out ----------------
__global__ __launch_bounds__(256) void ln_bf16_kernel(const float* in, unsigned* out,
                                                      const float* __restrict__ w, const float* __restrict__ b) {
  int wid = threadIdx.x >> 6, lane = threadIdx.x & 63;
  size_t token = (size_t)blockIdx.x * 4 + wid;
  const float* p = in + token * 128;
  float2 v = *(const float2*)(p + lane * 2);
  float s = v.x + v.y;
#pragma unroll
  for (int off = 1; off < 64; off <<= 1) s += __shfl_xor(s, off);
  float mu = s * (1.f / 128.f);
  float dx = v.x - mu, dy = v.y - mu;
  float vs = dx * dx + dy * dy;
#pragma unroll
  for (int off = 1; off < 64; off <<= 1) vs += __shfl_xor(vs, off);
  float r = rsqrtf(vs * (1.f / 128.f) + EPSF);
  unsigned lo = (unsigned short)f2bf(dx * r * w[lane * 2 + 0] + b[lane * 2 + 0]);
  unsigned hi = (unsigned short)f2bf(dy * r * w[lane * 2 + 1] + b[lane * 2 + 1]);
  out[token * 64 + lane] = lo | (hi << 16);
}

// ---------------- causal conv1d (DC=4) + SiLU over xbc channels ----------------
__global__ __launch_bounds__(256) void conv_silu_kernel(
    const float* __restrict__ zx, const float* __restrict__ cw,
    const float* __restrict__ cb, float* __restrict__ xbc) {
  int gid = blockIdx.x * 256 + threadIdx.x;  // T*96
  int token = gid / 96;
  int c4 = (gid - token * 96) * 4;
  int l = token & 255;
  const float* base = zx + (size_t)token * DIN + DI + c4;
  float4 z4 = make_float4(0.f, 0.f, 0.f, 0.f);
  float4 v0 = (l >= 3) ? *(const float4*)(base - 3 * DIN) : z4;
  float4 v1 = (l >= 2) ? *(const float4*)(base - 2 * DIN) : z4;
  float4 v2 = (l >= 1) ? *(const float4*)(base - 1 * DIN) : z4;
  float4 v3 = *(const float4*)(base);
  float4 w0 = *(const float4*)(cw + (c4 + 0) * 4);
  float4 w1 = *(const float4*)(cw + (c4 + 1) * 4);
  float4 w2 = *(const float4*)(cw + (c4 + 2) * 4);
  float4 w3 = *(const float4*)(cw + (c4 + 3) * 4);
  float4 cbv = *(const float4*)(cb + c4);
  float s0 = cbv.x + w0.x * v0.x + w0.y * v1.x + w0.z * v2.x + w0.w * v3.x;
  float s1 = cbv.y + w1.x * v0.y + w1.y * v1.y + w1.z * v2.y + w1.w * v3.y;
  float s2 = cbv.z + w2.x * v0.z + w2.y * v1.z + w2.z * v2.z + w2.w * v3.z;
  float s3 = cbv.w + w3.x * v0.w + w3.y * v1.w + w3.z * v2.w + w3.w * v3.w;
  s0 = s0 / (1.f + expf(-s0));
  s1 = s1 / (1.f + expf(-s1));
  s2 = s2 / (1.f + expf(-s2));
  s3 = s3 / (1.f + expf(-s3));
  *(float4*)(xbc + (size_t)token * XBC + c4) = make_float4(s0, s1, s2, s3);
}

// ---------------- dt = softplus(raw + bias), dA = exp(dt * -exp(A_log)) ----------------
__global__ __launch_bounds__(256) void dt_kernel(
    const float* __restrict__ zx, const float* __restrict__ dtb,
    const float* __restrict__ A_log, float* __restrict__ dtv, float* __restrict__ dAv) {
  int gid = blockIdx.x * 256 + threadIdx.x;  // T*8
  int token = gid >> 3, h = gid & 7;
  float raw = zx[(size_t)token * DIN + (DI + XBC) + h] + dtb[h];
  float dt = raw > 20.f ? raw : log1pf(expf(raw));
  dtv[gid] = dt;
  dAv[gid] = expf(-expf(A_log[h]) * dt);
}

// ---------------- sequential SSM scan, 8 waves = 2 head-groups x 4 n-quarters ----------------
// grid = 256 (one per b), 512 threads. Wave w: hg = w>>2 (heads hg*4..+3), q = w&3
// (n-quarter). Lane: p = lane&31, nh = lane>>5 -> 8 n's -> hs[4][8] states.
// Per-step n-partials go to yp LDS; per-8-group reduce sums 4 quarters, adds D*x,
// writes y into the x-slot of xbc. Token groups double-buffered, staged 1 tok/wave.
__global__ __launch_bounds__(512) void scan_kernel(
    const float* __restrict__ xbc, const float* __restrict__ dtv,
    const float* __restrict__ dAv, const float* __restrict__ Dp,
    float* __restrict__ yout) {
  const int b = blockIdx.x;
  const int tid = threadIdx.x;
  const int w = tid >> 6, lane = tid & 63;
  const int hg = w >> 2, q = w & 3;
  const int p = lane & 31, nh = lane >> 5;
  // token slot: [0..255]=x (h*32+p), [256..319]=B, [320..383]=C, [384..391]=dA, [392..399]=dt
  __shared__ float st[2][8][400];
  __shared__ float yp[8][8][128];   // [step][wave][p*4 + j]
  float hs[4][8];
#pragma unroll
  for (int j = 0; j < 4; ++j)
#pragma unroll
    for (int k = 0; k < 8; ++k) hs[j][k] = 0.f;
  // reduce-role constants (different decomposition of tid)
  const int rs = tid >> 6, rhg = (tid >> 5) & 1, rp = tid & 31;
  const float4 dpq = *(const float4*)(Dp + rhg * 4);

  float4 rA, rB; float sc = 0.f;

#define LOAD_GRP(g)                                                   \
  {                                                                   \
    int tok_ = b * 256 + (g) * 8 + w;                                 \
    const float* row_ = xbc + (size_t)tok_ * XBC;                     \
    rA = ((const float4*)row_)[lane];                                 \
    if (lane < 32) rB = ((const float4*)(row_ + 256))[lane];          \
    if (lane < 8) sc = dAv[tok_ * 8 + lane];                          \
    else if (lane < 16) sc = dtv[tok_ * 8 + lane - 8];                \
  }
#define WRITE_GRP(bf)                                                 \
  {                                                                   \
    float* sl_ = &st[bf][w][0];                                       \
    *(float4*)(sl_ + 4 * lane) = rA;                                  \
    if (lane < 32) *(float4*)(sl_ + 256 + 4 * lane) = rB;             \
    if (lane < 16) sl_[384 + lane] = sc;                              \
  }

  LOAD_GRP(0);
  WRITE_GRP(0);
  __syncthreads();
  LOAD_GRP(1);

  for (int g = 0; g < 32; ++g) {
    const int buf = g & 1;
#pragma unroll
    for (int s8 = 0; s8 < 8; ++s8) {
      const float* sl = &st[buf][s8][0];
      float4 dAq = *(const float4*)(sl + 384 + hg * 4);
      float4 dtq = *(const float4*)(sl + 392 + hg * 4);
      float xv0 = sl[(hg * 4 + 0) * 32 + p];
      float xv1 = sl[(hg * 4 + 1) * 32 + p];
      float xv2 = sl[(hg * 4 + 2) * 32 + p];
      float xv3 = sl[(hg * 4 + 3) * 32 + p];
      float c0 = dtq.x * xv0, c1 = dtq.y * xv1, c2 = dtq.z * xv2, c3 = dtq.w * xv3;
      const float* Bb = sl + 256 + q * 16 + nh * 8;
      const float* Cb = sl + 320 + q * 16 + nh * 8;
      float4 b0 = *(const float4*)(Bb), b1 = *(const float4*)(Bb + 4);
      float4 e0 = *(const float4*)(Cb), e1 = *(const float4*)(Cb + 4);
      float bn[8] = {b0.x, b0.y, b0.z, b0.w, b1.x, b1.y, b1.z, b1.w};
      float cn[8] = {e0.x, e0.y, e0.z, e0.w, e1.x, e1.y, e1.z, e1.w};
      float y0 = 0.f, y1 = 0.f, y2 = 0.f, y3 = 0.f;
#pragma unroll
      for (int k = 0; k < 8; ++k) {
        hs[0][k] = dAq.x * hs[0][k] + c0 * bn[k]; y0 += hs[0][k] * cn[k];
        hs[1][k] = dAq.y * hs[1][k] + c1 * bn[k]; y1 += hs[1][k] * cn[k];
        hs[2][k] = dAq.z * hs[2][k] + c2 * bn[k]; y2 += hs[2][k] * cn[k];
        hs[3][k] = dAq.w * hs[3][k] + c3 * bn[k]; y3 += hs[3][k] * cn[k];
      }
      y0 += __shfl_xor(y0, 32);
      y1 += __shfl_xor(y1, 32);
      y2 += __shfl_xor(y2, 32);
      y3 += __shfl_xor(y3, 32);
      if (nh == 0) *(float4*)&yp[s8][w][p * 4] = make_float4(y0, y1, y2, y3);
    }
    __syncthreads();
    // reduce 4 n-quarters + D*x, write y (into x-slot of xbc rows of group g)
    {
      int tok = b * 256 + g * 8 + rs;
      const float* slx = &st[buf][rs][0];
      float4 a0 = *(const float4*)&yp[rs][rhg * 4 + 0][rp * 4];
      float4 a1 = *(const float4*)&yp[rs][rhg * 4 + 1][rp * 4];
      float4 a2 = *(const float4*)&yp[rs][rhg * 4 + 2][rp * 4];
      float4 a3 = *(const float4*)&yp[rs][rhg * 4 + 3][rp * 4];
      float v0 = a0.x + a1.x + a2.x + a3.x + dpq.x * slx[(rhg * 4 + 0) * 32 + rp];
      float v1 = a0.y + a1.y + a2.y + a3.y + dpq.y * slx[(rhg * 4 + 1) * 32 + rp];
      float v2 = a0.z + a1.z + a2.z + a3.z + dpq.z * slx[(rhg * 4 + 2) * 32 + rp];
      float v3 = a0.w + a1.w + a2.w + a3.w + dpq.w * slx[(rhg * 4 + 3) * 32 + rp];
      float* yo = yout + (size_t)tok * XBC + rhg * 128;
      yo[0 * 32 + rp] = v0;
      yo[1 * 32 + rp] = v1;
      yo[2 * 32 + rp] = v2;
      yo[3 * 32 + rp] = v3;
    }
    if (g < 31) {
      WRITE_GRP(buf ^ 1);
      __syncthreads();
      if (g < 30) LOAD_GRP(g + 2);
    }
  }
#undef LOAD_GRP
#undef WRITE_GRP
}

// ---------------- y = rmsnorm(yraw * silu(z)) * nw -> bf16 ----------------
// yraw lives in xbc rows (stride XBC, first 256 floats).
__global__ __launch_bounds__(256) void gate_rms_kernel(
    const float* __restrict__ yraw, const float* __restrict__ zx,
    const float* __restrict__ nw, unsigned short* __restrict__ yout) {
  int wid = threadIdx.x >> 6, lane = threadIdx.x & 63;
  size_t token = (size_t)blockIdx.x * 4 + wid;
  float4 yv = *(const float4*)(yraw + token * XBC + lane * 4);
  float4 zv = *(const float4*)(zx + token * DIN + lane * 4);
  float g0 = yv.x * (zv.x / (1.f + expf(-zv.x)));
  float g1 = yv.y * (zv.y / (1.f + expf(-zv.y)));
  float g2 = yv.z * (zv.z / (1.f + expf(-zv.z)));
  float g3 = yv.w * (zv.w / (1.f + expf(-zv.w)));
  float ss = g0 * g0 + g1 * g1 + g2 * g2 + g3 * g3;
#pragma unroll
  for (int off = 1; off < 64; off <<= 1) ss += __shfl_xor(ss, off);
  float r = rsqrtf(ss * (1.f / 256.f) + EPSF);
  unsigned w0 = (unsigned short)f2bf(g0 * r * nw[lane * 4 + 0]);
  unsigned w1 = (unsigned short)f2bf(g1 * r * nw[lane * 4 + 1]);
  unsigned w2 = (unsigned short)f2bf(g2 * r * nw[lane * 4 + 2]);
  unsigned w3 = (unsigned short)f2bf(g3 * r * nw[lane * 4 + 3]);
  uint2 packed = make_uint2(w0 | (w1 << 16), w2 | (w3 << 16));
  *(uint2*)(yout + token * DI + lane * 4) = packed;
}

// ---------------- column mean over L (bf16 in) ----------------
__global__ __launch_bounds__(128) void colmean_kernel(const unsigned short* __restrict__ tn,
                                                      float* __restrict__ tmean) {
  int b = blockIdx.x, e = threadIdx.x;
  const unsigned short* p = tn + (size_t)b * 256 * 128 + e;
  float acc = 0.f;
  for (int l = 0; l < 256; ++l) acc += bf2f(p[l * 128]);
  tmean[b * 128 + e] = acc * (1.f / 256.f);
}

// ---------------- head matmul + L2 normalize ----------------
__global__ __launch_bounds__(128) void head_kernel(
    const float* __restrict__ tmean, const float* __restrict__ hw,
    const float* __restrict__ hb, float* __restrict__ out) {
  __shared__ float tm[128];
  __shared__ float red[2];
  int b = blockIdx.x, o = threadIdx.x;
  tm[o] = tmean[b * 128 + o];
  __syncthreads();
  float acc = hb[o];
  for (int e = 0; e < 128; ++e) acc += tm[e] * hw[o * 128 + e];
  float ss = acc * acc;
#pragma unroll
  for (int off = 1; off < 64; off <<= 1) ss += __shfl_xor(ss, off);
  if ((o & 63) == 0) red[o >> 6] = ss;
  __syncthreads();
  float nrm = fmaxf(sqrtf(red[0] + red[1]), 1e-12f);
  out[b * 128 + o] = acc / nrm;
}

extern "C" void kernel_launch(void* const* d_in, const int* in_sizes, int n_in,
                              void* d_out, int out_size, void* d_ws, size_t ws_size,
                              hipStream_t stream) {
  const float* x      = (const float*)d_in[0];
  const float* conv_w = (const float*)d_in[1];
  const float* conv_b = (const float*)d_in[2];
  const float* pe_w   = (const float*)d_in[3];
  const float* pe_b   = (const float*)d_in[4];
  const float* ln_w   = (const float*)d_in[5];
  const float* ln_b   = (const float*)d_in[6];
  const float* in_w   = (const float*)d_in[7];
  const float* c1w    = (const float*)d_in[8];
  const float* c1b    = (const float*)d_in[9];
  const float* dtb    = (const float*)d_in[10];
  const float* A_log  = (const float*)d_in[11];
  const float* Dp     = (const float*)d_in[12];
  const float* nw     = (const float*)d_in[13];
  const float* ow     = (const float*)d_in[14];
  const float* fn_w   = (const float*)d_in[15];
  const float* fn_b   = (const float*)d_in[16];
  const float* hw     = (const float*)d_in[17];
  const float* hb     = (const float*)d_in[18];
  float* out = (float*)d_out;

  const size_t T = TTOK;
  float* t_buf = (float*)d_ws;                               // T*128 f32
  unsigned* tnb = (unsigned*)(t_buf + T * 128);              // T*128 bf16 (T*64 u32)
  float* zx    = (float*)(tnb + T * 64);                     // T*648 f32
  float* xbc   = zx + T * DIN;                               // T*384 f32 (y reuses cols 0..255)
  float* dtv   = xbc + T * XBC;                              // T*8
  float* dAv   = dtv + T * 8;                                // T*8
  unsigned short* ybb = (unsigned short*)(dAv + T * 8);      // T*256 bf16
  float* tmean = (float*)(ybb + T * 256);                    // 256*128
  size_t need = 4 * (T * (size_t)(128 + 64 + 648 + 384 + 8 + 8 + 128) + 256 * 128);
  if (ws_size < need) return;  // workspace too small -> fail visibly

  // patch embed + bias, then pe layernorm (in place, fp32)
  gemm_bf16_patch<<<dim3(512, 1), 256, 0, stream>>>(x, conv_w, conv_b, t_buf);
  ln_kernel<<<16384, 256, 0, stream>>>(t_buf, t_buf, pe_w, pe_b);

  for (int i = 0; i < NL; ++i) {
    ln_bf16_kernel<<<16384, 256, 0, stream>>>(t_buf, tnb, ln_w + i * 128, ln_b + i * 128);
    gemm_bf16_nt_abf<<<dim3(512, 6), 256, 0, stream>>>(
        (const unsigned short*)tnb, in_w + (size_t)i * DIN * EE, zx, nullptr, nullptr, TTOK, DIN, EE);
    conv_silu_kernel<<<24576, 256, 0, stream>>>(zx, c1w + (size_t)i * XBC * DC, c1b + (size_t)i * XBC, xbc);
    dt_kernel<<<2048, 256, 0, stream>>>(zx, dtb + i * HH, A_log + i * HH, dtv, dAv);
    scan_kernel<<<256, 512, 0, stream>>>(xbc, dtv, dAv, Dp + i * HH, xbc);
    gate_rms_kernel<<<16384, 256, 0, stream>>>(xbc, zx, nw + i * DI, ybb);
    gemm_bf16_nt_abf<<<dim3(512, 1), 256, 0, stream>>>(
        ybb, ow + (size_t)i * EE * DI, t_buf, t_buf, nullptr, TTOK, EE, DI);
  }

  ln_bf16_kernel<<<16384, 256, 0, stream>>>(t_buf, tnb, fn_w, fn_b);
  colmean_kernel<<<256, 128, 0, stream>>>((const unsigned short*)tnb, tmean);
  head_kernel<<<256, 128, 0, stream>>>(tmean, hw, hb, out);
}

// Round 6
// 1371.332 us; speedup vs baseline: 1.9003x; 1.1347x over previous
//
#include <hip/hip_runtime.h>
#include <math.h>

// ---------------- constants ----------------
#define EE 128
#define DI 256
#define HH 8
#define PP 32
#define NN 64
#define DC 4
#define XBC 384
#define DIN 648
#define NL 4
#define LSEQ 256
#define BB 256
#define TTOK (BB * LSEQ)   // 65536 tokens
#define EPSF 1e-5f

typedef __attribute__((ext_vector_type(8))) short short8;
typedef __attribute__((ext_vector_type(4))) float f32x4;

__device__ inline short f2bf(float f) {
  unsigned u = __builtin_bit_cast(unsigned, f);
  u += 0x7fff + ((u >> 16) & 1);   // RNE
  return (short)(u >> 16);
}
__device__ inline float bf2f(unsigned short u) {
  unsigned x = ((unsigned)u) << 16;
  return __builtin_bit_cast(float, x);
}

// ---------------- bf16 MFMA GEMM, A bf16, fp32 out (+resid): out-proj ----------------
__global__ __launch_bounds__(256) void gemm_bf16_nt_abf(
    const unsigned short* __restrict__ A, const float* __restrict__ B,
    float* C, const float* resid, int M, int N, int K) {
  __shared__ short As[128][40];
  __shared__ short Bs[128][40];
  const int tid = threadIdx.x;
  const int lane = tid & 63, wid = tid >> 6;
  const int wm = wid >> 1, wn = wid & 1;
  const int m0 = blockIdx.x * 128, n0 = blockIdx.y * 128;
  const int r = tid >> 1, hf = tid & 1;
  const int lr = lane & 15, lk = (lane >> 4) * 8;
  f32x4 acc[4][4] = {};
  for (int k0 = 0; k0 < K; k0 += 32) {
    {
      const unsigned short* ap = A + (size_t)(m0 + r) * K + k0 + hf * 16;
      *(short8*)&As[r][hf * 16] = *(const short8*)(ap);
      *(short8*)&As[r][hf * 16 + 8] = *(const short8*)(ap + 8);
    }
    {
      short8 s0 = {}, s1 = {};
      if (n0 + r < N) {
        const float* bp = B + (size_t)(n0 + r) * K + k0 + hf * 16;
        float4 v0 = *(const float4*)(bp + 0);
        float4 v1 = *(const float4*)(bp + 4);
        float4 v2 = *(const float4*)(bp + 8);
        float4 v3 = *(const float4*)(bp + 12);
        s0[0] = f2bf(v0.x); s0[1] = f2bf(v0.y); s0[2] = f2bf(v0.z); s0[3] = f2bf(v0.w);
        s0[4] = f2bf(v1.x); s0[5] = f2bf(v1.y); s0[6] = f2bf(v1.z); s0[7] = f2bf(v1.w);
        s1[0] = f2bf(v2.x); s1[1] = f2bf(v2.y); s1[2] = f2bf(v2.z); s1[3] = f2bf(v2.w);
        s1[4] = f2bf(v3.x); s1[5] = f2bf(v3.y); s1[6] = f2bf(v3.z); s1[7] = f2bf(v3.w);
      }
      *(short8*)&Bs[r][hf * 16] = s0;
      *(short8*)&Bs[r][hf * 16 + 8] = s1;
    }
    __syncthreads();
    short8 af[4], bfr[4];
#pragma unroll
    for (int mi = 0; mi < 4; ++mi) af[mi] = *(const short8*)&As[wm * 64 + mi * 16 + lr][lk];
#pragma unroll
    for (int ni = 0; ni < 4; ++ni) bfr[ni] = *(const short8*)&Bs[wn * 64 + ni * 16 + lr][lk];
#pragma unroll
    for (int mi = 0; mi < 4; ++mi)
#pragma unroll
      for (int ni = 0; ni < 4; ++ni)
        acc[mi][ni] = __builtin_amdgcn_mfma_f32_16x16x32_bf16(af[mi], bfr[ni], acc[mi][ni], 0, 0, 0);
    __syncthreads();
  }
#pragma unroll
  for (int mi = 0; mi < 4; ++mi) {
#pragma unroll
    for (int ni = 0; ni < 4; ++ni) {
      int row0 = m0 + wm * 64 + mi * 16 + (lane >> 4) * 4;
      int col = n0 + wn * 64 + ni * 16 + (lane & 15);
      if (col < N) {
#pragma unroll
        for (int j = 0; j < 4; ++j) {
          size_t idx = (size_t)(row0 + j) * N + col;
          float v = acc[mi][ni][j];
          if (resid) v += resid[idx];
          C[idx] = v;
        }
      }
    }
  }
}

// ---------------- in-proj GEMM: bf16 out + fp32 dt side-channel (cols 640..647) ----------------
__global__ __launch_bounds__(256) void gemm_in_proj(
    const unsigned short* __restrict__ A, const float* __restrict__ B,
    unsigned short* __restrict__ Czx, float* __restrict__ dtraw,
    int M, int N, int K) {
  __shared__ short As[128][40];
  __shared__ short Bs[128][40];
  const int tid = threadIdx.x;
  const int lane = tid & 63, wid = tid >> 6;
  const int wm = wid >> 1, wn = wid & 1;
  const int m0 = blockIdx.x * 128, n0 = blockIdx.y * 128;
  const int r = tid >> 1, hf = tid & 1;
  const int lr = lane & 15, lk = (lane >> 4) * 8;
  f32x4 acc[4][4] = {};
  for (int k0 = 0; k0 < K; k0 += 32) {
    {
      const unsigned short* ap = A + (size_t)(m0 + r) * K + k0 + hf * 16;
      *(short8*)&As[r][hf * 16] = *(const short8*)(ap);
      *(short8*)&As[r][hf * 16 + 8] = *(const short8*)(ap + 8);
    }
    {
      short8 s0 = {}, s1 = {};
      if (n0 + r < N) {
        const float* bp = B + (size_t)(n0 + r) * K + k0 + hf * 16;
        float4 v0 = *(const float4*)(bp + 0);
        float4 v1 = *(const float4*)(bp + 4);
        float4 v2 = *(const float4*)(bp + 8);
        float4 v3 = *(const float4*)(bp + 12);
        s0[0] = f2bf(v0.x); s0[1] = f2bf(v0.y); s0[2] = f2bf(v0.z); s0[3] = f2bf(v0.w);
        s0[4] = f2bf(v1.x); s0[5] = f2bf(v1.y); s0[6] = f2bf(v1.z); s0[7] = f2bf(v1.w);
        s1[0] = f2bf(v2.x); s1[1] = f2bf(v2.y); s1[2] = f2bf(v2.z); s1[3] = f2bf(v2.w);
        s1[4] = f2bf(v3.x); s1[5] = f2bf(v3.y); s1[6] = f2bf(v3.z); s1[7] = f2bf(v3.w);
      }
      *(short8*)&Bs[r][hf * 16] = s0;
      *(short8*)&Bs[r][hf * 16 + 8] = s1;
    }
    __syncthreads();
    short8 af[4], bfr[4];
#pragma unroll
    for (int mi = 0; mi < 4; ++mi) af[mi] = *(const short8*)&As[wm * 64 + mi * 16 + lr][lk];
#pragma unroll
    for (int ni = 0; ni < 4; ++ni) bfr[ni] = *(const short8*)&Bs[wn * 64 + ni * 16 + lr][lk];
#pragma unroll
    for (int mi = 0; mi < 4; ++mi)
#pragma unroll
      for (int ni = 0; ni < 4; ++ni)
        acc[mi][ni] = __builtin_amdgcn_mfma_f32_16x16x32_bf16(af[mi], bfr[ni], acc[mi][ni], 0, 0, 0);
    __syncthreads();
  }
#pragma unroll
  for (int mi = 0; mi < 4; ++mi) {
#pragma unroll
    for (int ni = 0; ni < 4; ++ni) {
      int row0 = m0 + wm * 64 + mi * 16 + (lane >> 4) * 4;
      int col = n0 + wn * 64 + ni * 16 + (lane & 15);
      if (col < N) {
#pragma unroll
        for (int j = 0; j < 4; ++j) {
          int row = row0 + j;
          float v = acc[mi][ni][j];
          Czx[(size_t)row * DIN + col] = (unsigned short)f2bf(v);
          if (col >= DI + XBC) dtraw[(size_t)row * 8 + (col - (DI + XBC))] = v;
        }
      }
    }
  }
}

// ---------------- patch-embed bf16 MFMA GEMM ----------------
__global__ __launch_bounds__(256) void gemm_bf16_patch(
    const float* __restrict__ X, const float* __restrict__ B,
    const float* __restrict__ bias, float* __restrict__ C) {
  __shared__ short As[128][40];
  __shared__ short Bs[128][40];
  const int tid = threadIdx.x;
  const int lane = tid & 63, wid = tid >> 6;
  const int wm = wid >> 1, wn = wid & 1;
  const int m0 = blockIdx.x * 128;
  const int r = tid >> 1, hf = tid & 1;
  const int lr = lane & 15, lk = (lane >> 4) * 8;
  const int m = m0 + r;
  const int bb = m >> 8, px = (m >> 4) & 15, py = m & 15;
  f32x4 acc[4][4] = {};
  for (int k0 = 0; k0 < 768; k0 += 32) {
    int k = k0 + hf * 16;
    int c = k >> 8, dx = (k >> 4) & 15;
    {
      const float* ap = X + (((size_t)(bb * 3 + c) * 256 + px * 16 + dx) * 256 + py * 16);
      float4 v0 = *(const float4*)(ap + 0);
      float4 v1 = *(const float4*)(ap + 4);
      float4 v2 = *(const float4*)(ap + 8);
      float4 v3 = *(const float4*)(ap + 12);
      short8 s0, s1;
      s0[0] = f2bf(v0.x); s0[1] = f2bf(v0.y); s0[2] = f2bf(v0.z); s0[3] = f2bf(v0.w);
      s0[4] = f2bf(v1.x); s0[5] = f2bf(v1.y); s0[6] = f2bf(v1.z); s0[7] = f2bf(v1.w);
      s1[0] = f2bf(v2.x); s1[1] = f2bf(v2.y); s1[2] = f2bf(v2.z); s1[3] = f2bf(v2.w);
      s1[4] = f2bf(v3.x); s1[5] = f2bf(v3.y); s1[6] = f2bf(v3.z); s1[7] = f2bf(v3.w);
      *(short8*)&As[r][hf * 16] = s0;
      *(short8*)&As[r][hf * 16 + 8] = s1;
    }
    {
      const float* bp = B + (size_t)r * 768 + k;
      float4 v0 = *(const float4*)(bp + 0);
      float4 v1 = *(const float4*)(bp + 4);
      float4 v2 = *(const float4*)(bp + 8);
      float4 v3 = *(const float4*)(bp + 12);
      short8 s0, s1;
      s0[0] = f2bf(v0.x); s0[1] = f2bf(v0.y); s0[2] = f2bf(v0.z); s0[3] = f2bf(v0.w);
      s0[4] = f2bf(v1.x); s0[5] = f2bf(v1.y); s0[6] = f2bf(v1.z); s0[7] = f2bf(v1.w);
      s1[0] = f2bf(v2.x); s1[1] = f2bf(v2.y); s1[2] = f2bf(v2.z); s1[3] = f2bf(v2.w);
      s1[4] = f2bf(v3.x); s1[5] = f2bf(v3.y); s1[6] = f2bf(v3.z); s1[7] = f2bf(v3.w);
      *(short8*)&Bs[r][hf * 16] = s0;
      *(short8*)&Bs[r][hf * 16 + 8] = s1;
    }
    __syncthreads();
    short8 af[4], bfr[4];
#pragma unroll
    for (int mi = 0; mi < 4; ++mi) af[mi] = *(const short8*)&As[wm * 64 + mi * 16 + lr][lk];
#pragma unroll
    for (int ni = 0; ni < 4; ++ni) bfr[ni] = *(const short8*)&Bs[wn * 64 + ni * 16 + lr][lk];
#pragma unroll
    for (int mi = 0; mi < 4; ++mi)
#pragma unroll
      for (int ni = 0; ni < 4; ++ni)
        acc[mi][ni] = __builtin_amdgcn_mfma_f32_16x16x32_bf16(af[mi], bfr[ni], acc[mi][ni], 0, 0, 0);
    __syncthreads();
  }
#pragma unroll
  for (int mi = 0; mi < 4; ++mi) {
#pragma unroll
    for (int ni = 0; ni < 4; ++ni) {
      int row0 = m0 + wm * 64 + mi * 16 + (lane >> 4) * 4;
      int col = wn * 64 + ni * 16 + (lane & 15);
#pragma unroll
      for (int j = 0; j < 4; ++j)
        C[(size_t)(row0 + j) * 128 + col] = acc[mi][ni][j] + bias[col];
    }
  }
}

// ---------------- LayerNorm over E=128, fp32 out (PE only) ----------------
__global__ __launch_bounds__(256) void ln_kernel(const float* in, float* out,
                                                 const float* __restrict__ w, const float* __restrict__ b) {
  int wid = threadIdx.x >> 6, lane = threadIdx.x & 63;
  size_t token = (size_t)blockIdx.x * 4 + wid;
  const float* p = in + token * 128;
  float2 v = *(const float2*)(p + lane * 2);
  float s = v.x + v.y;
#pragma unroll
  for (int off = 1; off < 64; off <<= 1) s += __shfl_xor(s, off);
  float mu = s * (1.f / 128.f);
  float dx = v.x - mu, dy = v.y - mu;
  float vs = dx * dx + dy * dy;
#pragma unroll
  for (int off = 1; off < 64; off <<= 1) vs += __shfl_xor(vs, off);
  float r = rsqrtf(vs * (1.f / 128.f) + EPSF);
  float2 o;
  o.x = dx * r * w[lane * 2 + 0] + b[lane * 2 + 0];
  o.y = dy * r * w[lane * 2 + 1] + b[lane * 2 + 1];
  *(float2*)(out + token * 128 + lane * 2) = o;
}

// ---------------- LayerNorm over E=128, bf16-packed out ----------------
__global__ __launch_bounds__(256) void ln_bf16_kernel(const float* in, unsigned* out,
                                                      const float* __restrict__ w, const float* __restrict__ b) {
  int wid = threadIdx.x >> 6, lane = threadIdx.x & 63;
  size_t token = (size_t)blockIdx.x * 4 + wid;
  const float* p = in + token * 128;
  float2 v = *(const float2*)(p + lane * 2);
  float s = v.x + v.y;
#pragma unroll
  for (int off = 1; off < 64; off <<= 1) s += __shfl_xor(s, off);
  float mu = s * (1.f / 128.f);
  float dx = v.x - mu, dy = v.y - mu;
  float vs = dx * dx + dy * dy;
#pragma unroll
  for (int off = 1; off < 64; off <<= 1) vs += __shfl_xor(vs, off);
  float r = rsqrtf(vs * (1.f / 128.f) + EPSF);
  unsigned lo = (unsigned short)f2bf(dx * r * w[lane * 2 + 0] + b[lane * 2 + 0]);
  unsigned hi = (unsigned short)f2bf(dy * r * w[lane * 2 + 1] + b[lane * 2 + 1]);
  out[token * 64 + lane] = lo | (hi << 16);
}

// ---------------- causal conv1d (DC=4) + SiLU, bf16 in/out ----------------
__global__ __launch_bounds__(256) void conv_silu_kernel(
    const unsigned short* __restrict__ zx, const float* __restrict__ cw,
    const float* __restrict__ cb, unsigned short* __restrict__ xbc) {
  int gid = blockIdx.x * 256 + threadIdx.x;  // T*96
  int token = gid / 96;
  int c4 = (gid - token * 96) * 4;
  int l = token & 255;
  const unsigned short* base = zx + (size_t)token * DIN + DI + c4;
  ushort4 z4 = make_ushort4(0, 0, 0, 0);
  ushort4 u0 = (l >= 3) ? *(const ushort4*)(base - 3 * DIN) : z4;
  ushort4 u1 = (l >= 2) ? *(const ushort4*)(base - 2 * DIN) : z4;
  ushort4 u2 = (l >= 1) ? *(const ushort4*)(base - 1 * DIN) : z4;
  ushort4 u3 = *(const ushort4*)(base);
  float4 w0 = *(const float4*)(cw + (c4 + 0) * 4);
  float4 w1 = *(const float4*)(cw + (c4 + 1) * 4);
  float4 w2 = *(const float4*)(cw + (c4 + 2) * 4);
  float4 w3 = *(const float4*)(cw + (c4 + 3) * 4);
  float4 cbv = *(const float4*)(cb + c4);
  float s0 = cbv.x + w0.x * bf2f(u0.x) + w0.y * bf2f(u1.x) + w0.z * bf2f(u2.x) + w0.w * bf2f(u3.x);
  float s1 = cbv.y + w1.x * bf2f(u0.y) + w1.y * bf2f(u1.y) + w1.z * bf2f(u2.y) + w1.w * bf2f(u3.y);
  float s2 = cbv.z + w2.x * bf2f(u0.z) + w2.y * bf2f(u1.z) + w2.z * bf2f(u2.z) + w2.w * bf2f(u3.z);
  float s3 = cbv.w + w3.x * bf2f(u0.w) + w3.y * bf2f(u1.w) + w3.z * bf2f(u2.w) + w3.w * bf2f(u3.w);
  s0 = s0 / (1.f + expf(-s0));
  s1 = s1 / (1.f + expf(-s1));
  s2 = s2 / (1.f + expf(-s2));
  s3 = s3 / (1.f + expf(-s3));
  unsigned a0 = (unsigned short)f2bf(s0), a1 = (unsigned short)f2bf(s1);
  unsigned a2 = (unsigned short)f2bf(s2), a3 = (unsigned short)f2bf(s3);
  uint2 o = make_uint2(a0 | (a1 << 16), a2 | (a3 << 16));
  *(uint2*)(xbc + (size_t)token * XBC + c4) = o;
}

// ---------------- dt = softplus(raw + bias); ldA = -exp(A_log)*dt ----------------
__global__ __launch_bounds__(256) void dt_kernel(
    const float* __restrict__ dtraw, const float* __restrict__ dtb,
    const float* __restrict__ A_log, float* __restrict__ dtv, float* __restrict__ ldAv) {
  int gid = blockIdx.x * 256 + threadIdx.x;  // T*8
  int h = gid & 7;
  float raw = dtraw[gid] + dtb[h];
  float dt = raw > 20.f ? raw : log1pf(expf(raw));
  dtv[gid] = dt;
  ldAv[gid] = -expf(A_log[h]) * dt;
}

// ---------------- chunked SSM scan via MFMA ----------------
// grid = B*H = 2048 blocks, 256 threads (4 waves). Block owns (b, h); loops 4 chunks
// of 64 tokens. Per chunk: S = C@B^T (bf16 MFMA), P = mask(S)*exp(la_t-la_s)*dt_s,
// y = exp(la_t)*(C@h_in^T) + P@x + D*x, h = exp(la63)*h + x^T@(w_s*B).
__global__ __launch_bounds__(256) void scan_chunk_kernel(
    const unsigned short* __restrict__ xbc,  // [T][384] bf16
    const float* __restrict__ dtv,           // [T][8]
    const float* __restrict__ ldA,           // [T][8]
    const float* __restrict__ Dp,            // [8]
    float* __restrict__ ybuf) {              // [T][256]
  const int b = blockIdx.x >> 3, h = blockIdx.x & 7;
  const int tid = threadIdx.x;
  const int w = tid >> 6, lane = tid & 63;
  const int lr = lane & 15, lj = lane >> 4;
  __shared__ __align__(16) unsigned short Cb[64][72];
  __shared__ __align__(16) unsigned short Bb[64][72];
  __shared__ __align__(16) unsigned short Bw[64][72];
  __shared__ __align__(16) unsigned short Pb[64][72];
  __shared__ __align__(16) unsigned short xb[64][40];
  __shared__ __align__(16) unsigned short hb[32][72];
  __shared__ float la[64], dtc[64];
  // zero h (bf16 copy used as MFMA operand)
  for (int i = tid; i < 32 * 72 / 2; i += 256) ((unsigned*)hb)[i] = 0;
  f32x4 acc_h[4] = {};   // waves 0,1 own h rows p = w*16..w*16+15
  const float dph = Dp[h];
  __syncthreads();

  for (int c = 0; c < 4; ++c) {
    const int tok0 = b * 256 + c * 64;
    // ---- stage: la/dt prefix-scan (wave 0) + tiles ----
    if (w == 0) {
      float v = ldA[(size_t)(tok0 + lane) * 8 + h];
#pragma unroll
      for (int off = 1; off < 64; off <<= 1) {
        float u = __shfl_up(v, off);
        if (lane >= off) v += u;
      }
      la[lane] = v;
      dtc[lane] = dtv[(size_t)(tok0 + lane) * 8 + h];
    }
    for (int idx = tid; idx < 64 * 20; idx += 256) {
      int t = idx / 20, seg = idx % 20;
      const unsigned short* row = xbc + (size_t)(tok0 + t) * XBC;
      if (seg < 4)       *(short8*)&xb[t][seg * 8]        = *(const short8*)(row + h * 32 + seg * 8);
      else if (seg < 12) *(short8*)&Bb[t][(seg - 4) * 8]  = *(const short8*)(row + 256 + (seg - 4) * 8);
      else               *(short8*)&Cb[t][(seg - 12) * 8] = *(const short8*)(row + 320 + (seg - 12) * 8);
    }
    __syncthreads();
    // ---- S = C @ B^T : wave w owns rows t in [w*16, w*16+16), all 64 s ----
    short8 afC0 = *(const short8*)&Cb[w * 16 + lr][lj * 8];
    short8 afC1 = *(const short8*)&Cb[w * 16 + lr][32 + lj * 8];
    f32x4 acc_s[4] = {};
#pragma unroll
    for (int ni = 0; ni < 4; ++ni) {
      short8 bf0 = *(const short8*)&Bb[ni * 16 + lr][lj * 8];
      short8 bf1 = *(const short8*)&Bb[ni * 16 + lr][32 + lj * 8];
      acc_s[ni] = __builtin_amdgcn_mfma_f32_16x16x32_bf16(afC0, bf0, acc_s[ni], 0, 0, 0);
      acc_s[ni] = __builtin_amdgcn_mfma_f32_16x16x32_bf16(afC1, bf1, acc_s[ni], 0, 0, 0);
    }
    // ---- mask/weight -> Pb ; weighted B -> Bw ----
    float la63 = la[63];
#pragma unroll
    for (int ni = 0; ni < 4; ++ni) {
      int s = ni * 16 + lr;
      float las = la[s], dts = dtc[s];
#pragma unroll
      for (int j = 0; j < 4; ++j) {
        int t = w * 16 + lj * 4 + j;
        float pv = 0.f;
        if (s <= t) pv = acc_s[ni][j] * __expf(la[t] - las) * dts;
        Pb[t][s] = (unsigned short)f2bf(pv);
      }
    }
    {
      int s = tid >> 2, nq = (tid & 3) * 16;
      float wgt = __expf(la63 - la[s]) * dtc[s];
      short8 b0 = *(const short8*)&Bb[s][nq];
      short8 b1 = *(const short8*)&Bb[s][nq + 8];
      short8 o0, o1;
#pragma unroll
      for (int j = 0; j < 8; ++j) {
        o0[j] = f2bf(bf2f((unsigned short)b0[j]) * wgt);
        o1[j] = f2bf(bf2f((unsigned short)b1[j]) * wgt);
      }
      *(short8*)&Bw[s][nq] = o0;
      *(short8*)&Bw[s][nq + 8] = o1;
    }
    __syncthreads();
    // ---- y = exp(la_t)*(C@h^T) + P@x ; h-update (waves 0,1) ----
    f32x4 acc_y[2] = {};
#pragma unroll
    for (int ni = 0; ni < 2; ++ni) {
      short8 hf0 = *(const short8*)&hb[ni * 16 + lr][lj * 8];
      short8 hf1 = *(const short8*)&hb[ni * 16 + lr][32 + lj * 8];
      acc_y[ni] = __builtin_amdgcn_mfma_f32_16x16x32_bf16(afC0, hf0, acc_y[ni], 0, 0, 0);
      acc_y[ni] = __builtin_amdgcn_mfma_f32_16x16x32_bf16(afC1, hf1, acc_y[ni], 0, 0, 0);
    }
#pragma unroll
    for (int j = 0; j < 4; ++j) {
      float at = __expf(la[w * 16 + lj * 4 + j]);
      acc_y[0][j] *= at;
      acc_y[1][j] *= at;
    }
    {
      short8 afP0 = *(const short8*)&Pb[w * 16 + lr][lj * 8];
      short8 afP1 = *(const short8*)&Pb[w * 16 + lr][32 + lj * 8];
#pragma unroll
      for (int ni = 0; ni < 2; ++ni) {
        short8 xf0, xf1;
#pragma unroll
        for (int j = 0; j < 8; ++j) {
          xf0[j] = (short)xb[lj * 8 + j][ni * 16 + lr];
          xf1[j] = (short)xb[32 + lj * 8 + j][ni * 16 + lr];
        }
        acc_y[ni] = __builtin_amdgcn_mfma_f32_16x16x32_bf16(afP0, xf0, acc_y[ni], 0, 0, 0);
        acc_y[ni] = __builtin_amdgcn_mfma_f32_16x16x32_bf16(afP1, xf1, acc_y[ni], 0, 0, 0);
      }
    }
    if (w < 2) {
      float aend = __expf(la63);
      short8 axf0, axf1;
#pragma unroll
      for (int j = 0; j < 8; ++j) {
        axf0[j] = (short)xb[lj * 8 + j][w * 16 + lr];
        axf1[j] = (short)xb[32 + lj * 8 + j][w * 16 + lr];
      }
#pragma unroll
      for (int ni = 0; ni < 4; ++ni) {
#pragma unroll
        for (int j = 0; j < 4; ++j) acc_h[ni][j] *= aend;
        short8 bw0, bw1;
#pragma unroll
        for (int j = 0; j < 8; ++j) {
          bw0[j] = (short)Bw[lj * 8 + j][ni * 16 + lr];
          bw1[j] = (short)Bw[32 + lj * 8 + j][ni * 16 + lr];
        }
        acc_h[ni] = __builtin_amdgcn_mfma_f32_16x16x32_bf16(axf0, bw0, acc_h[ni], 0, 0, 0);
        acc_h[ni] = __builtin_amdgcn_mfma_f32_16x16x32_bf16(axf1, bw1, acc_h[ni], 0, 0, 0);
      }
    }
    // ---- y epilogue: += D*x, global write ----
#pragma unroll
    for (int ni = 0; ni < 2; ++ni) {
#pragma unroll
      for (int j = 0; j < 4; ++j) {
        int t = w * 16 + lj * 4 + j;
        int p = ni * 16 + lr;
        float yv = acc_y[ni][j] + dph * bf2f(xb[t][p]);
        ybuf[(size_t)(tok0 + t) * DI + h * 32 + p] = yv;
      }
    }
    __syncthreads();
    // ---- write new h (bf16) for next chunk's y_inter ----
    if (w < 2) {
#pragma unroll
      for (int ni = 0; ni < 4; ++ni)
#pragma unroll
        for (int j = 0; j < 4; ++j)
          hb[w * 16 + lj * 4 + j][ni * 16 + lr] = (unsigned short)f2bf(acc_h[ni][j]);
    }
    __syncthreads();
  }
}

// ---------------- y = rmsnorm(yraw * silu(z)) * nw -> bf16 ----------------
__global__ __launch_bounds__(256) void gate_rms_kernel(
    const float* __restrict__ yraw, const unsigned short* __restrict__ zx,
    const float* __restrict__ nw, unsigned short* __restrict__ yout) {
  int wid = threadIdx.x >> 6, lane = threadIdx.x & 63;
  size_t token = (size_t)blockIdx.x * 4 + wid;
  float4 yv = *(const float4*)(yraw + token * DI + lane * 4);
  ushort4 zu = *(const ushort4*)(zx + token * DIN + lane * 4);
  float z0 = bf2f(zu.x), z1 = bf2f(zu.y), z2 = bf2f(zu.z), z3 = bf2f(zu.w);
  float g0 = yv.x * (z0 / (1.f + expf(-z0)));
  float g1 = yv.y * (z1 / (1.f + expf(-z1)));
  float g2 = yv.z * (z2 / (1.f + expf(-z2)));
  float g3 = yv.w * (z3 / (1.f + expf(-z3)));
  float ss = g0 * g0 + g1 * g1 + g2 * g2 + g3 * g3;
#pragma unroll
  for (int off = 1; off < 64; off <<= 1) ss += __shfl_xor(ss, off);
  float r = rsqrtf(ss * (1.f / 256.f) + EPSF);
  unsigned w0 = (unsigned short)f2bf(g0 * r * nw[lane * 4 + 0]);
  unsigned w1 = (unsigned short)f2bf(g1 * r * nw[lane * 4 + 1]);
  unsigned w2 = (unsigned short)f2bf(g2 * r * nw[lane * 4 + 2]);
  unsigned w3 = (unsigned short)f2bf(g3 * r * nw[lane * 4 + 3]);
  uint2 packed = make_uint2(w0 | (w1 << 16), w2 | (w3 << 16));
  *(uint2*)(yout + token * DI + lane * 4) = packed;
}

// ---------------- column mean over L (bf16 in) ----------------
__global__ __launch_bounds__(128) void colmean_kernel(const unsigned short* __restrict__ tn,
                                                      float* __restrict__ tmean) {
  int b = blockIdx.x, e = threadIdx.x;
  const unsigned short* p = tn + (size_t)b * 256 * 128 + e;
  float acc = 0.f;
  for (int l = 0; l < 256; ++l) acc += bf2f(p[l * 128]);
  tmean[b * 128 + e] = acc * (1.f / 256.f);
}

// ---------------- head matmul + L2 normalize ----------------
__global__ __launch_bounds__(128) void head_kernel(
    const float* __restrict__ tmean, const float* __restrict__ hw,
    const float* __restrict__ hb, float* __restrict__ out) {
  __shared__ float tm[128];
  __shared__ float red[2];
  int b = blockIdx.x, o = threadIdx.x;
  tm[o] = tmean[b * 128 + o];
  __syncthreads();
  float acc = hb[o];
  for (int e = 0; e < 128; ++e) acc += tm[e] * hw[o * 128 + e];
  float ss = acc * acc;
#pragma unroll
  for (int off = 1; off < 64; off <<= 1) ss += __shfl_xor(ss, off);
  if ((o & 63) == 0) red[o >> 6] = ss;
  __syncthreads();
  float nrm = fmaxf(sqrtf(red[0] + red[1]), 1e-12f);
  out[b * 128 + o] = acc / nrm;
}

extern "C" void kernel_launch(void* const* d_in, const int* in_sizes, int n_in,
                              void* d_out, int out_size, void* d_ws, size_t ws_size,
                              hipStream_t stream) {
  const float* x      = (const float*)d_in[0];
  const float* conv_w = (const float*)d_in[1];
  const float* conv_b = (const float*)d_in[2];
  const float* pe_w   = (const float*)d_in[3];
  const float* pe_b   = (const float*)d_in[4];
  const float* ln_w   = (const float*)d_in[5];
  const float* ln_b   = (const float*)d_in[6];
  const float* in_w   = (const float*)d_in[7];
  const float* c1w    = (const float*)d_in[8];
  const float* c1b    = (const float*)d_in[9];
  const float* dtb    = (const float*)d_in[10];
  const float* A_log  = (const float*)d_in[11];
  const float* Dp     = (const float*)d_in[12];
  const float* nw     = (const float*)d_in[13];
  const float* ow     = (const float*)d_in[14];
  const float* fn_w   = (const float*)d_in[15];
  const float* fn_b   = (const float*)d_in[16];
  const float* hw     = (const float*)d_in[17];
  const float* hb     = (const float*)d_in[18];
  float* out = (float*)d_out;

  const size_t T = TTOK;
  char* w8 = (char*)d_ws;
  float*          t_buf = (float*)w8;            w8 += T * 128 * 4;   // residual fp32
  unsigned*       tnb   = (unsigned*)w8;         w8 += T * 128 * 2;   // ln out bf16
  unsigned short* zx    = (unsigned short*)w8;   w8 += T * (size_t)DIN * 2; // in-proj bf16
  unsigned short* xbc   = (unsigned short*)w8;   w8 += T * (size_t)XBC * 2; // conv out bf16
  float*          dtraw = (float*)w8;            w8 += T * 8 * 4;
  float*          dtv   = (float*)w8;            w8 += T * 8 * 4;
  float*          ldAv  = (float*)w8;            w8 += T * 8 * 4;
  float*          ybuf  = (float*)w8;            w8 += T * (size_t)DI * 4;  // scan out fp32
  unsigned short* ybb   = (unsigned short*)w8;   w8 += T * (size_t)DI * 2;  // gated bf16
  float*          tmean = (float*)w8;            w8 += 256 * 128 * 4;
  if ((size_t)(w8 - (char*)d_ws) > ws_size) return;  // workspace too small

  // patch embed + bias, then pe layernorm (in place, fp32)
  gemm_bf16_patch<<<dim3(512, 1), 256, 0, stream>>>(x, conv_w, conv_b, t_buf);
  ln_kernel<<<16384, 256, 0, stream>>>(t_buf, t_buf, pe_w, pe_b);

  for (int i = 0; i < NL; ++i) {
    ln_bf16_kernel<<<16384, 256, 0, stream>>>(t_buf, tnb, ln_w + i * 128, ln_b + i * 128);
    gemm_in_proj<<<dim3(512, 6), 256, 0, stream>>>(
        (const unsigned short*)tnb, in_w + (size_t)i * DIN * EE, zx, dtraw, TTOK, DIN, EE);
    conv_silu_kernel<<<24576, 256, 0, stream>>>(zx, c1w + (size_t)i * XBC * DC, c1b + (size_t)i * XBC, xbc);
    dt_kernel<<<2048, 256, 0, stream>>>(dtraw, dtb + i * HH, A_log + i * HH, dtv, ldAv);
    scan_chunk_kernel<<<2048, 256, 0, stream>>>(xbc, dtv, ldAv, Dp + i * HH, ybuf);
    gate_rms_kernel<<<16384, 256, 0, stream>>>(ybuf, zx, nw + i * DI, ybb);
    gemm_bf16_nt_abf<<<dim3(512, 1), 256, 0, stream>>>(
        ybb, ow + (size_t)i * EE * DI, t_buf, t_buf, TTOK, EE, DI);
  }

  ln_bf16_kernel<<<16384, 256, 0, stream>>>(t_buf, tnb, fn_w, fn_b);
  colmean_kernel<<<256, 128, 0, stream>>>((const unsigned short*)tnb, tmean);
  head_kernel<<<256, 128, 0, stream>>>(tmean, hw, hb, out);
}

// Round 7
// 1263.191 us; speedup vs baseline: 2.0630x; 1.0856x over previous
//
#include <hip/hip_runtime.h>
#include <math.h>

// ---------------- constants ----------------
#define EE 128
#define DI 256
#define HH 8
#define PP 32
#define NN 64
#define DC 4
#define XBC 384
#define DIN 648
#define NL 4
#define LSEQ 256
#define BB 256
#define TTOK (BB * LSEQ)   // 65536 tokens
#define EPSF 1e-5f

typedef __attribute__((ext_vector_type(8))) short short8;
typedef __attribute__((ext_vector_type(4))) float f32x4;

__device__ inline short f2bf(float f) {
  unsigned u = __builtin_bit_cast(unsigned, f);
  u += 0x7fff + ((u >> 16) & 1);   // RNE
  return (short)(u >> 16);
}
__device__ inline float bf2f(unsigned short u) {
  unsigned x = ((unsigned)u) << 16;
  return __builtin_bit_cast(float, x);
}

// ---------------- one-shot weight conversion fp32 -> bf16 ----------------
__global__ __launch_bounds__(256) void cvt_w_kernel(
    const float* __restrict__ in_w, const float* __restrict__ ow,
    unsigned short* __restrict__ in_wb, unsigned short* __restrict__ owb) {
  int i = blockIdx.x * 256 + threadIdx.x;   // grid covers NL*DIN*EE = 331776
  in_wb[i] = (unsigned short)f2bf(in_w[i]);
  if (i < NL * EE * DI) owb[i] = (unsigned short)f2bf(ow[i]);
}

// ---------------- bf16 MFMA GEMM, A and B bf16, fp32 out (+resid): out-proj ----------------
__global__ __launch_bounds__(256) void gemm_bf16_nt_abf(
    const unsigned short* __restrict__ A, const unsigned short* __restrict__ B,
    float* C, const float* resid, int M, int N, int K) {
  __shared__ short As[128][40];
  __shared__ short Bs[128][40];
  const int tid = threadIdx.x;
  const int lane = tid & 63, wid = tid >> 6;
  const int wm = wid >> 1, wn = wid & 1;
  const int m0 = blockIdx.x * 128, n0 = blockIdx.y * 128;
  const int r = tid >> 1, hf = tid & 1;
  const int lr = lane & 15, lk = (lane >> 4) * 8;
  f32x4 acc[4][4] = {};
  for (int k0 = 0; k0 < K; k0 += 32) {
    {
      const unsigned short* ap = A + (size_t)(m0 + r) * K + k0 + hf * 16;
      *(short8*)&As[r][hf * 16] = *(const short8*)(ap);
      *(short8*)&As[r][hf * 16 + 8] = *(const short8*)(ap + 8);
    }
    {
      short8 s0 = {}, s1 = {};
      if (n0 + r < N) {
        const unsigned short* bp = B + (size_t)(n0 + r) * K + k0 + hf * 16;
        s0 = *(const short8*)(bp);
        s1 = *(const short8*)(bp + 8);
      }
      *(short8*)&Bs[r][hf * 16] = s0;
      *(short8*)&Bs[r][hf * 16 + 8] = s1;
    }
    __syncthreads();
    short8 af[4], bfr[4];
#pragma unroll
    for (int mi = 0; mi < 4; ++mi) af[mi] = *(const short8*)&As[wm * 64 + mi * 16 + lr][lk];
#pragma unroll
    for (int ni = 0; ni < 4; ++ni) bfr[ni] = *(const short8*)&Bs[wn * 64 + ni * 16 + lr][lk];
#pragma unroll
    for (int mi = 0; mi < 4; ++mi)
#pragma unroll
      for (int ni = 0; ni < 4; ++ni)
        acc[mi][ni] = __builtin_amdgcn_mfma_f32_16x16x32_bf16(af[mi], bfr[ni], acc[mi][ni], 0, 0, 0);
    __syncthreads();
  }
#pragma unroll
  for (int mi = 0; mi < 4; ++mi) {
#pragma unroll
    for (int ni = 0; ni < 4; ++ni) {
      int row0 = m0 + wm * 64 + mi * 16 + (lane >> 4) * 4;
      int col = n0 + wn * 64 + ni * 16 + (lane & 15);
      if (col < N) {
#pragma unroll
        for (int j = 0; j < 4; ++j) {
          size_t idx = (size_t)(row0 + j) * N + col;
          float v = acc[mi][ni][j];
          if (resid) v += resid[idx];
          C[idx] = v;
        }
      }
    }
  }
}

// ---------------- in-proj GEMM: bf16 A,B; bf16 out + fp32 dt side-channel ----------------
__global__ __launch_bounds__(256) void gemm_in_proj(
    const unsigned short* __restrict__ A, const unsigned short* __restrict__ B,
    unsigned short* __restrict__ Czx, float* __restrict__ dtraw,
    int M, int N, int K) {
  __shared__ short As[128][40];
  __shared__ short Bs[128][40];
  const int tid = threadIdx.x;
  const int lane = tid & 63, wid = tid >> 6;
  const int wm = wid >> 1, wn = wid & 1;
  const int m0 = blockIdx.x * 128, n0 = blockIdx.y * 128;
  const int r = tid >> 1, hf = tid & 1;
  const int lr = lane & 15, lk = (lane >> 4) * 8;
  f32x4 acc[4][4] = {};
  for (int k0 = 0; k0 < K; k0 += 32) {
    {
      const unsigned short* ap = A + (size_t)(m0 + r) * K + k0 + hf * 16;
      *(short8*)&As[r][hf * 16] = *(const short8*)(ap);
      *(short8*)&As[r][hf * 16 + 8] = *(const short8*)(ap + 8);
    }
    {
      short8 s0 = {}, s1 = {};
      if (n0 + r < N) {
        const unsigned short* bp = B + (size_t)(n0 + r) * K + k0 + hf * 16;
        s0 = *(const short8*)(bp);
        s1 = *(const short8*)(bp + 8);
      }
      *(short8*)&Bs[r][hf * 16] = s0;
      *(short8*)&Bs[r][hf * 16 + 8] = s1;
    }
    __syncthreads();
    short8 af[4], bfr[4];
#pragma unroll
    for (int mi = 0; mi < 4; ++mi) af[mi] = *(const short8*)&As[wm * 64 + mi * 16 + lr][lk];
#pragma unroll
    for (int ni = 0; ni < 4; ++ni) bfr[ni] = *(const short8*)&Bs[wn * 64 + ni * 16 + lr][lk];
#pragma unroll
    for (int mi = 0; mi < 4; ++mi)
#pragma unroll
      for (int ni = 0; ni < 4; ++ni)
        acc[mi][ni] = __builtin_amdgcn_mfma_f32_16x16x32_bf16(af[mi], bfr[ni], acc[mi][ni], 0, 0, 0);
    __syncthreads();
  }
#pragma unroll
  for (int mi = 0; mi < 4; ++mi) {
#pragma unroll
    for (int ni = 0; ni < 4; ++ni) {
      int row0 = m0 + wm * 64 + mi * 16 + (lane >> 4) * 4;
      int col = n0 + wn * 64 + ni * 16 + (lane & 15);
      if (col < N) {
#pragma unroll
        for (int j = 0; j < 4; ++j) {
          int row = row0 + j;
          float v = acc[mi][ni][j];
          Czx[(size_t)row * DIN + col] = (unsigned short)f2bf(v);
          if (col >= DI + XBC) dtraw[(size_t)row * 8 + (col - (DI + XBC))] = v;
        }
      }
    }
  }
}

// ---------------- patch-embed bf16 MFMA GEMM ----------------
__global__ __launch_bounds__(256) void gemm_bf16_patch(
    const float* __restrict__ X, const float* __restrict__ B,
    const float* __restrict__ bias, float* __restrict__ C) {
  __shared__ short As[128][40];
  __shared__ short Bs[128][40];
  const int tid = threadIdx.x;
  const int lane = tid & 63, wid = tid >> 6;
  const int wm = wid >> 1, wn = wid & 1;
  const int m0 = blockIdx.x * 128;
  const int r = tid >> 1, hf = tid & 1;
  const int lr = lane & 15, lk = (lane >> 4) * 8;
  const int m = m0 + r;
  const int bb = m >> 8, px = (m >> 4) & 15, py = m & 15;
  f32x4 acc[4][4] = {};
  for (int k0 = 0; k0 < 768; k0 += 32) {
    int k = k0 + hf * 16;
    int c = k >> 8, dx = (k >> 4) & 15;
    {
      const float* ap = X + (((size_t)(bb * 3 + c) * 256 + px * 16 + dx) * 256 + py * 16);
      float4 v0 = *(const float4*)(ap + 0);
      float4 v1 = *(const float4*)(ap + 4);
      float4 v2 = *(const float4*)(ap + 8);
      float4 v3 = *(const float4*)(ap + 12);
      short8 s0, s1;
      s0[0] = f2bf(v0.x); s0[1] = f2bf(v0.y); s0[2] = f2bf(v0.z); s0[3] = f2bf(v0.w);
      s0[4] = f2bf(v1.x); s0[5] = f2bf(v1.y); s0[6] = f2bf(v1.z); s0[7] = f2bf(v1.w);
      s1[0] = f2bf(v2.x); s1[1] = f2bf(v2.y); s1[2] = f2bf(v2.z); s1[3] = f2bf(v2.w);
      s1[4] = f2bf(v3.x); s1[5] = f2bf(v3.y); s1[6] = f2bf(v3.z); s1[7] = f2bf(v3.w);
      *(short8*)&As[r][hf * 16] = s0;
      *(short8*)&As[r][hf * 16 + 8] = s1;
    }
    {
      const float* bp = B + (size_t)r * 768 + k;
      float4 v0 = *(const float4*)(bp + 0);
      float4 v1 = *(const float4*)(bp + 4);
      float4 v2 = *(const float4*)(bp + 8);
      float4 v3 = *(const float4*)(bp + 12);
      short8 s0, s1;
      s0[0] = f2bf(v0.x); s0[1] = f2bf(v0.y); s0[2] = f2bf(v0.z); s0[3] = f2bf(v0.w);
      s0[4] = f2bf(v1.x); s0[5] = f2bf(v1.y); s0[6] = f2bf(v1.z); s0[7] = f2bf(v1.w);
      s1[0] = f2bf(v2.x); s1[1] = f2bf(v2.y); s1[2] = f2bf(v2.z); s1[3] = f2bf(v2.w);
      s1[4] = f2bf(v3.x); s1[5] = f2bf(v3.y); s1[6] = f2bf(v3.z); s1[7] = f2bf(v3.w);
      *(short8*)&Bs[r][hf * 16] = s0;
      *(short8*)&Bs[r][hf * 16 + 8] = s1;
    }
    __syncthreads();
    short8 af[4], bfr[4];
#pragma unroll
    for (int mi = 0; mi < 4; ++mi) af[mi] = *(const short8*)&As[wm * 64 + mi * 16 + lr][lk];
#pragma unroll
    for (int ni = 0; ni < 4; ++ni) bfr[ni] = *(const short8*)&Bs[wn * 64 + ni * 16 + lr][lk];
#pragma unroll
    for (int mi = 0; mi < 4; ++mi)
#pragma unroll
      for (int ni = 0; ni < 4; ++ni)
        acc[mi][ni] = __builtin_amdgcn_mfma_f32_16x16x32_bf16(af[mi], bfr[ni], acc[mi][ni], 0, 0, 0);
    __syncthreads();
  }
#pragma unroll
  for (int mi = 0; mi < 4; ++mi) {
#pragma unroll
    for (int ni = 0; ni < 4; ++ni) {
      int row0 = m0 + wm * 64 + mi * 16 + (lane >> 4) * 4;
      int col = wn * 64 + ni * 16 + (lane & 15);
#pragma unroll
      for (int j = 0; j < 4; ++j)
        C[(size_t)(row0 + j) * 128 + col] = acc[mi][ni][j] + bias[col];
    }
  }
}

// ---------------- LayerNorm over E=128, fp32 out (PE only) ----------------
__global__ __launch_bounds__(256) void ln_kernel(const float* in, float* out,
                                                 const float* __restrict__ w, const float* __restrict__ b) {
  int wid = threadIdx.x >> 6, lane = threadIdx.x & 63;
  size_t token = (size_t)blockIdx.x * 4 + wid;
  const float* p = in + token * 128;
  float2 v = *(const float2*)(p + lane * 2);
  float s = v.x + v.y;
#pragma unroll
  for (int off = 1; off < 64; off <<= 1) s += __shfl_xor(s, off);
  float mu = s * (1.f / 128.f);
  float dx = v.x - mu, dy = v.y - mu;
  float vs = dx * dx + dy * dy;
#pragma unroll
  for (int off = 1; off < 64; off <<= 1) vs += __shfl_xor(vs, off);
  float r = rsqrtf(vs * (1.f / 128.f) + EPSF);
  float2 o;
  o.x = dx * r * w[lane * 2 + 0] + b[lane * 2 + 0];
  o.y = dy * r * w[lane * 2 + 1] + b[lane * 2 + 1];
  *(float2*)(out + token * 128 + lane * 2) = o;
}

// ---------------- LayerNorm over E=128, bf16-packed out ----------------
__global__ __launch_bounds__(256) void ln_bf16_kernel(const float* in, unsigned* out,
                                                      const float* __restrict__ w, const float* __restrict__ b) {
  int wid = threadIdx.x >> 6, lane = threadIdx.x & 63;
  size_t token = (size_t)blockIdx.x * 4 + wid;
  const float* p = in + token * 128;
  float2 v = *(const float2*)(p + lane * 2);
  float s = v.x + v.y;
#pragma unroll
  for (int off = 1; off < 64; off <<= 1) s += __shfl_xor(s, off);
  float mu = s * (1.f / 128.f);
  float dx = v.x - mu, dy = v.y - mu;
  float vs = dx * dx + dy * dy;
#pragma unroll
  for (int off = 1; off < 64; off <<= 1) vs += __shfl_xor(vs, off);
  float r = rsqrtf(vs * (1.f / 128.f) + EPSF);
  unsigned lo = (unsigned short)f2bf(dx * r * w[lane * 2 + 0] + b[lane * 2 + 0]);
  unsigned hi = (unsigned short)f2bf(dy * r * w[lane * 2 + 1] + b[lane * 2 + 1]);
  out[token * 64 + lane] = lo | (hi << 16);
}

// ---------------- causal conv1d (DC=4) + SiLU, bf16 in/out ----------------
__global__ __launch_bounds__(256) void conv_silu_kernel(
    const unsigned short* __restrict__ zx, const float* __restrict__ cw,
    const float* __restrict__ cb, unsigned short* __restrict__ xbc) {
  int gid = blockIdx.x * 256 + threadIdx.x;  // T*96
  int token = gid / 96;
  int c4 = (gid - token * 96) * 4;
  int l = token & 255;
  const unsigned short* base = zx + (size_t)token * DIN + DI + c4;
  ushort4 z4 = make_ushort4(0, 0, 0, 0);
  ushort4 u0 = (l >= 3) ? *(const ushort4*)(base - 3 * DIN) : z4;
  ushort4 u1 = (l >= 2) ? *(const ushort4*)(base - 2 * DIN) : z4;
  ushort4 u2 = (l >= 1) ? *(const ushort4*)(base - 1 * DIN) : z4;
  ushort4 u3 = *(const ushort4*)(base);
  float4 w0 = *(const float4*)(cw + (c4 + 0) * 4);
  float4 w1 = *(const float4*)(cw + (c4 + 1) * 4);
  float4 w2 = *(const float4*)(cw + (c4 + 2) * 4);
  float4 w3 = *(const float4*)(cw + (c4 + 3) * 4);
  float4 cbv = *(const float4*)(cb + c4);
  float s0 = cbv.x + w0.x * bf2f(u0.x) + w0.y * bf2f(u1.x) + w0.z * bf2f(u2.x) + w0.w * bf2f(u3.x);
  float s1 = cbv.y + w1.x * bf2f(u0.y) + w1.y * bf2f(u1.y) + w1.z * bf2f(u2.y) + w1.w * bf2f(u3.y);
  float s2 = cbv.z + w2.x * bf2f(u0.z) + w2.y * bf2f(u1.z) + w2.z * bf2f(u2.z) + w2.w * bf2f(u3.z);
  float s3 = cbv.w + w3.x * bf2f(u0.w) + w3.y * bf2f(u1.w) + w3.z * bf2f(u2.w) + w3.w * bf2f(u3.w);
  s0 = s0 / (1.f + expf(-s0));
  s1 = s1 / (1.f + expf(-s1));
  s2 = s2 / (1.f + expf(-s2));
  s3 = s3 / (1.f + expf(-s3));
  unsigned a0 = (unsigned short)f2bf(s0), a1 = (unsigned short)f2bf(s1);
  unsigned a2 = (unsigned short)f2bf(s2), a3 = (unsigned short)f2bf(s3);
  uint2 o = make_uint2(a0 | (a1 << 16), a2 | (a3 << 16));
  *(uint2*)(xbc + (size_t)token * XBC + c4) = o;
}

// ---------------- dt = softplus(raw + bias); ldA = -exp(A_log)*dt ----------------
__global__ __launch_bounds__(256) void dt_kernel(
    const float* __restrict__ dtraw, const float* __restrict__ dtb,
    const float* __restrict__ A_log, float* __restrict__ dtv, float* __restrict__ ldAv) {
  int gid = blockIdx.x * 256 + threadIdx.x;  // T*8
  int h = gid & 7;
  float raw = dtraw[gid] + dtb[h];
  float dt = raw > 20.f ? raw : log1pf(expf(raw));
  dtv[gid] = dt;
  ldAv[gid] = -expf(A_log[h]) * dt;
}

// ---------------- chunked SSM scan via MFMA (b128-operand version) ----------------
// grid = 2048; b = bid&255, h = bid>>8 (same-b heads share an XCD under round-robin).
// 256 threads (4 waves). Per chunk of 64 tokens:
//   phase1: S = C@B^T (Cb,Bb rows) and y_inter = C@h^T (hbT[p][n] rows)
//   P = mask(S)*exp(la_t-la_s)*dt_s  -> written into Cb (aliased, Cb reads done)
//   phase2: y += P@x (xT[p][t] rows as B-frag); h = exp(la63)*h + (x*wt)^T@B (BbT rows)
// All MFMA operand reads are contiguous ds_read_b128; transposes done at staging writes.
__global__ __launch_bounds__(256, 4) void scan_chunk_kernel(
    const unsigned short* __restrict__ xbc,  // [T][384] bf16
    const float* __restrict__ dtv,           // [T][8]
    const float* __restrict__ ldA,           // [T][8]
    const float* __restrict__ Dp,            // [8]
    float* __restrict__ ybuf) {              // [T][256] fp32
  const int b = blockIdx.x & 255, h = blockIdx.x >> 8;
  const int tid = threadIdx.x;
  const int w = tid >> 6, lane = tid & 63;
  const int lr = lane & 15, lj = lane >> 4;
  __shared__ __align__(16) unsigned short Cb[64][72];   // C rows [t][n]; P after phase1
  __shared__ __align__(16) unsigned short Bb[64][72];   // B rows [s][n]
  __shared__ __align__(16) unsigned short BbT[64][72];  // [n][s]
  __shared__ __align__(16) unsigned short xT[32][72];   // [p][t]
  __shared__ __align__(16) unsigned short hbT[32][72];  // h [p][n]
  __shared__ float la[64], dtc[64], wt[64];
  for (int i = tid; i < 32 * 72 / 2; i += 256) ((unsigned*)hbT)[i] = 0;
  f32x4 acc_h[4] = {};   // waves 0,1 own h rows p = w*16 .. w*16+15
  const float dph = Dp[h];
  __syncthreads();

  for (int c = 0; c < 4; ++c) {
    const int tok0 = b * 256 + c * 64;
    // ---- stage ----
    if (w == 0) {
      float v = ldA[(size_t)(tok0 + lane) * 8 + h];
#pragma unroll
      for (int off = 1; off < 64; off <<= 1) {
        float u = __shfl_up(v, off);
        if (lane >= off) v += u;
      }
      la[lane] = v;
      dtc[lane] = dtv[(size_t)(tok0 + lane) * 8 + h];
    }
    for (int idx = tid; idx < 64 * 20; idx += 256) {
      int t = idx / 20, seg = idx - t * 20;
      const unsigned short* row = xbc + (size_t)(tok0 + t) * XBC;
      if (seg < 4) {
        short8 v = *(const short8*)(row + h * 32 + seg * 8);
#pragma unroll
        for (int j = 0; j < 8; ++j) xT[seg * 8 + j][t] = (unsigned short)v[j];
      } else if (seg < 12) {
        int si = seg - 4;
        short8 v = *(const short8*)(row + 256 + si * 8);
        *(short8*)&Bb[t][si * 8] = v;
#pragma unroll
        for (int j = 0; j < 8; ++j) BbT[si * 8 + j][t] = (unsigned short)v[j];
      } else {
        int si = seg - 12;
        *(short8*)&Cb[t][si * 8] = *(const short8*)(row + 320 + si * 8);
      }
    }
    __syncthreads();   // bar1
    if (w == 3) wt[lane] = __expf(la[63] - la[lane]) * dtc[lane];
    // ---- phase1: S and y_inter ----
    short8 afC0 = *(const short8*)&Cb[w * 16 + lr][lj * 8];
    short8 afC1 = *(const short8*)&Cb[w * 16 + lr][32 + lj * 8];
    f32x4 acc_s[4] = {};
#pragma unroll
    for (int ni = 0; ni < 4; ++ni) {
      short8 bf0 = *(const short8*)&Bb[ni * 16 + lr][lj * 8];
      short8 bf1 = *(const short8*)&Bb[ni * 16 + lr][32 + lj * 8];
      acc_s[ni] = __builtin_amdgcn_mfma_f32_16x16x32_bf16(afC0, bf0, acc_s[ni], 0, 0, 0);
      acc_s[ni] = __builtin_amdgcn_mfma_f32_16x16x32_bf16(afC1, bf1, acc_s[ni], 0, 0, 0);
    }
    f32x4 acc_y[2] = {};
#pragma unroll
    for (int ni = 0; ni < 2; ++ni) {
      short8 hf0 = *(const short8*)&hbT[ni * 16 + lr][lj * 8];
      short8 hf1 = *(const short8*)&hbT[ni * 16 + lr][32 + lj * 8];
      acc_y[ni] = __builtin_amdgcn_mfma_f32_16x16x32_bf16(afC0, hf0, acc_y[ni], 0, 0, 0);
      acc_y[ni] = __builtin_amdgcn_mfma_f32_16x16x32_bf16(afC1, hf1, acc_y[ni], 0, 0, 0);
    }
#pragma unroll
    for (int j = 0; j < 4; ++j) {
      float at = __expf(la[w * 16 + lj * 4 + j]);
      acc_y[0][j] *= at;
      acc_y[1][j] *= at;
    }
    __syncthreads();   // bar2: Cb reads done
    // ---- P -> Cb (alias) ----
#pragma unroll
    for (int ni = 0; ni < 4; ++ni) {
      int s = ni * 16 + lr;
      float las = la[s], dts = dtc[s];
#pragma unroll
      for (int j = 0; j < 4; ++j) {
        int t = w * 16 + lj * 4 + j;
        float pv = 0.f;
        if (s <= t) pv = acc_s[ni][j] * __expf(la[t] - las) * dts;
        Cb[t][s] = (unsigned short)f2bf(pv);
      }
    }
    __syncthreads();   // bar3
    // ---- phase2: y += P@x ; h-update ----
    {
      short8 afP0 = *(const short8*)&Cb[w * 16 + lr][lj * 8];
      short8 afP1 = *(const short8*)&Cb[w * 16 + lr][32 + lj * 8];
#pragma unroll
      for (int ni = 0; ni < 2; ++ni) {
        short8 xf0 = *(const short8*)&xT[ni * 16 + lr][lj * 8];
        short8 xf1 = *(const short8*)&xT[ni * 16 + lr][32 + lj * 8];
        acc_y[ni] = __builtin_amdgcn_mfma_f32_16x16x32_bf16(afP0, xf0, acc_y[ni], 0, 0, 0);
        acc_y[ni] = __builtin_amdgcn_mfma_f32_16x16x32_bf16(afP1, xf1, acc_y[ni], 0, 0, 0);
      }
    }
    if (w < 2) {
      float aend = __expf(la[63]);
#pragma unroll
      for (int ni = 0; ni < 4; ++ni)
#pragma unroll
        for (int j = 0; j < 4; ++j) acc_h[ni][j] *= aend;
#pragma unroll
      for (int kk = 0; kk < 2; ++kk) {
        short8 xv = *(const short8*)&xT[w * 16 + lr][kk * 32 + lj * 8];
        short8 axf;
#pragma unroll
        for (int j = 0; j < 8; ++j)
          axf[j] = f2bf(bf2f((unsigned short)xv[j]) * wt[kk * 32 + lj * 8 + j]);
#pragma unroll
        for (int ni = 0; ni < 4; ++ni) {
          short8 bw = *(const short8*)&BbT[ni * 16 + lr][kk * 32 + lj * 8];
          acc_h[ni] = __builtin_amdgcn_mfma_f32_16x16x32_bf16(axf, bw, acc_h[ni], 0, 0, 0);
        }
      }
    }
    // ---- y epilogue ----
#pragma unroll
    for (int ni = 0; ni < 2; ++ni) {
#pragma unroll
      for (int j = 0; j < 4; ++j) {
        int t = w * 16 + lj * 4 + j;
        int p = ni * 16 + lr;
        ybuf[(size_t)(tok0 + t) * DI + h * 32 + p] = acc_y[ni][j] + dph * bf2f(xT[p][t]);
      }
    }
    if (w < 2) {
#pragma unroll
      for (int ni = 0; ni < 4; ++ni)
#pragma unroll
        for (int j = 0; j < 4; ++j)
          hbT[w * 16 + lj * 4 + j][ni * 16 + lr] = (unsigned short)f2bf(acc_h[ni][j]);
    }
    __syncthreads();   // bar4: protect tiles from next stage
  }
}

// ---------------- y = rmsnorm(yraw * silu(z)) * nw -> bf16 ----------------
__global__ __launch_bounds__(256) void gate_rms_kernel(
    const float* __restrict__ yraw, const unsigned short* __restrict__ zx,
    const float* __restrict__ nw, unsigned short* __restrict__ yout) {
  int wid = threadIdx.x >> 6, lane = threadIdx.x & 63;
  size_t token = (size_t)blockIdx.x * 4 + wid;
  float4 yv = *(const float4*)(yraw + token * DI + lane * 4);
  ushort4 zu = *(const ushort4*)(zx + token * DIN + lane * 4);
  float z0 = bf2f(zu.x), z1 = bf2f(zu.y), z2 = bf2f(zu.z), z3 = bf2f(zu.w);
  float g0 = yv.x * (z0 / (1.f + expf(-z0)));
  float g1 = yv.y * (z1 / (1.f + expf(-z1)));
  float g2 = yv.z * (z2 / (1.f + expf(-z2)));
  float g3 = yv.w * (z3 / (1.f + expf(-z3)));
  float ss = g0 * g0 + g1 * g1 + g2 * g2 + g3 * g3;
#pragma unroll
  for (int off = 1; off < 64; off <<= 1) ss += __shfl_xor(ss, off);
  float r = rsqrtf(ss * (1.f / 256.f) + EPSF);
  unsigned w0 = (unsigned short)f2bf(g0 * r * nw[lane * 4 + 0]);
  unsigned w1 = (unsigned short)f2bf(g1 * r * nw[lane * 4 + 1]);
  unsigned w2 = (unsigned short)f2bf(g2 * r * nw[lane * 4 + 2]);
  unsigned w3 = (unsigned short)f2bf(g3 * r * nw[lane * 4 + 3]);
  uint2 packed = make_uint2(w0 | (w1 << 16), w2 | (w3 << 16));
  *(uint2*)(yout + token * DI + lane * 4) = packed;
}

// ---------------- column mean over L (bf16 in) ----------------
__global__ __launch_bounds__(128) void colmean_kernel(const unsigned short* __restrict__ tn,
                                                      float* __restrict__ tmean) {
  int b = blockIdx.x, e = threadIdx.x;
  const unsigned short* p = tn + (size_t)b * 256 * 128 + e;
  float acc = 0.f;
  for (int l = 0; l < 256; ++l) acc += bf2f(p[l * 128]);
  tmean[b * 128 + e] = acc * (1.f / 256.f);
}

// ---------------- head matmul + L2 normalize ----------------
__global__ __launch_bounds__(128) void head_kernel(
    const float* __restrict__ tmean, const float* __restrict__ hw,
    const float* __restrict__ hb, float* __restrict__ out) {
  __shared__ float tm[128];
  __shared__ float red[2];
  int b = blockIdx.x, o = threadIdx.x;
  tm[o] = tmean[b * 128 + o];
  __syncthreads();
  float acc = hb[o];
  for (int e = 0; e < 128; ++e) acc += tm[e] * hw[o * 128 + e];
  float ss = acc * acc;
#pragma unroll
  for (int off = 1; off < 64; off <<= 1) ss += __shfl_xor(ss, off);
  if ((o & 63) == 0) red[o >> 6] = ss;
  __syncthreads();
  float nrm = fmaxf(sqrtf(red[0] + red[1]), 1e-12f);
  out[b * 128 + o] = acc / nrm;
}

extern "C" void kernel_launch(void* const* d_in, const int* in_sizes, int n_in,
                              void* d_out, int out_size, void* d_ws, size_t ws_size,
                              hipStream_t stream) {
  const float* x      = (const float*)d_in[0];
  const float* conv_w = (const float*)d_in[1];
  const float* conv_b = (const float*)d_in[2];
  const float* pe_w   = (const float*)d_in[3];
  const float* pe_b   = (const float*)d_in[4];
  const float* ln_w   = (const float*)d_in[5];
  const float* ln_b   = (const float*)d_in[6];
  const float* in_w   = (const float*)d_in[7];
  const float* c1w    = (const float*)d_in[8];
  const float* c1b    = (const float*)d_in[9];
  const float* dtb    = (const float*)d_in[10];
  const float* A_log  = (const float*)d_in[11];
  const float* Dp     = (const float*)d_in[12];
  const float* nw     = (const float*)d_in[13];
  const float* ow     = (const float*)d_in[14];
  const float* fn_w   = (const float*)d_in[15];
  const float* fn_b   = (const float*)d_in[16];
  const float* hw     = (const float*)d_in[17];
  const float* hb     = (const float*)d_in[18];
  float* out = (float*)d_out;

  const size_t T = TTOK;
  char* w8 = (char*)d_ws;
  float*          t_buf = (float*)w8;            w8 += T * 128 * 4;   // residual fp32
  unsigned*       tnb   = (unsigned*)w8;         w8 += T * 128 * 2;   // ln out bf16
  unsigned short* zx    = (unsigned short*)w8;   w8 += T * (size_t)DIN * 2; // in-proj bf16
  unsigned short* xbc   = (unsigned short*)w8;   w8 += T * (size_t)XBC * 2; // conv out bf16
  float*          dtraw = (float*)w8;            w8 += T * 8 * 4;
  float*          dtv   = (float*)w8;            w8 += T * 8 * 4;
  float*          ldAv  = (float*)w8;            w8 += T * 8 * 4;
  float*          ybuf  = (float*)w8;            w8 += T * (size_t)DI * 4;  // scan out fp32
  unsigned short* ybb   = (unsigned short*)w8;   w8 += T * (size_t)DI * 2;  // gated bf16
  float*          tmean = (float*)w8;            w8 += 256 * 128 * 4;
  unsigned short* in_wb = (unsigned short*)w8;   w8 += (size_t)NL * DIN * EE * 2;
  unsigned short* owb   = (unsigned short*)w8;   w8 += (size_t)NL * EE * DI * 2;
  if ((size_t)(w8 - (char*)d_ws) > ws_size) return;  // workspace too small

  // one-shot weight conversion (NL*DIN*EE = 331776 = 1296*256)
  cvt_w_kernel<<<1296, 256, 0, stream>>>(in_w, ow, in_wb, owb);

  // patch embed + bias, then pe layernorm (in place, fp32)
  gemm_bf16_patch<<<dim3(512, 1), 256, 0, stream>>>(x, conv_w, conv_b, t_buf);
  ln_kernel<<<16384, 256, 0, stream>>>(t_buf, t_buf, pe_w, pe_b);

  for (int i = 0; i < NL; ++i) {
    ln_bf16_kernel<<<16384, 256, 0, stream>>>(t_buf, tnb, ln_w + i * 128, ln_b + i * 128);
    gemm_in_proj<<<dim3(512, 6), 256, 0, stream>>>(
        (const unsigned short*)tnb, in_wb + (size_t)i * DIN * EE, zx, dtraw, TTOK, DIN, EE);
    conv_silu_kernel<<<24576, 256, 0, stream>>>(zx, c1w + (size_t)i * XBC * DC, c1b + (size_t)i * XBC, xbc);
    dt_kernel<<<2048, 256, 0, stream>>>(dtraw, dtb + i * HH, A_log + i * HH, dtv, ldAv);
    scan_chunk_kernel<<<2048, 256, 0, stream>>>(xbc, dtv, ldAv, Dp + i * HH, ybuf);
    gate_rms_kernel<<<16384, 256, 0, stream>>>(ybuf, zx, nw + i * DI, ybb);
    gemm_bf16_nt_abf<<<dim3(512, 1), 256, 0, stream>>>(
        ybb, owb + (size_t)i * EE * DI, t_buf, t_buf, TTOK, EE, DI);
  }

  ln_bf16_kernel<<<16384, 256, 0, stream>>>(t_buf, tnb, fn_w, fn_b);
  colmean_kernel<<<256, 128, 0, stream>>>((const unsigned short*)tnb, tmean);
  head_kernel<<<256, 128, 0, stream>>>(tmean, hw, hb, out);
}

// Round 8
// 921.596 us; speedup vs baseline: 2.8276x; 1.3707x over previous
//
#include <hip/hip_runtime.h>
#include <math.h>

// ---------------- constants ----------------
#define EE 128
#define DI 256
#define HH 8
#define PP 32
#define NN 64
#define DC 4
#define XBC 384
#define DIN 648
#define NL 4
#define LSEQ 256
#define BB 256
#define TTOK (BB * LSEQ)   // 65536 tokens
#define EPSF 1e-5f

typedef __attribute__((ext_vector_type(8))) short short8;
typedef __attribute__((ext_vector_type(4))) float f32x4;

__device__ inline short f2bf(float f) {
  unsigned u = __builtin_bit_cast(unsigned, f);
  u += 0x7fff + ((u >> 16) & 1);   // RNE
  return (short)(u >> 16);
}
__device__ inline float bf2f(unsigned short u) {
  unsigned x = ((unsigned)u) << 16;
  return __builtin_bit_cast(float, x);
}

// ---------------- one-shot weight conversion fp32 -> bf16 ----------------
__global__ __launch_bounds__(256) void cvt_w_kernel(
    const float* __restrict__ in_w, const float* __restrict__ ow,
    unsigned short* __restrict__ in_wb, unsigned short* __restrict__ owb) {
  int i = blockIdx.x * 256 + threadIdx.x;   // grid covers NL*DIN*EE = 331776
  in_wb[i] = (unsigned short)f2bf(in_w[i]);
  if (i < NL * EE * DI) owb[i] = (unsigned short)f2bf(ow[i]);
}

// ---------------- in-proj GEMM: bf16 A,B; bf16 out + fp32 dt side-channel ----------------
__global__ __launch_bounds__(256) void gemm_in_proj(
    const unsigned short* __restrict__ A, const unsigned short* __restrict__ B,
    unsigned short* __restrict__ Czx, float* __restrict__ dtraw,
    int M, int N, int K) {
  __shared__ short As[128][40];
  __shared__ short Bs[128][40];
  const int tid = threadIdx.x;
  const int lane = tid & 63, wid = tid >> 6;
  const int wm = wid >> 1, wn = wid & 1;
  const int m0 = blockIdx.x * 128, n0 = blockIdx.y * 128;
  const int r = tid >> 1, hf = tid & 1;
  const int lr = lane & 15, lk = (lane >> 4) * 8;
  f32x4 acc[4][4] = {};
  for (int k0 = 0; k0 < K; k0 += 32) {
    {
      const unsigned short* ap = A + (size_t)(m0 + r) * K + k0 + hf * 16;
      *(short8*)&As[r][hf * 16] = *(const short8*)(ap);
      *(short8*)&As[r][hf * 16 + 8] = *(const short8*)(ap + 8);
    }
    {
      short8 s0 = {}, s1 = {};
      if (n0 + r < N) {
        const unsigned short* bp = B + (size_t)(n0 + r) * K + k0 + hf * 16;
        s0 = *(const short8*)(bp);
        s1 = *(const short8*)(bp + 8);
      }
      *(short8*)&Bs[r][hf * 16] = s0;
      *(short8*)&Bs[r][hf * 16 + 8] = s1;
    }
    __syncthreads();
    short8 af[4], bfr[4];
#pragma unroll
    for (int mi = 0; mi < 4; ++mi) af[mi] = *(const short8*)&As[wm * 64 + mi * 16 + lr][lk];
#pragma unroll
    for (int ni = 0; ni < 4; ++ni) bfr[ni] = *(const short8*)&Bs[wn * 64 + ni * 16 + lr][lk];
#pragma unroll
    for (int mi = 0; mi < 4; ++mi)
#pragma unroll
      for (int ni = 0; ni < 4; ++ni)
        acc[mi][ni] = __builtin_amdgcn_mfma_f32_16x16x32_bf16(af[mi], bfr[ni], acc[mi][ni], 0, 0, 0);
    __syncthreads();
  }
#pragma unroll
  for (int mi = 0; mi < 4; ++mi) {
#pragma unroll
    for (int ni = 0; ni < 4; ++ni) {
      int row0 = m0 + wm * 64 + mi * 16 + (lane >> 4) * 4;
      int col = n0 + wn * 64 + ni * 16 + (lane & 15);
      if (col < N) {
#pragma unroll
        for (int j = 0; j < 4; ++j) {
          int row = row0 + j;
          float v = acc[mi][ni][j];
          Czx[(size_t)row * DIN + col] = (unsigned short)f2bf(v);
          if (col >= DI + XBC) dtraw[(size_t)row * 8 + (col - (DI + XBC))] = v;
        }
      }
    }
  }
}

// ---------------- out-proj + residual + fused next-LayerNorm ----------------
// A[M][256] bf16, B[128][256] bf16. tres (fp32) updated in place with residual;
// tnb gets packed-bf16 LayerNorm(tres_new) with (lnw, lnb).
__global__ __launch_bounds__(256) void gemm_out_ln(
    const unsigned short* __restrict__ A, const unsigned short* __restrict__ B,
    float* __restrict__ tres, const float* __restrict__ lnw,
    const float* __restrict__ lnb, unsigned* __restrict__ tnb) {
  __shared__ short As[128][40];
  __shared__ short Bs[128][40];
  __shared__ unsigned short Vt[128][136];
  __shared__ float mu_s[128], rs_s[128];
  const int tid = threadIdx.x;
  const int lane = tid & 63, wid = tid >> 6;
  const int wm = wid >> 1, wn = wid & 1;
  const int m0 = blockIdx.x * 128;
  const int r = tid >> 1, hf = tid & 1;
  const int lr = lane & 15, lk = (lane >> 4) * 8;
  f32x4 acc[4][4] = {};
  for (int k0 = 0; k0 < 256; k0 += 32) {
    {
      const unsigned short* ap = A + (size_t)(m0 + r) * 256 + k0 + hf * 16;
      *(short8*)&As[r][hf * 16] = *(const short8*)(ap);
      *(short8*)&As[r][hf * 16 + 8] = *(const short8*)(ap + 8);
    }
    {
      const unsigned short* bp = B + (size_t)r * 256 + k0 + hf * 16;
      *(short8*)&Bs[r][hf * 16] = *(const short8*)(bp);
      *(short8*)&Bs[r][hf * 16 + 8] = *(const short8*)(bp + 8);
    }
    __syncthreads();
    short8 af[4], bfr[4];
#pragma unroll
    for (int mi = 0; mi < 4; ++mi) af[mi] = *(const short8*)&As[wm * 64 + mi * 16 + lr][lk];
#pragma unroll
    for (int ni = 0; ni < 4; ++ni) bfr[ni] = *(const short8*)&Bs[wn * 64 + ni * 16 + lr][lk];
#pragma unroll
    for (int mi = 0; mi < 4; ++mi)
#pragma unroll
      for (int ni = 0; ni < 4; ++ni)
        acc[mi][ni] = __builtin_amdgcn_mfma_f32_16x16x32_bf16(af[mi], bfr[ni], acc[mi][ni], 0, 0, 0);
    __syncthreads();
  }
  // epilogue: residual add, fp32 store, bf16 LDS tile
#pragma unroll
  for (int mi = 0; mi < 4; ++mi) {
#pragma unroll
    for (int ni = 0; ni < 4; ++ni) {
      int row0 = wm * 64 + mi * 16 + (lane >> 4) * 4;
      int col = wn * 64 + ni * 16 + lr;
#pragma unroll
      for (int j = 0; j < 4; ++j) {
        int row = row0 + j;
        size_t idx = (size_t)(m0 + row) * 128 + col;
        float v = acc[mi][ni][j] + tres[idx];
        tres[idx] = v;
        Vt[row][col] = (unsigned short)f2bf(v);
      }
    }
  }
  __syncthreads();
  // per-row stats (2 threads per row)
  {
    int row = tid >> 1;
    float s = 0.f, ss = 0.f;
#pragma unroll
    for (int kk = 0; kk < 8; ++kk) {
      short8 vv = *(const short8*)&Vt[row][hf * 64 + kk * 8];
#pragma unroll
      for (int j = 0; j < 8; ++j) {
        float f = bf2f((unsigned short)vv[j]);
        s += f; ss += f * f;
      }
    }
    s += __shfl_xor(s, 1);
    ss += __shfl_xor(ss, 1);
    if (hf == 0) {
      float mu = s * (1.f / 128.f);
      mu_s[row] = mu;
      rs_s[row] = rsqrtf(ss * (1.f / 128.f) - mu * mu + EPSF);
    }
  }
  __syncthreads();
  // LN write: packed bf16, coalesced
  float w0 = lnw[lane * 2], w1 = lnw[lane * 2 + 1];
  float b0 = lnb[lane * 2], b1 = lnb[lane * 2 + 1];
  for (int it = 0; it < 32; ++it) {
    int row = it * 4 + wid;
    float mu = mu_s[row], rr = rs_s[row];
    float v0 = bf2f(Vt[row][lane * 2]);
    float v1 = bf2f(Vt[row][lane * 2 + 1]);
    unsigned lo = (unsigned short)f2bf((v0 - mu) * rr * w0 + b0);
    unsigned hi = (unsigned short)f2bf((v1 - mu) * rr * w1 + b1);
    tnb[(size_t)(m0 + row) * 64 + lane] = lo | (hi << 16);
  }
}

// ---------------- patch-embed bf16 MFMA GEMM ----------------
__global__ __launch_bounds__(256) void gemm_bf16_patch(
    const float* __restrict__ X, const float* __restrict__ B,
    const float* __restrict__ bias, float* __restrict__ C) {
  __shared__ short As[128][40];
  __shared__ short Bs[128][40];
  const int tid = threadIdx.x;
  const int lane = tid & 63, wid = tid >> 6;
  const int wm = wid >> 1, wn = wid & 1;
  const int m0 = blockIdx.x * 128;
  const int r = tid >> 1, hf = tid & 1;
  const int lr = lane & 15, lk = (lane >> 4) * 8;
  const int m = m0 + r;
  const int bb = m >> 8, px = (m >> 4) & 15, py = m & 15;
  f32x4 acc[4][4] = {};
  for (int k0 = 0; k0 < 768; k0 += 32) {
    int k = k0 + hf * 16;
    int c = k >> 8, dx = (k >> 4) & 15;
    {
      const float* ap = X + (((size_t)(bb * 3 + c) * 256 + px * 16 + dx) * 256 + py * 16);
      float4 v0 = *(const float4*)(ap + 0);
      float4 v1 = *(const float4*)(ap + 4);
      float4 v2 = *(const float4*)(ap + 8);
      float4 v3 = *(const float4*)(ap + 12);
      short8 s0, s1;
      s0[0] = f2bf(v0.x); s0[1] = f2bf(v0.y); s0[2] = f2bf(v0.z); s0[3] = f2bf(v0.w);
      s0[4] = f2bf(v1.x); s0[5] = f2bf(v1.y); s0[6] = f2bf(v1.z); s0[7] = f2bf(v1.w);
      s1[0] = f2bf(v2.x); s1[1] = f2bf(v2.y); s1[2] = f2bf(v2.z); s1[3] = f2bf(v2.w);
      s1[4] = f2bf(v3.x); s1[5] = f2bf(v3.y); s1[6] = f2bf(v3.z); s1[7] = f2bf(v3.w);
      *(short8*)&As[r][hf * 16] = s0;
      *(short8*)&As[r][hf * 16 + 8] = s1;
    }
    {
      const float* bp = B + (size_t)r * 768 + k;
      float4 v0 = *(const float4*)(bp + 0);
      float4 v1 = *(const float4*)(bp + 4);
      float4 v2 = *(const float4*)(bp + 8);
      float4 v3 = *(const float4*)(bp + 12);
      short8 s0, s1;
      s0[0] = f2bf(v0.x); s0[1] = f2bf(v0.y); s0[2] = f2bf(v0.z); s0[3] = f2bf(v0.w);
      s0[4] = f2bf(v1.x); s0[5] = f2bf(v1.y); s0[6] = f2bf(v1.z); s0[7] = f2bf(v1.w);
      s1[0] = f2bf(v2.x); s1[1] = f2bf(v2.y); s1[2] = f2bf(v2.z); s1[3] = f2bf(v2.w);
      s1[4] = f2bf(v3.x); s1[5] = f2bf(v3.y); s1[6] = f2bf(v3.z); s1[7] = f2bf(v3.w);
      *(short8*)&Bs[r][hf * 16] = s0;
      *(short8*)&Bs[r][hf * 16 + 8] = s1;
    }
    __syncthreads();
    short8 af[4], bfr[4];
#pragma unroll
    for (int mi = 0; mi < 4; ++mi) af[mi] = *(const short8*)&As[wm * 64 + mi * 16 + lr][lk];
#pragma unroll
    for (int ni = 0; ni < 4; ++ni) bfr[ni] = *(const short8*)&Bs[wn * 64 + ni * 16 + lr][lk];
#pragma unroll
    for (int mi = 0; mi < 4; ++mi)
#pragma unroll
      for (int ni = 0; ni < 4; ++ni)
        acc[mi][ni] = __builtin_amdgcn_mfma_f32_16x16x32_bf16(af[mi], bfr[ni], acc[mi][ni], 0, 0, 0);
    __syncthreads();
  }
#pragma unroll
  for (int mi = 0; mi < 4; ++mi) {
#pragma unroll
    for (int ni = 0; ni < 4; ++ni) {
      int row0 = m0 + wm * 64 + mi * 16 + (lane >> 4) * 4;
      int col = wn * 64 + ni * 16 + (lane & 15);
#pragma unroll
      for (int j = 0; j < 4; ++j)
        C[(size_t)(row0 + j) * 128 + col] = acc[mi][ni][j] + bias[col];
    }
  }
}

// ---------------- LayerNorm over E=128, fp32 out (PE only) ----------------
__global__ __launch_bounds__(256) void ln_kernel(const float* in, float* out,
                                                 const float* __restrict__ w, const float* __restrict__ b) {
  int wid = threadIdx.x >> 6, lane = threadIdx.x & 63;
  size_t token = (size_t)blockIdx.x * 4 + wid;
  const float* p = in + token * 128;
  float2 v = *(const float2*)(p + lane * 2);
  float s = v.x + v.y;
#pragma unroll
  for (int off = 1; off < 64; off <<= 1) s += __shfl_xor(s, off);
  float mu = s * (1.f / 128.f);
  float dx = v.x - mu, dy = v.y - mu;
  float vs = dx * dx + dy * dy;
#pragma unroll
  for (int off = 1; off < 64; off <<= 1) vs += __shfl_xor(vs, off);
  float r = rsqrtf(vs * (1.f / 128.f) + EPSF);
  float2 o;
  o.x = dx * r * w[lane * 2 + 0] + b[lane * 2 + 0];
  o.y = dy * r * w[lane * 2 + 1] + b[lane * 2 + 1];
  *(float2*)(out + token * 128 + lane * 2) = o;
}

// ---------------- LayerNorm over E=128, bf16-packed out (pre-loop only) ----------------
__global__ __launch_bounds__(256) void ln_bf16_kernel(const float* in, unsigned* out,
                                                      const float* __restrict__ w, const float* __restrict__ b) {
  int wid = threadIdx.x >> 6, lane = threadIdx.x & 63;
  size_t token = (size_t)blockIdx.x * 4 + wid;
  const float* p = in + token * 128;
  float2 v = *(const float2*)(p + lane * 2);
  float s = v.x + v.y;
#pragma unroll
  for (int off = 1; off < 64; off <<= 1) s += __shfl_xor(s, off);
  float mu = s * (1.f / 128.f);
  float dx = v.x - mu, dy = v.y - mu;
  float vs = dx * dx + dy * dy;
#pragma unroll
  for (int off = 1; off < 64; off <<= 1) vs += __shfl_xor(vs, off);
  float r = rsqrtf(vs * (1.f / 128.f) + EPSF);
  unsigned lo = (unsigned short)f2bf(dx * r * w[lane * 2 + 0] + b[lane * 2 + 0]);
  unsigned hi = (unsigned short)f2bf(dy * r * w[lane * 2 + 1] + b[lane * 2 + 1]);
  out[token * 64 + lane] = lo | (hi << 16);
}

// ---------------- causal conv1d (DC=4) + SiLU, bf16 in/out ----------------
__global__ __launch_bounds__(256) void conv_silu_kernel(
    const unsigned short* __restrict__ zx, const float* __restrict__ cw,
    const float* __restrict__ cb, unsigned short* __restrict__ xbc) {
  int gid = blockIdx.x * 256 + threadIdx.x;  // T*96
  int token = gid / 96;
  int c4 = (gid - token * 96) * 4;
  int l = token & 255;
  const unsigned short* base = zx + (size_t)token * DIN + DI + c4;
  ushort4 z4 = make_ushort4(0, 0, 0, 0);
  ushort4 u0 = (l >= 3) ? *(const ushort4*)(base - 3 * DIN) : z4;
  ushort4 u1 = (l >= 2) ? *(const ushort4*)(base - 2 * DIN) : z4;
  ushort4 u2 = (l >= 1) ? *(const ushort4*)(base - 1 * DIN) : z4;
  ushort4 u3 = *(const ushort4*)(base);
  float4 w0 = *(const float4*)(cw + (c4 + 0) * 4);
  float4 w1 = *(const float4*)(cw + (c4 + 1) * 4);
  float4 w2 = *(const float4*)(cw + (c4 + 2) * 4);
  float4 w3 = *(const float4*)(cw + (c4 + 3) * 4);
  float4 cbv = *(const float4*)(cb + c4);
  float s0 = cbv.x + w0.x * bf2f(u0.x) + w0.y * bf2f(u1.x) + w0.z * bf2f(u2.x) + w0.w * bf2f(u3.x);
  float s1 = cbv.y + w1.x * bf2f(u0.y) + w1.y * bf2f(u1.y) + w1.z * bf2f(u2.y) + w1.w * bf2f(u3.y);
  float s2 = cbv.z + w2.x * bf2f(u0.z) + w2.y * bf2f(u1.z) + w2.z * bf2f(u2.z) + w2.w * bf2f(u3.z);
  float s3 = cbv.w + w3.x * bf2f(u0.w) + w3.y * bf2f(u1.w) + w3.z * bf2f(u2.w) + w3.w * bf2f(u3.w);
  s0 = s0 / (1.f + expf(-s0));
  s1 = s1 / (1.f + expf(-s1));
  s2 = s2 / (1.f + expf(-s2));
  s3 = s3 / (1.f + expf(-s3));
  unsigned a0 = (unsigned short)f2bf(s0), a1 = (unsigned short)f2bf(s1);
  unsigned a2 = (unsigned short)f2bf(s2), a3 = (unsigned short)f2bf(s3);
  uint2 o = make_uint2(a0 | (a1 << 16), a2 | (a3 << 16));
  *(uint2*)(xbc + (size_t)token * XBC + c4) = o;
}

// ---------------- dt = softplus(raw + bias); ldA = -exp(A_log)*dt ----------------
__global__ __launch_bounds__(256) void dt_kernel(
    const float* __restrict__ dtraw, const float* __restrict__ dtb,
    const float* __restrict__ A_log, float* __restrict__ dtv, float* __restrict__ ldAv) {
  int gid = blockIdx.x * 256 + threadIdx.x;  // T*8
  int h = gid & 7;
  float raw = dtraw[gid] + dtb[h];
  float dt = raw > 20.f ? raw : log1pf(expf(raw));
  dtv[gid] = dt;
  ldAv[gid] = -expf(A_log[h]) * dt;
}

// ---------------- chunked SSM scan via MFMA, packed-transpose staging ----------------
// grid = 2048; b = bid&255, h = bid>>8. 256 threads (4 waves). 4 chunks of 64 tokens.
// Staging in 4-token quads: transposed tiles written as ds_write_b64 (ushort4),
// row tiles as short8. y output bf16.
__global__ __launch_bounds__(256, 4) void scan_chunk_kernel(
    const unsigned short* __restrict__ xbc,  // [T][384] bf16
    const float* __restrict__ dtv,           // [T][8]
    const float* __restrict__ ldA,           // [T][8]
    const float* __restrict__ Dp,            // [8]
    unsigned short* __restrict__ ysc) {      // [T][256] bf16
  const int b = blockIdx.x & 255, h = blockIdx.x >> 8;
  const int tid = threadIdx.x;
  const int w = tid >> 6, lane = tid & 63;
  const int lr = lane & 15, lj = lane >> 4;
  __shared__ __align__(16) unsigned short Cb[64][72];   // C rows [t][n]; P after phase1
  __shared__ __align__(16) unsigned short Bb[64][72];   // B rows [s][n]
  __shared__ __align__(16) unsigned short BbT[64][72];  // [n][s]
  __shared__ __align__(16) unsigned short xT[32][72];   // [p][t]
  __shared__ __align__(16) unsigned short hbT[32][72];  // h [p][n]
  __shared__ float la[64], dtc[64], wt[64];
  for (int i = tid; i < 32 * 72 / 2; i += 256) ((unsigned*)hbT)[i] = 0;
  f32x4 acc_h[4] = {};   // waves 0,1 own h rows p = w*16 .. w*16+15
  const float dph = Dp[h];
  __syncthreads();

  for (int c = 0; c < 4; ++c) {
    const int tok0 = b * 256 + c * 64;
    // ---- stage ----
    if (w == 0) {
      float v = ldA[(size_t)(tok0 + lane) * 8 + h];
#pragma unroll
      for (int off = 1; off < 64; off <<= 1) {
        float u = __shfl_up(v, off);
        if (lane >= off) v += u;
      }
      la[lane] = v;
      dtc[lane] = dtv[(size_t)(tok0 + lane) * 8 + h];
    }
    // items: 64 x-transpose, 128 B (row+transpose), 128 C rows  (quads of 4 tokens)
    for (int it = tid; it < 320; it += 256) {
      if (it < 64) {
        int pq = it & 3, tq = it >> 2;
        int t0 = tq * 4, p0 = pq * 8;
        const unsigned short* r0 = xbc + (size_t)(tok0 + t0) * XBC + h * 32 + p0;
        short8 a0 = *(const short8*)(r0);
        short8 a1 = *(const short8*)(r0 + XBC);
        short8 a2 = *(const short8*)(r0 + 2 * XBC);
        short8 a3 = *(const short8*)(r0 + 3 * XBC);
#pragma unroll
        for (int j = 0; j < 8; ++j) {
          ushort4 v;
          v.x = (unsigned short)a0[j]; v.y = (unsigned short)a1[j];
          v.z = (unsigned short)a2[j]; v.w = (unsigned short)a3[j];
          *(ushort4*)&xT[p0 + j][t0] = v;
        }
      } else if (it < 192) {
        int id = it - 64;
        int nq = id & 7, tq = id >> 3;
        int t0 = tq * 4, n0 = nq * 8;
        const unsigned short* r0 = xbc + (size_t)(tok0 + t0) * XBC + 256 + n0;
        short8 a0 = *(const short8*)(r0);
        short8 a1 = *(const short8*)(r0 + XBC);
        short8 a2 = *(const short8*)(r0 + 2 * XBC);
        short8 a3 = *(const short8*)(r0 + 3 * XBC);
        *(short8*)&Bb[t0 + 0][n0] = a0;
        *(short8*)&Bb[t0 + 1][n0] = a1;
        *(short8*)&Bb[t0 + 2][n0] = a2;
        *(short8*)&Bb[t0 + 3][n0] = a3;
#pragma unroll
        for (int j = 0; j < 8; ++j) {
          ushort4 v;
          v.x = (unsigned short)a0[j]; v.y = (unsigned short)a1[j];
          v.z = (unsigned short)a2[j]; v.w = (unsigned short)a3[j];
          *(ushort4*)&BbT[n0 + j][t0] = v;
        }
      } else {
        int id = it - 192;
        int nq = id & 7, tq = id >> 3;
        int t0 = tq * 4, n0 = nq * 8;
        const unsigned short* r0 = xbc + (size_t)(tok0 + t0) * XBC + 320 + n0;
        *(short8*)&Cb[t0 + 0][n0] = *(const short8*)(r0);
        *(short8*)&Cb[t0 + 1][n0] = *(const short8*)(r0 + XBC);
        *(short8*)&Cb[t0 + 2][n0] = *(const short8*)(r0 + 2 * XBC);
        *(short8*)&Cb[t0 + 3][n0] = *(const short8*)(r0 + 3 * XBC);
      }
    }
    __syncthreads();   // bar1
    if (w == 3) wt[lane] = __expf(la[63] - la[lane]) * dtc[lane];
    // ---- phase1: S = C@B^T and y_inter = C@h^T ----
    short8 afC0 = *(const short8*)&Cb[w * 16 + lr][lj * 8];
    short8 afC1 = *(const short8*)&Cb[w * 16 + lr][32 + lj * 8];
    f32x4 acc_s[4] = {};
#pragma unroll
    for (int ni = 0; ni < 4; ++ni) {
      short8 bf0 = *(const short8*)&Bb[ni * 16 + lr][lj * 8];
      short8 bf1 = *(const short8*)&Bb[ni * 16 + lr][32 + lj * 8];
      acc_s[ni] = __builtin_amdgcn_mfma_f32_16x16x32_bf16(afC0, bf0, acc_s[ni], 0, 0, 0);
      acc_s[ni] = __builtin_amdgcn_mfma_f32_16x16x32_bf16(afC1, bf1, acc_s[ni], 0, 0, 0);
    }
    f32x4 acc_y[2] = {};
#pragma unroll
    for (int ni = 0; ni < 2; ++ni) {
      short8 hf0 = *(const short8*)&hbT[ni * 16 + lr][lj * 8];
      short8 hf1 = *(const short8*)&hbT[ni * 16 + lr][32 + lj * 8];
      acc_y[ni] = __builtin_amdgcn_mfma_f32_16x16x32_bf16(afC0, hf0, acc_y[ni], 0, 0, 0);
      acc_y[ni] = __builtin_amdgcn_mfma_f32_16x16x32_bf16(afC1, hf1, acc_y[ni], 0, 0, 0);
    }
#pragma unroll
    for (int j = 0; j < 4; ++j) {
      float at = __expf(la[w * 16 + lj * 4 + j]);
      acc_y[0][j] *= at;
      acc_y[1][j] *= at;
    }
    __syncthreads();   // bar2: Cb reads done
    // ---- P -> Cb (alias) ----
#pragma unroll
    for (int ni = 0; ni < 4; ++ni) {
      int s = ni * 16 + lr;
      float las = la[s], dts = dtc[s];
#pragma unroll
      for (int j = 0; j < 4; ++j) {
        int t = w * 16 + lj * 4 + j;
        float pv = 0.f;
        if (s <= t) pv = acc_s[ni][j] * __expf(la[t] - las) * dts;
        Cb[t][s] = (unsigned short)f2bf(pv);
      }
    }
    __syncthreads();   // bar3
    // ---- phase2: y += P@x ; h-update ----
    {
      short8 afP0 = *(const short8*)&Cb[w * 16 + lr][lj * 8];
      short8 afP1 = *(const short8*)&Cb[w * 16 + lr][32 + lj * 8];
#pragma unroll
      for (int ni = 0; ni < 2; ++ni) {
        short8 xf0 = *(const short8*)&xT[ni * 16 + lr][lj * 8];
        short8 xf1 = *(const short8*)&xT[ni * 16 + lr][32 + lj * 8];
        acc_y[ni] = __builtin_amdgcn_mfma_f32_16x16x32_bf16(afP0, xf0, acc_y[ni], 0, 0, 0);
        acc_y[ni] = __builtin_amdgcn_mfma_f32_16x16x32_bf16(afP1, xf1, acc_y[ni], 0, 0, 0);
      }
    }
    if (w < 2) {
      float aend = __expf(la[63]);
#pragma unroll
      for (int ni = 0; ni < 4; ++ni)
#pragma unroll
        for (int j = 0; j < 4; ++j) acc_h[ni][j] *= aend;
#pragma unroll
      for (int kk = 0; kk < 2; ++kk) {
        short8 xv = *(const short8*)&xT[w * 16 + lr][kk * 32 + lj * 8];
        short8 axf;
#pragma unroll
        for (int j = 0; j < 8; ++j)
          axf[j] = f2bf(bf2f((unsigned short)xv[j]) * wt[kk * 32 + lj * 8 + j]);
#pragma unroll
        for (int ni = 0; ni < 4; ++ni) {
          short8 bw = *(const short8*)&BbT[ni * 16 + lr][kk * 32 + lj * 8];
          acc_h[ni] = __builtin_amdgcn_mfma_f32_16x16x32_bf16(axf, bw, acc_h[ni], 0, 0, 0);
        }
      }
    }
    // ---- y epilogue (bf16) ----
#pragma unroll
    for (int ni = 0; ni < 2; ++ni) {
#pragma unroll
      for (int j = 0; j < 4; ++j) {
        int t = w * 16 + lj * 4 + j;
        int p = ni * 16 + lr;
        float yv = acc_y[ni][j] + dph * bf2f(xT[p][t]);
        ysc[(size_t)(tok0 + t) * DI + h * 32 + p] = (unsigned short)f2bf(yv);
      }
    }
    if (w < 2) {
#pragma unroll
      for (int ni = 0; ni < 4; ++ni)
#pragma unroll
        for (int j = 0; j < 4; ++j)
          hbT[w * 16 + lj * 4 + j][ni * 16 + lr] = (unsigned short)f2bf(acc_h[ni][j]);
    }
    __syncthreads();   // bar4: protect tiles from next stage
  }
}

// ---------------- y = rmsnorm(y * silu(z)) * nw -> bf16 (y bf16 in) ----------------
__global__ __launch_bounds__(256) void gate_rms_kernel(
    const unsigned short* __restrict__ ysc, const unsigned short* __restrict__ zx,
    const float* __restrict__ nw, unsigned short* __restrict__ yout) {
  int wid = threadIdx.x >> 6, lane = threadIdx.x & 63;
  size_t token = (size_t)blockIdx.x * 4 + wid;
  ushort4 yu = *(const ushort4*)(ysc + token * DI + lane * 4);
  ushort4 zu = *(const ushort4*)(zx + token * DIN + lane * 4);
  float y0 = bf2f(yu.x), y1 = bf2f(yu.y), y2 = bf2f(yu.z), y3 = bf2f(yu.w);
  float z0 = bf2f(zu.x), z1 = bf2f(zu.y), z2 = bf2f(zu.z), z3 = bf2f(zu.w);
  float g0 = y0 * (z0 / (1.f + expf(-z0)));
  float g1 = y1 * (z1 / (1.f + expf(-z1)));
  float g2 = y2 * (z2 / (1.f + expf(-z2)));
  float g3 = y3 * (z3 / (1.f + expf(-z3)));
  float ss = g0 * g0 + g1 * g1 + g2 * g2 + g3 * g3;
#pragma unroll
  for (int off = 1; off < 64; off <<= 1) ss += __shfl_xor(ss, off);
  float r = rsqrtf(ss * (1.f / 256.f) + EPSF);
  unsigned w0 = (unsigned short)f2bf(g0 * r * nw[lane * 4 + 0]);
  unsigned w1 = (unsigned short)f2bf(g1 * r * nw[lane * 4 + 1]);
  unsigned w2 = (unsigned short)f2bf(g2 * r * nw[lane * 4 + 2]);
  unsigned w3 = (unsigned short)f2bf(g3 * r * nw[lane * 4 + 3]);
  uint2 packed = make_uint2(w0 | (w1 << 16), w2 | (w3 << 16));
  *(uint2*)(yout + token * DI + lane * 4) = packed;
}

// ---------------- column mean over L (bf16 in) ----------------
__global__ __launch_bounds__(128) void colmean_kernel(const unsigned short* __restrict__ tn,
                                                      float* __restrict__ tmean) {
  int b = blockIdx.x, e = threadIdx.x;
  const unsigned short* p = tn + (size_t)b * 256 * 128 + e;
  float acc = 0.f;
  for (int l = 0; l < 256; ++l) acc += bf2f(p[l * 128]);
  tmean[b * 128 + e] = acc * (1.f / 256.f);
}

// ---------------- head matmul + L2 normalize ----------------
__global__ __launch_bounds__(128) void head_kernel(
    const float* __restrict__ tmean, const float* __restrict__ hw,
    const float* __restrict__ hb, float* __restrict__ out) {
  __shared__ float tm[128];
  __shared__ float red[2];
  int b = blockIdx.x, o = threadIdx.x;
  tm[o] = tmean[b * 128 + o];
  __syncthreads();
  float acc = hb[o];
  for (int e = 0; e < 128; ++e) acc += tm[e] * hw[o * 128 + e];
  float ss = acc * acc;
#pragma unroll
  for (int off = 1; off < 64; off <<= 1) ss += __shfl_xor(ss, off);
  if ((o & 63) == 0) red[o >> 6] = ss;
  __syncthreads();
  float nrm = fmaxf(sqrtf(red[0] + red[1]), 1e-12f);
  out[b * 128 + o] = acc / nrm;
}

extern "C" void kernel_launch(void* const* d_in, const int* in_sizes, int n_in,
                              void* d_out, int out_size, void* d_ws, size_t ws_size,
                              hipStream_t stream) {
  const float* x      = (const float*)d_in[0];
  const float* conv_w = (const float*)d_in[1];
  const float* conv_b = (const float*)d_in[2];
  const float* pe_w   = (const float*)d_in[3];
  const float* pe_b   = (const float*)d_in[4];
  const float* ln_w   = (const float*)d_in[5];
  const float* ln_b   = (const float*)d_in[6];
  const float* in_w   = (const float*)d_in[7];
  const float* c1w    = (const float*)d_in[8];
  const float* c1b    = (const float*)d_in[9];
  const float* dtb    = (const float*)d_in[10];
  const float* A_log  = (const float*)d_in[11];
  const float* Dp     = (const float*)d_in[12];
  const float* nw     = (const float*)d_in[13];
  const float* ow     = (const float*)d_in[14];
  const float* fn_w   = (const float*)d_in[15];
  const float* fn_b   = (const float*)d_in[16];
  const float* hw     = (const float*)d_in[17];
  const float* hb     = (const float*)d_in[18];
  float* out = (float*)d_out;

  const size_t T = TTOK;
  char* w8 = (char*)d_ws;
  float*          t_buf = (float*)w8;            w8 += T * 128 * 4;   // residual fp32
  unsigned*       tnb   = (unsigned*)w8;         w8 += T * 128 * 2;   // ln out bf16
  unsigned short* zx    = (unsigned short*)w8;   w8 += T * (size_t)DIN * 2; // in-proj bf16
  unsigned short* xbc   = (unsigned short*)w8;   w8 += T * (size_t)XBC * 2; // conv out bf16
  float*          dtraw = (float*)w8;            w8 += T * 8 * 4;
  float*          dtv   = (float*)w8;            w8 += T * 8 * 4;
  float*          ldAv  = (float*)w8;            w8 += T * 8 * 4;
  unsigned short* ysc   = (unsigned short*)w8;   w8 += T * (size_t)DI * 2;  // scan out bf16
  unsigned short* ybb   = (unsigned short*)w8;   w8 += T * (size_t)DI * 2;  // gated bf16
  float*          tmean = (float*)w8;            w8 += 256 * 128 * 4;
  unsigned short* in_wb = (unsigned short*)w8;   w8 += (size_t)NL * DIN * EE * 2;
  unsigned short* owb   = (unsigned short*)w8;   w8 += (size_t)NL * EE * DI * 2;
  if ((size_t)(w8 - (char*)d_ws) > ws_size) return;  // workspace too small

  // one-shot weight conversion (NL*DIN*EE = 331776 = 1296*256)
  cvt_w_kernel<<<1296, 256, 0, stream>>>(in_w, ow, in_wb, owb);

  // patch embed + bias, pe layernorm (fp32), first block LN (bf16)
  gemm_bf16_patch<<<dim3(512, 1), 256, 0, stream>>>(x, conv_w, conv_b, t_buf);
  ln_kernel<<<16384, 256, 0, stream>>>(t_buf, t_buf, pe_w, pe_b);
  ln_bf16_kernel<<<16384, 256, 0, stream>>>(t_buf, tnb, ln_w, ln_b);

  for (int i = 0; i < NL; ++i) {
    gemm_in_proj<<<dim3(512, 6), 256, 0, stream>>>(
        (const unsigned short*)tnb, in_wb + (size_t)i * DIN * EE, zx, dtraw, TTOK, DIN, EE);
    conv_silu_kernel<<<24576, 256, 0, stream>>>(zx, c1w + (size_t)i * XBC * DC, c1b + (size_t)i * XBC, xbc);
    dt_kernel<<<2048, 256, 0, stream>>>(dtraw, dtb + i * HH, A_log + i * HH, dtv, ldAv);
    scan_chunk_kernel<<<2048, 256, 0, stream>>>(xbc, dtv, ldAv, Dp + i * HH, ysc);
    gate_rms_kernel<<<16384, 256, 0, stream>>>(ysc, zx, nw + i * DI, ybb);
    const float* nlw = (i < NL - 1) ? (ln_w + (i + 1) * 128) : fn_w;
    const float* nlb = (i < NL - 1) ? (ln_b + (i + 1) * 128) : fn_b;
    gemm_out_ln<<<512, 256, 0, stream>>>(
        ybb, owb + (size_t)i * EE * DI, t_buf, nlw, nlb, tnb);
  }

  // tnb now holds final-LN output (fused in last gemm_out_ln)
  colmean_kernel<<<256, 128, 0, stream>>>((const unsigned short*)tnb, tmean);
  head_kernel<<<256, 128, 0, stream>>>(tmean, hw, hb, out);
}